// Round 16
// baseline (2194.443 us; speedup 1.0000x reference)
//
#include <hip/hip_runtime.h>
#include <math.h>

// Problem constants
#define BTOT   4096
#define CIN    3
#define TIN    64
#define SIN    128

// ws layout (float offsets)
#define SEQ_OFF    0                            // [4096][60][124]
#define G_OFF      (SEQ_OFF + 4096*60*124)      // [4096][129]
#define HST_OFF    (G_OFF + 4096*129)           // [4096][148] h state between chunks
#define WHR_OFF    (HST_OFF + 4096*148)         // [27][576][4] lane-linear Whh
#define WIR_OFF    (WHR_OFF + 27*576*4)         // [24][576][4] lane-linear Wih
#define MUWP_OFF   (WIR_OFF + 24*576*4)         // [129][260]
#define LSWP_OFF   (MUWP_OFF + 129*260)         // [129][260]
#define GIC_OFF    (LSWP_OFF + 129*260)         // [CT][387][4096] gi chunk

// Inline transcendentals (no libm calls in hot loops; ocml calls force
// loop-resident values into callee-saved regs -> spill)
__device__ __forceinline__ float fast_tanh(float x) {
    float ax = fabsf(x);
    float t  = __expf(-2.f * ax);
    float r  = (1.f - t) / (1.f + t);
    return copysignf(r, x);
}
__device__ __forceinline__ float fast_sigmoid(float x) {
    return 1.f / (1.f + __expf(-x));
}

// ---------------------------------------------------------------------------
// Prep: lane-linear weight tables + fc weight padding (see R14/R15 notes).
// ---------------------------------------------------------------------------
__global__ __launch_bounds__(256) void prep_pad(
    const float* __restrict__ Whh, const float* __restrict__ Wih,
    const float* __restrict__ muw, const float* __restrict__ lsw,
    float* __restrict__ ws)
{
    int idx = blockIdx.x * 256 + threadIdx.x;
    const int NH = 27 * 576 * 4;
    const int NI = 24 * 576 * 4;
    const int N2 = 129 * 260;
    if (idx < NH) {
        int m   = idx / 2304;
        int rem = idx - m * 2304;
        int l   = rem >> 2;
        int c   = rem & 3;
        int g   = m / 9;
        int i   = m - g * 9;
        int gq  = (l < 512) ? (l >> 2) : 128;
        int kq  = l & 3;
        int row = g * 129 + gq;
        int col = kq * 36 + i * 4 + c;
        ws[WHR_OFF + idx] = (col < 129) ? Whh[(size_t)row * 129 + col] : 0.f;
    } else if (idx < NH + NI) {
        int i2  = idx - NH;
        int m   = i2 / 2304;
        int rem = i2 - m * 2304;
        int l   = rem >> 2;
        int c   = rem & 3;
        int g   = m / 8;
        int i   = m - g * 8;
        int gq  = (l < 512) ? (l >> 2) : 128;
        int kq  = l & 3;
        int row = g * 129 + gq;
        int col = kq * 32 + i * 4 + c;
        ws[WIR_OFF + i2] = (col < 124) ? Wih[(size_t)row * 124 + col] : 0.f;
    } else if (idx < NH + NI + N2) {
        int i = idx - NH - NI; int j = i / 260, k = i - j * 260;
        ws[MUWP_OFF + i] = (k < 258) ? muw[j * 258 + k] : 0.f;
    } else if (idx < NH + NI + 2 * N2) {
        int i = idx - NH - NI - N2; int j = i / 260, k = i - j * 260;
        ws[LSWP_OFF + i] = (k < 258) ? lsw[j * 258 + k] : 0.f;
    }
}

// ---------------------------------------------------------------------------
// Fused conv1+conv2 v2 (register-blocked, weight-resident) — passing R13.
// ---------------------------------------------------------------------------
#define C1SEG(c_, kt_, W0_, W1_, W2_) { \
    const float* rp_ = xt + ((c_) * 14 + tq + (kt_)) * 128 + s0; \
    float4 v4_ = *(const float4*)rp_; \
    float2 v2_ = *(const float2*)(rp_ + 4); \
    acc0 += v4_.x*(W0_) + v4_.y*(W1_) + v4_.z*(W2_); \
    acc1 += v4_.y*(W0_) + v4_.z*(W1_) + v4_.w*(W2_); \
    acc2 += v4_.z*(W0_) + v4_.w*(W1_) + v2_.x*(W2_); \
    acc3 += v4_.w*(W0_) + v2_.x*(W1_) + v2_.y*(W2_); }

#define C2SEG(o_, kt_, W0_, W1_, W2_) { \
    const float* rp_ = h1t + ((o_) * 12 + tq + (kt_)) * 128 + s0; \
    float4 v4_ = *(const float4*)rp_; \
    float2 v2_ = *(const float2*)(rp_ + 4); \
    acc0 += v4_.x*(W0_) + v4_.y*(W1_) + v4_.z*(W2_); \
    acc1 += v4_.y*(W0_) + v4_.z*(W1_) + v4_.w*(W2_); \
    acc2 += v4_.z*(W0_) + v4_.w*(W1_) + v2_.x*(W2_); \
    acc3 += v4_.w*(W0_) + v2_.x*(W1_) + v2_.y*(W2_); }

__global__ __launch_bounds__(256) void conv_fused(
    const float* __restrict__ x,
    const float* __restrict__ w1, const float* __restrict__ b1,
    const float* __restrict__ w2, const float* __restrict__ b2,
    float* __restrict__ seq)
{
    __shared__ __attribute__((aligned(16))) float xt[3 * 14 * 128 + 8];
    __shared__ __attribute__((aligned(16))) float h1t[6 * 12 * 128];
    __shared__ float w1s[162];
    __shared__ float w2s[54];
    __shared__ float b1s[6];
    __shared__ float b2s;

    const int tid  = threadIdx.x;
    const int tile = blockIdx.x;   // 0..5
    const int bb   = blockIdx.y;   // batch
    const int T0   = tile * 10;

    if (tid < 162)                  w1s[tid] = w1[tid];
    if (tid >= 192 && tid < 246)    w2s[tid - 192] = w2[tid - 192];
    if (tid >= 248 && tid < 254)    b1s[tid - 248] = b1[tid - 248];
    if (tid == 255)                 b2s = b2[0];

    // stage x tile: 42 rows x 32 float4 (coalesced)
    {
        const float* xb = x + (size_t)bb * CIN * TIN * SIN;
        for (int i = tid; i < 3 * 14 * 32; i += 256) {
            int c   = i / (14 * 32);
            int rem = i - c * (14 * 32);
            int t   = rem >> 5;
            int k4  = rem & 31;
            ((float4*)(xt + (c * 14 + t) * 128))[k4] =
                *(const float4*)(xb + ((size_t)(c * TIN + T0 + t)) * SIN + k4 * 4);
        }
    }
    __syncthreads();

    // ---- conv1 + leaky: tid<192, thread = (o, 4-col group), 12 t-rows ----
    if (tid < 192) {
        const int o  = tid >> 5;
        const int s0 = (tid & 31) * 4;
        const float* wb = w1s + o * 27;
        float w000 = wb[0],  w001 = wb[1],  w002 = wb[2];
        float w010 = wb[3],  w011 = wb[4],  w012 = wb[5];
        float w020 = wb[6],  w021 = wb[7],  w022 = wb[8];
        float w100 = wb[9],  w101 = wb[10], w102 = wb[11];
        float w110 = wb[12], w111 = wb[13], w112 = wb[14];
        float w120 = wb[15], w121 = wb[16], w122 = wb[17];
        float w200 = wb[18], w201 = wb[19], w202 = wb[20];
        float w210 = wb[21], w211 = wb[22], w212 = wb[23];
        float w220 = wb[24], w221 = wb[25], w222 = wb[26];
        float bo = b1s[o];
        for (int tq = 0; tq < 12; ++tq) {
            float acc0 = bo, acc1 = bo, acc2 = bo, acc3 = bo;
            C1SEG(0, 0, w000, w001, w002)
            C1SEG(0, 1, w010, w011, w012)
            C1SEG(0, 2, w020, w021, w022)
            C1SEG(1, 0, w100, w101, w102)
            C1SEG(1, 1, w110, w111, w112)
            C1SEG(1, 2, w120, w121, w122)
            C1SEG(2, 0, w200, w201, w202)
            C1SEG(2, 1, w210, w211, w212)
            C1SEG(2, 2, w220, w221, w222)
            float4 r;
            r.x = (acc0 >= 0.f) ? acc0 : 0.01f * acc0;
            r.y = (acc1 >= 0.f) ? acc1 : 0.01f * acc1;
            r.z = (acc2 >= 0.f) ? acc2 : 0.01f * acc2;
            r.w = (acc3 >= 0.f) ? acc3 : 0.01f * acc3;
            *(float4*)(h1t + (o * 12 + tq) * 128 + s0) = r;
        }
    }
    __syncthreads();

    // ---- conv2 + leaky: 310 tasks = (t in [0,10), sg in [0,31)) ----
    {
        float u000 = w2s[0],  u001 = w2s[1],  u002 = w2s[2];
        float u010 = w2s[3],  u011 = w2s[4],  u012 = w2s[5];
        float u020 = w2s[6],  u021 = w2s[7],  u022 = w2s[8];
        float u100 = w2s[9],  u101 = w2s[10], u102 = w2s[11];
        float u110 = w2s[12], u111 = w2s[13], u112 = w2s[14];
        float u120 = w2s[15], u121 = w2s[16], u122 = w2s[17];
        float u200 = w2s[18], u201 = w2s[19], u202 = w2s[20];
        float u210 = w2s[21], u211 = w2s[22], u212 = w2s[23];
        float u220 = w2s[24], u221 = w2s[25], u222 = w2s[26];
        float u300 = w2s[27], u301 = w2s[28], u302 = w2s[29];
        float u310 = w2s[30], u311 = w2s[31], u312 = w2s[32];
        float u320 = w2s[33], u321 = w2s[34], u322 = w2s[35];
        float u400 = w2s[36], u401 = w2s[37], u402 = w2s[38];
        float u410 = w2s[39], u411 = w2s[40], u412 = w2s[41];
        float u420 = w2s[42], u421 = w2s[43], u422 = w2s[44];
        float u500 = w2s[45], u501 = w2s[46], u502 = w2s[47];
        float u510 = w2s[48], u511 = w2s[49], u512 = w2s[50];
        float u520 = w2s[51], u521 = w2s[52], u522 = w2s[53];
        float bo2 = b2s;
        for (int idx = tid; idx < 310; idx += 256) {
            const int tq = idx / 31;
            const int s0 = (idx - tq * 31) * 4;
            float acc0 = bo2, acc1 = bo2, acc2 = bo2, acc3 = bo2;
            C2SEG(0, 0, u000, u001, u002)
            C2SEG(0, 1, u010, u011, u012)
            C2SEG(0, 2, u020, u021, u022)
            C2SEG(1, 0, u100, u101, u102)
            C2SEG(1, 1, u110, u111, u112)
            C2SEG(1, 2, u120, u121, u122)
            C2SEG(2, 0, u200, u201, u202)
            C2SEG(2, 1, u210, u211, u212)
            C2SEG(2, 2, u220, u221, u222)
            C2SEG(3, 0, u300, u301, u302)
            C2SEG(3, 1, u310, u311, u312)
            C2SEG(3, 2, u320, u321, u322)
            C2SEG(4, 0, u400, u401, u402)
            C2SEG(4, 1, u410, u411, u412)
            C2SEG(4, 2, u420, u421, u422)
            C2SEG(5, 0, u500, u501, u502)
            C2SEG(5, 1, u510, u511, u512)
            C2SEG(5, 2, u520, u521, u522)
            float4 r;
            r.x = (acc0 >= 0.f) ? acc0 : 0.01f * acc0;
            r.y = (acc1 >= 0.f) ? acc1 : 0.01f * acc1;
            r.z = (acc2 >= 0.f) ? acc2 : 0.01f * acc2;
            r.w = (acc3 >= 0.f) ? acc3 : 0.01f * acc3;
            *(float4*)(seq + ((size_t)bb * 60 + T0 + tq) * 124 + s0) = r;
        }
    }
}

// ---------------------------------------------------------------------------
// Shared macro kit (R10 lesson: macro params must not be named x/y/z/w)
// ---------------------------------------------------------------------------
#define D4(acc_, hv4_, wv4_) acc_ += (hv4_).x*(wv4_).x + (hv4_).y*(wv4_).y + (hv4_).z*(wv4_).z + (hv4_).w*(wv4_).w;
#define RED(acc_) { acc_ += __shfl_xor(acc_, 1, 64); acc_ += __shfl_xor(acc_, 2, 64); }

// ---------------------------------------------------------------------------
// gi GEMM v4: 8 rows/block x 512 blocks (2 blocks/CU -> 4.5 waves/SIMD;
// R15 lesson: 1 block/CU left reload+barrier latency exposed).
// ---------------------------------------------------------------------------
#define GI_ROW(R, aA, aB, aC) { \
    const float4* hv_ = (const float4*)(xs2 + (R) * 132) + kqo8; \
    float4 h4_; \
    h4_ = hv_[0]; D4(aA, h4_, Va0) D4(aB, h4_, Vb0) D4(aC, h4_, Vc0) \
    h4_ = hv_[1]; D4(aA, h4_, Va1) D4(aB, h4_, Vb1) D4(aC, h4_, Vc1) \
    h4_ = hv_[2]; D4(aA, h4_, Va2) D4(aB, h4_, Vb2) D4(aC, h4_, Vc2) \
    h4_ = hv_[3]; D4(aA, h4_, Va3) D4(aB, h4_, Vb3) D4(aC, h4_, Vc3) \
    h4_ = hv_[4]; D4(aA, h4_, Va4) D4(aB, h4_, Vb4) D4(aC, h4_, Vc4) \
    h4_ = hv_[5]; D4(aA, h4_, Va5) D4(aB, h4_, Vb5) D4(aC, h4_, Vc5) \
    h4_ = hv_[6]; D4(aA, h4_, Va6) D4(aB, h4_, Vb6) D4(aC, h4_, Vc6) \
    h4_ = hv_[7]; D4(aA, h4_, Va7) D4(aB, h4_, Vb7) D4(aC, h4_, Vc7) }

#define GI_CHUNK(R0) { \
    float aA0 = 0.f, aB0 = 0.f, aC0 = 0.f, aA1 = 0.f, aB1 = 0.f, aC1 = 0.f; \
    float aA2 = 0.f, aB2 = 0.f, aC2 = 0.f, aA3 = 0.f, aB3 = 0.f, aC3 = 0.f; \
    GI_ROW((R0) + 0, aA0, aB0, aC0) \
    GI_ROW((R0) + 1, aA1, aB1, aC1) \
    GI_ROW((R0) + 2, aA2, aB2, aC2) \
    GI_ROW((R0) + 3, aA3, aB3, aC3) \
    RED(aA0) RED(aB0) RED(aC0) RED(aA1) RED(aB1) RED(aC1) \
    RED(aA2) RED(aB2) RED(aC2) RED(aA3) RED(aB3) RED(aC3) \
    float sA = (kq == 0) ? aA0 : (kq == 1) ? aA1 : (kq == 2) ? aA2 : aA3; \
    float sB = (kq == 0) ? aB0 : (kq == 1) ? aB1 : (kq == 2) ? aB2 : aB3; \
    float sC = (kq == 0) ? aC0 : (kq == 1) ? aC1 : (kq == 2) ? aC2 : aC3; \
    int rw_ = (R0) + kq; \
    GIb[rw_ * 389 + gq]       = sA; \
    GIb[rw_ * 389 + 129 + gq] = sB; \
    GIb[rw_ * 389 + 258 + gq] = sC; }

__global__ __launch_bounds__(576)
void gi_gemm2(
    const float* __restrict__ seq, const float* __restrict__ wir,  // [24][576][4]
    float* __restrict__ gic, int t0, int nt)
{
    __shared__ __attribute__((aligned(16))) float xs2[8 * 132];  // stride 132
    __shared__ float GIb[8 * 389];

    const int tid    = threadIdx.x;
    const int kq     = tid & 3;
    const int kqo8   = kq * 8;           // f4 offset into a 32-float k-chunk
    const int b0     = blockIdx.x * 8;
    const bool isMain = (tid < 512);
    const int gq     = isMain ? (tid >> 2) : 0;      // [0,128)
    const int rsp8   = ((tid - 512) >> 2) & 7;       // special wave row (x2 dup)

    // lane-linear coalesced weight loads (L2-resident table)
    const float4* wir4 = (const float4*)wir;
    float4 Va0 = wir4[0*576+tid],  Va1 = wir4[1*576+tid],
           Va2 = wir4[2*576+tid],  Va3 = wir4[3*576+tid],
           Va4 = wir4[4*576+tid],  Va5 = wir4[5*576+tid],
           Va6 = wir4[6*576+tid],  Va7 = wir4[7*576+tid];
    float4 Vb0 = wir4[8*576+tid],  Vb1 = wir4[9*576+tid],
           Vb2 = wir4[10*576+tid], Vb3 = wir4[11*576+tid],
           Vb4 = wir4[12*576+tid], Vb5 = wir4[13*576+tid],
           Vb6 = wir4[14*576+tid], Vb7 = wir4[15*576+tid];
    float4 Vc0 = wir4[16*576+tid], Vc1 = wir4[17*576+tid],
           Vc2 = wir4[18*576+tid], Vc3 = wir4[19*576+tid],
           Vc4 = wir4[20*576+tid], Vc5 = wir4[21*576+tid],
           Vc6 = wir4[22*576+tid], Vc7 = wir4[23*576+tid];

    // zero the k-pad (floats 124..127 of each row) so 0-weight x pad = 0
    if (tid < 32) xs2[(tid >> 2) * 132 + 124 + (tid & 3)] = 0.f;

    const int sr = tid / 31;             // row 0..7 (tid<248)
    const int sk = tid - sr * 31;        // f4 0..30

    for (int tt = 0; tt < nt; ++tt) {
        if (tid < 248) {
            const float4* srcf4 =
                (const float4*)(seq + ((size_t)(b0 + sr) * 60 + (t0 + tt)) * 124);
            ((float4*)(xs2 + sr * 132))[sk] = srcf4[sk];
        }
        __syncthreads();

        if (isMain) {
            GI_CHUNK(0)
            GI_CHUNK(4)
        } else {
            #pragma unroll
            for (int rr = 0; rr < 8; ++rr) {
                float aA = 0.f, aB = 0.f, aC = 0.f;
                GI_ROW(rr, aA, aB, aC)
                RED(aA) RED(aB) RED(aC)
                if (rr == rsp8 && kq == 0) {
                    GIb[rr * 389 + 128] = aA;
                    GIb[rr * 389 + 257] = aB;
                    GIb[rr * 389 + 386] = aC;
                }
            }
        }
        __syncthreads();

        {
            float* gout = gic + (size_t)tt * 387 * 4096 + b0;
            for (int e = tid; e < 3096; e += 576) {
                int r = e & 7;
                int j = e >> 3;
                gout[(size_t)j * 4096 + r] = GIb[r * 389 + j];
            }
        }
        __syncthreads();
    }
}

// ---------------------------------------------------------------------------
// GRU recurrence v6: 8 rows/block x 512 blocks (2 blocks/CU).
// ---------------------------------------------------------------------------
#define GH_ROW(R, aA, aB, aC) { \
    const float4* hv_ = (const float4*)(hs2 + (R) * 148) + kqo; \
    float4 h4_; \
    h4_ = hv_[0]; D4(aA, h4_, Wa0) D4(aB, h4_, Wb0) D4(aC, h4_, Wc0) \
    h4_ = hv_[1]; D4(aA, h4_, Wa1) D4(aB, h4_, Wb1) D4(aC, h4_, Wc1) \
    h4_ = hv_[2]; D4(aA, h4_, Wa2) D4(aB, h4_, Wb2) D4(aC, h4_, Wc2) \
    h4_ = hv_[3]; D4(aA, h4_, Wa3) D4(aB, h4_, Wb3) D4(aC, h4_, Wc3) \
    h4_ = hv_[4]; D4(aA, h4_, Wa4) D4(aB, h4_, Wb4) D4(aC, h4_, Wc4) \
    h4_ = hv_[5]; D4(aA, h4_, Wa5) D4(aB, h4_, Wb5) D4(aC, h4_, Wc5) \
    h4_ = hv_[6]; D4(aA, h4_, Wa6) D4(aB, h4_, Wb6) D4(aC, h4_, Wc6) \
    h4_ = hv_[7]; D4(aA, h4_, Wa7) D4(aB, h4_, Wb7) D4(aC, h4_, Wc7) \
    h4_ = hv_[8]; D4(aA, h4_, Wa8) D4(aB, h4_, Wb8) D4(aC, h4_, Wc8) }

#define CHUNK(R0) { \
    float aA0 = 0.f, aB0 = 0.f, aC0 = 0.f, aA1 = 0.f, aB1 = 0.f, aC1 = 0.f; \
    float aA2 = 0.f, aB2 = 0.f, aC2 = 0.f, aA3 = 0.f, aB3 = 0.f, aC3 = 0.f; \
    GH_ROW((R0) + 0, aA0, aB0, aC0) \
    GH_ROW((R0) + 1, aA1, aB1, aC1) \
    GH_ROW((R0) + 2, aA2, aB2, aC2) \
    GH_ROW((R0) + 3, aA3, aB3, aC3) \
    RED(aA0) RED(aB0) RED(aC0) RED(aA1) RED(aB1) RED(aC1) \
    RED(aA2) RED(aB2) RED(aC2) RED(aA3) RED(aB3) RED(aC3) \
    float sA = (kq == 0) ? aA0 : (kq == 1) ? aA1 : (kq == 2) ? aA2 : aA3; \
    float sB = (kq == 0) ? aB0 : (kq == 1) ? aB1 : (kq == 2) ? aB2 : aB3; \
    float sC = (kq == 0) ? aC0 : (kq == 1) ? aC1 : (kq == 2) ? aC2 : aC3; \
    int rw_ = (R0) + kq; \
    GHb[rw_ * 388 + gq]       = sA; \
    GHb[rw_ * 388 + 129 + gq] = sB; \
    GHb[rw_ * 388 + 258 + gq] = sC; }

#define APPLY(E, PGA, PGB, PGC) { \
    int r_ = (E) & 7, j_ = (E) >> 3; \
    float pr_  = (PGA) + GHb[r_ * 388 + j_]       + bihS[j_]       + bhhS[j_]; \
    float pz_  = (PGB) + GHb[r_ * 388 + 129 + j_] + bihS[129 + j_] + bhhS[129 + j_]; \
    float gin_ = (PGC) + bihS[258 + j_]; \
    float ghn_ = GHb[r_ * 388 + 258 + j_] + bhhS[258 + j_]; \
    float rg_ = fast_sigmoid(pr_); \
    float zg_ = fast_sigmoid(pz_); \
    float nn_ = fast_tanh(gin_ + rg_ * ghn_); \
    hs2[r_ * 148 + j_] = (1.f - zg_) * nn_ + zg_ * hs2[r_ * 148 + j_]; }

__global__ __launch_bounds__(576)
void gru_rec(
    const float* __restrict__ gic, const float* __restrict__ whr,  // [27][576][4]
    const float* __restrict__ bih, const float* __restrict__ bhh,
    float* __restrict__ hstate, float* __restrict__ g_out,
    int t0, int nt)
{
    __shared__ __attribute__((aligned(16))) float hs2[8 * 148];  // stride 148
    __shared__ float GHb[8 * 388];
    __shared__ float bihS[387];
    __shared__ float bhhS[387];

    const int tid    = threadIdx.x;
    const int kq     = tid & 3;
    const int kqo    = kq * 9;           // f4 offset into a 36-float k-chunk
    const int b0     = blockIdx.x * 8;
    const bool isMain = (tid < 512);
    const int gq     = isMain ? (tid >> 2) : 0;      // [0,128)
    const int rsp8   = ((tid - 512) >> 2) & 7;       // special wave row (x2 dup)

    // lane-linear coalesced weight loads (L2-resident table)
    const float4* whr4 = (const float4*)whr;
    float4 Wa0 = whr4[0*576+tid],  Wa1 = whr4[1*576+tid],
           Wa2 = whr4[2*576+tid],  Wa3 = whr4[3*576+tid],
           Wa4 = whr4[4*576+tid],  Wa5 = whr4[5*576+tid],
           Wa6 = whr4[6*576+tid],  Wa7 = whr4[7*576+tid],
           Wa8 = whr4[8*576+tid];
    float4 Wb0 = whr4[9*576+tid],  Wb1 = whr4[10*576+tid],
           Wb2 = whr4[11*576+tid], Wb3 = whr4[12*576+tid],
           Wb4 = whr4[13*576+tid], Wb5 = whr4[14*576+tid],
           Wb6 = whr4[15*576+tid], Wb7 = whr4[16*576+tid],
           Wb8 = whr4[17*576+tid];
    float4 Wc0 = whr4[18*576+tid], Wc1 = whr4[19*576+tid],
           Wc2 = whr4[20*576+tid], Wc3 = whr4[21*576+tid],
           Wc4 = whr4[22*576+tid], Wc5 = whr4[23*576+tid],
           Wc6 = whr4[24*576+tid], Wc7 = whr4[25*576+tid],
           Wc8 = whr4[26*576+tid];

    if (tid < 387) { bihS[tid] = bih[tid]; bhhS[tid] = bhh[tid]; }
    if (t0 == 0) {
        for (int e = tid; e < 8 * 148; e += 576) hs2[e] = 0.f;
    } else {
        for (int e = tid; e < 8 * 148; e += 576) hs2[e] = hstate[(size_t)b0 * 148 + e];
    }
    __syncthreads();

    const int e0 = tid, e1 = tid + 576;   // gate elems: 8*129 = 1032

    for (int tt = 0; tt < nt; ++tt) {
        const float* gib = gic + (size_t)tt * 387 * 4096 + b0;
        float pa0, pb0, pc0;
        float pa1 = 0.f, pb1 = 0.f, pc1 = 0.f;
        {
            int r = e0 & 7, j = e0 >> 3;
            if (e0 < 1032) {
                pa0 = gib[(size_t)j * 4096 + r];
                pb0 = gib[(size_t)(129 + j) * 4096 + r];
                pc0 = gib[(size_t)(258 + j) * 4096 + r];
            } else { pa0 = pb0 = pc0 = 0.f; }
            if (e1 < 1032) {
                r = e1 & 7; j = e1 >> 3;
                pa1 = gib[(size_t)j * 4096 + r];
                pb1 = gib[(size_t)(129 + j) * 4096 + r];
                pc1 = gib[(size_t)(258 + j) * 4096 + r];
            }
        }

        if (isMain) {
            CHUNK(0)
            CHUNK(4)
        } else {
            float aA = 0.f, aB = 0.f, aC = 0.f;
            GH_ROW(rsp8, aA, aB, aC)
            RED(aA) RED(aB) RED(aC)
            if (kq == 0) {
                GHb[rsp8 * 388 + 128] = aA;
                GHb[rsp8 * 388 + 257] = aB;
                GHb[rsp8 * 388 + 386] = aC;
            }
        }
        __syncthreads();

        if (e0 < 1032) { APPLY(e0, pa0, pb0, pc0) }
        if (e1 < 1032) { APPLY(e1, pa1, pb1, pc1) }
        __syncthreads();
    }

    for (int e = tid; e < 8 * 148; e += 576) hstate[(size_t)b0 * 148 + e] = hs2[e];
    if (t0 + nt >= 60) {
        if (e0 < 1032) { int r = e0 & 7, j = e0 >> 3; float v = hs2[r * 148 + j];
            g_out[(size_t)(b0 + r) * 129 + j] = (v >= 0.f) ? v : 0.01f * v; }
        if (e1 < 1032) { int r = e1 & 7, j = e1 >> 3; float v = hs2[r * 148 + j];
            g_out[(size_t)(b0 + r) * 129 + j] = (v >= 0.f) ? v : 0.01f * v; }
    }
}

// ---------------------------------------------------------------------------
// Head: feat=[g,w] (258) -> mu, log_std -> sample, tanh, log_pi, normalize.
// ---------------------------------------------------------------------------
__global__ __launch_bounds__(256) void head_kernel(
    const float* __restrict__ gbuf, const float* __restrict__ wvec,
    const float* __restrict__ eps,
    const float* __restrict__ muwp, const float* __restrict__ lswp,
    const float* __restrict__ mub,  const float* __restrict__ lsb,
    float* __restrict__ out)
{
    __shared__ __attribute__((aligned(16))) float feat[16 * 260];
    __shared__ float PA[16 * 130];
    __shared__ float TERM[16 * 130];
    __shared__ float ROWSUM[16];
    __shared__ float ROWLOG[16];

    const int tid = threadIdx.x;
    const int b0  = blockIdx.x * 16;

    for (int i = tid; i < 16 * 260; i += 256) {
        int r = i / 260;
        int k = i - r * 260;
        float v = 0.f;
        if (k < 129)       v = gbuf[(size_t)(b0 + r) * 129 + k];
        else if (k < 258)  v = wvec[(size_t)(b0 + r) * 129 + (k - 129)];
        feat[i] = v;
    }
    __syncthreads();

    for (int idx = tid; idx < 16 * 129; idx += 256) {
        int r = idx & 15;
        int j = idx >> 4;
        const float4* fv = (const float4*)(feat + r * 260);
        const float4* mw = (const float4*)(muwp + (size_t)j * 260);
        const float4* lw = (const float4*)(lswp + (size_t)j * 260);
        float am = 0.f, al = 0.f;
        for (int k = 0; k < 65; ++k) {
            float4 f = fv[k];
            float4 m = mw[k];
            float4 l = lw[k];
            am += f.x * m.x + f.y * m.y + f.z * m.z + f.w * m.w;
            al += f.x * l.x + f.y * l.y + f.z * l.z + f.w * l.w;
        }
        float mu = am + mub[j];
        float ls = fminf(fmaxf(al + lsb[j], -20.f), 2.f);
        float sd = __expf(ls);
        float e  = eps[(size_t)(b0 + r) * 129 + j];
        float xv = mu + sd * e;
        float pa = fast_tanh(xv);
        float tt = (xv - mu) / sd;
        float term = -0.5f * tt * tt - ls - 0.91893853320467274f
                     - __logf(1.f - pa * pa + 1e-6f);
        PA[r * 130 + j]   = pa;
        TERM[r * 130 + j] = term;
    }
    __syncthreads();

    {
        int r = tid >> 4;
        int i = tid & 15;
        float sp = 0.f, st = 0.f;
        for (int j = i; j < 129; j += 16) {
            sp += PA[r * 130 + j];
            st += TERM[r * 130 + j];
        }
        for (int off = 8; off > 0; off >>= 1) {
            sp += __shfl_down(sp, off, 16);
            st += __shfl_down(st, off, 16);
        }
        if (i == 0) { ROWSUM[r] = sp + 129.f; ROWLOG[r] = st; }
    }
    __syncthreads();

    for (int idx = tid; idx < 16 * 129; idx += 256) {
        int r = idx & 15;
        int j = idx >> 4;
        out[(size_t)(b0 + r) * 129 + j] = (PA[r * 130 + j] + 1.f) / ROWSUM[r];
    }
    if (tid < 16)
        out[(size_t)4096 * 129 + b0 + tid] = ROWLOG[tid];
}

// ---------------------------------------------------------------------------
extern "C" void kernel_launch(void* const* d_in, const int* in_sizes, int n_in,
                              void* d_out, int out_size, void* d_ws, size_t ws_size,
                              hipStream_t stream)
{
    const float* x   = (const float*)d_in[0];
    const float* wv  = (const float*)d_in[1];
    const float* eps = (const float*)d_in[2];
    const float* c1w = (const float*)d_in[3];
    const float* c1b = (const float*)d_in[4];
    const float* c2w = (const float*)d_in[5];
    const float* c2b = (const float*)d_in[6];
    const float* Wih = (const float*)d_in[7];
    const float* Whh = (const float*)d_in[8];
    const float* bih = (const float*)d_in[9];
    const float* bhh = (const float*)d_in[10];
    const float* muw = (const float*)d_in[11];
    const float* mub = (const float*)d_in[12];
    const float* lsw = (const float*)d_in[13];
    const float* lsb = (const float*)d_in[14];

    float* ws     = (float*)d_ws;
    float* seq    = ws + SEQ_OFF;
    float* g      = ws + G_OFF;
    float* hstate = ws + HST_OFF;
    float* whr    = ws + WHR_OFF;
    float* wir    = ws + WIR_OFF;
    float* muwp   = ws + MUWP_OFF;
    float* lswp   = ws + LSWP_OFF;
    float* gic    = ws + GIC_OFF;
    float* outp   = (float*)d_out;

    // chunk size over t, limited by workspace (deterministic given ws_size)
    const long per_t = 387L * 4096;
    long avail = (long)(ws_size / 4) - (long)GIC_OFF;
    int CT = 60;
    if (avail < 60 * per_t) {
        CT = (int)(avail / per_t);
        if (CT < 1) CT = 1;
        if (CT > 60) CT = 60;
    }

    const int prep_elems = 27 * 576 * 4 + 24 * 576 * 4 + 2 * (129 * 260);
    prep_pad<<<(prep_elems + 255) / 256, 256, 0, stream>>>(Whh, Wih, muw, lsw, ws);
    conv_fused<<<dim3(6, BTOT), 256, 0, stream>>>(x, c1w, c1b, c2w, c2b, seq);

    for (int t0 = 0; t0 < 60; t0 += CT) {
        int nt = 60 - t0; if (nt > CT) nt = CT;
        gi_gemm2<<<512, 576, 0, stream>>>(seq, wir, gic, t0, nt);
        gru_rec<<<512, 576, 0, stream>>>(gic, whr, bih, bhh, hstate, g, t0, nt);
    }
    head_kernel<<<BTOT / 16, 256, 0, stream>>>(g, wv, eps, muwp, lswp, mub, lsb, outp);
}

// Round 17
// 2181.918 us; speedup vs baseline: 1.0057x; 1.0057x over previous
//
#include <hip/hip_runtime.h>
#include <math.h>

// Problem constants
#define BTOT   4096
#define CIN    3
#define TIN    64
#define SIN    128

// ws layout (float offsets)
#define SEQ_OFF    0                            // [4096][60][124]
#define G_OFF      (SEQ_OFF + 4096*60*124)      // [4096][129]
#define HST_OFF    (G_OFF + 4096*129)           // [4096][148] h state between chunks
#define WHR_OFF    (HST_OFF + 4096*148)         // [27][576][4] lane-linear Whh
#define WIR_OFF    (WHR_OFF + 27*576*4)         // [24][576][4] lane-linear Wih
#define MUWP_OFF   (WIR_OFF + 24*576*4)         // [129][260]
#define LSWP_OFF   (MUWP_OFF + 129*260)         // [129][260]
#define GIC_OFF    (LSWP_OFF + 129*260)         // [CT][387][4096] gi chunk

// Inline transcendentals (no libm calls in hot loops; ocml calls force
// loop-resident values into callee-saved regs -> spill)
__device__ __forceinline__ float fast_tanh(float x) {
    float ax = fabsf(x);
    float t  = __expf(-2.f * ax);
    float r  = (1.f - t) / (1.f + t);
    return copysignf(r, x);
}
__device__ __forceinline__ float fast_sigmoid(float x) {
    return 1.f / (1.f + __expf(-x));
}

// ---------------------------------------------------------------------------
// Prep: lane-linear weight tables + fc weight padding (see R14/R15 notes).
// ---------------------------------------------------------------------------
__global__ __launch_bounds__(256) void prep_pad(
    const float* __restrict__ Whh, const float* __restrict__ Wih,
    const float* __restrict__ muw, const float* __restrict__ lsw,
    float* __restrict__ ws)
{
    int idx = blockIdx.x * 256 + threadIdx.x;
    const int NH = 27 * 576 * 4;
    const int NI = 24 * 576 * 4;
    const int N2 = 129 * 260;
    if (idx < NH) {
        int m   = idx / 2304;
        int rem = idx - m * 2304;
        int l   = rem >> 2;
        int c   = rem & 3;
        int g   = m / 9;
        int i   = m - g * 9;
        int gq  = (l < 512) ? (l >> 2) : 128;
        int kq  = l & 3;
        int row = g * 129 + gq;
        int col = kq * 36 + i * 4 + c;
        ws[WHR_OFF + idx] = (col < 129) ? Whh[(size_t)row * 129 + col] : 0.f;
    } else if (idx < NH + NI) {
        int i2  = idx - NH;
        int m   = i2 / 2304;
        int rem = i2 - m * 2304;
        int l   = rem >> 2;
        int c   = rem & 3;
        int g   = m / 8;
        int i   = m - g * 8;
        int gq  = (l < 512) ? (l >> 2) : 128;
        int kq  = l & 3;
        int row = g * 129 + gq;
        int col = kq * 32 + i * 4 + c;
        ws[WIR_OFF + i2] = (col < 124) ? Wih[(size_t)row * 124 + col] : 0.f;
    } else if (idx < NH + NI + N2) {
        int i = idx - NH - NI; int j = i / 260, k = i - j * 260;
        ws[MUWP_OFF + i] = (k < 258) ? muw[j * 258 + k] : 0.f;
    } else if (idx < NH + NI + 2 * N2) {
        int i = idx - NH - NI - N2; int j = i / 260, k = i - j * 260;
        ws[LSWP_OFF + i] = (k < 258) ? lsw[j * 258 + k] : 0.f;
    }
}

// ---------------------------------------------------------------------------
// Fused conv1+conv2 v2 (register-blocked, weight-resident) — passing R13.
// ---------------------------------------------------------------------------
#define C1SEG(c_, kt_, W0_, W1_, W2_) { \
    const float* rp_ = xt + ((c_) * 14 + tq + (kt_)) * 128 + s0; \
    float4 v4_ = *(const float4*)rp_; \
    float2 v2_ = *(const float2*)(rp_ + 4); \
    acc0 += v4_.x*(W0_) + v4_.y*(W1_) + v4_.z*(W2_); \
    acc1 += v4_.y*(W0_) + v4_.z*(W1_) + v4_.w*(W2_); \
    acc2 += v4_.z*(W0_) + v4_.w*(W1_) + v2_.x*(W2_); \
    acc3 += v4_.w*(W0_) + v2_.x*(W1_) + v2_.y*(W2_); }

#define C2SEG(o_, kt_, W0_, W1_, W2_) { \
    const float* rp_ = h1t + ((o_) * 12 + tq + (kt_)) * 128 + s0; \
    float4 v4_ = *(const float4*)rp_; \
    float2 v2_ = *(const float2*)(rp_ + 4); \
    acc0 += v4_.x*(W0_) + v4_.y*(W1_) + v4_.z*(W2_); \
    acc1 += v4_.y*(W0_) + v4_.z*(W1_) + v4_.w*(W2_); \
    acc2 += v4_.z*(W0_) + v4_.w*(W1_) + v2_.x*(W2_); \
    acc3 += v4_.w*(W0_) + v2_.x*(W1_) + v2_.y*(W2_); }

__global__ __launch_bounds__(256) void conv_fused(
    const float* __restrict__ x,
    const float* __restrict__ w1, const float* __restrict__ b1,
    const float* __restrict__ w2, const float* __restrict__ b2,
    float* __restrict__ seq)
{
    __shared__ __attribute__((aligned(16))) float xt[3 * 14 * 128 + 8];
    __shared__ __attribute__((aligned(16))) float h1t[6 * 12 * 128];
    __shared__ float w1s[162];
    __shared__ float w2s[54];
    __shared__ float b1s[6];
    __shared__ float b2s;

    const int tid  = threadIdx.x;
    const int tile = blockIdx.x;   // 0..5
    const int bb   = blockIdx.y;   // batch
    const int T0   = tile * 10;

    if (tid < 162)                  w1s[tid] = w1[tid];
    if (tid >= 192 && tid < 246)    w2s[tid - 192] = w2[tid - 192];
    if (tid >= 248 && tid < 254)    b1s[tid - 248] = b1[tid - 248];
    if (tid == 255)                 b2s = b2[0];

    // stage x tile: 42 rows x 32 float4 (coalesced)
    {
        const float* xb = x + (size_t)bb * CIN * TIN * SIN;
        for (int i = tid; i < 3 * 14 * 32; i += 256) {
            int c   = i / (14 * 32);
            int rem = i - c * (14 * 32);
            int t   = rem >> 5;
            int k4  = rem & 31;
            ((float4*)(xt + (c * 14 + t) * 128))[k4] =
                *(const float4*)(xb + ((size_t)(c * TIN + T0 + t)) * SIN + k4 * 4);
        }
    }
    __syncthreads();

    // ---- conv1 + leaky: tid<192, thread = (o, 4-col group), 12 t-rows ----
    if (tid < 192) {
        const int o  = tid >> 5;
        const int s0 = (tid & 31) * 4;
        const float* wb = w1s + o * 27;
        float w000 = wb[0],  w001 = wb[1],  w002 = wb[2];
        float w010 = wb[3],  w011 = wb[4],  w012 = wb[5];
        float w020 = wb[6],  w021 = wb[7],  w022 = wb[8];
        float w100 = wb[9],  w101 = wb[10], w102 = wb[11];
        float w110 = wb[12], w111 = wb[13], w112 = wb[14];
        float w120 = wb[15], w121 = wb[16], w122 = wb[17];
        float w200 = wb[18], w201 = wb[19], w202 = wb[20];
        float w210 = wb[21], w211 = wb[22], w212 = wb[23];
        float w220 = wb[24], w221 = wb[25], w222 = wb[26];
        float bo = b1s[o];
        for (int tq = 0; tq < 12; ++tq) {
            float acc0 = bo, acc1 = bo, acc2 = bo, acc3 = bo;
            C1SEG(0, 0, w000, w001, w002)
            C1SEG(0, 1, w010, w011, w012)
            C1SEG(0, 2, w020, w021, w022)
            C1SEG(1, 0, w100, w101, w102)
            C1SEG(1, 1, w110, w111, w112)
            C1SEG(1, 2, w120, w121, w122)
            C1SEG(2, 0, w200, w201, w202)
            C1SEG(2, 1, w210, w211, w212)
            C1SEG(2, 2, w220, w221, w222)
            float4 r;
            r.x = (acc0 >= 0.f) ? acc0 : 0.01f * acc0;
            r.y = (acc1 >= 0.f) ? acc1 : 0.01f * acc1;
            r.z = (acc2 >= 0.f) ? acc2 : 0.01f * acc2;
            r.w = (acc3 >= 0.f) ? acc3 : 0.01f * acc3;
            *(float4*)(h1t + (o * 12 + tq) * 128 + s0) = r;
        }
    }
    __syncthreads();

    // ---- conv2 + leaky: 310 tasks = (t in [0,10), sg in [0,31)) ----
    {
        float u000 = w2s[0],  u001 = w2s[1],  u002 = w2s[2];
        float u010 = w2s[3],  u011 = w2s[4],  u012 = w2s[5];
        float u020 = w2s[6],  u021 = w2s[7],  u022 = w2s[8];
        float u100 = w2s[9],  u101 = w2s[10], u102 = w2s[11];
        float u110 = w2s[12], u111 = w2s[13], u112 = w2s[14];
        float u120 = w2s[15], u121 = w2s[16], u122 = w2s[17];
        float u200 = w2s[18], u201 = w2s[19], u202 = w2s[20];
        float u210 = w2s[21], u211 = w2s[22], u212 = w2s[23];
        float u220 = w2s[24], u221 = w2s[25], u222 = w2s[26];
        float u300 = w2s[27], u301 = w2s[28], u302 = w2s[29];
        float u310 = w2s[30], u311 = w2s[31], u312 = w2s[32];
        float u320 = w2s[33], u321 = w2s[34], u322 = w2s[35];
        float u400 = w2s[36], u401 = w2s[37], u402 = w2s[38];
        float u410 = w2s[39], u411 = w2s[40], u412 = w2s[41];
        float u420 = w2s[42], u421 = w2s[43], u422 = w2s[44];
        float u500 = w2s[45], u501 = w2s[46], u502 = w2s[47];
        float u510 = w2s[48], u511 = w2s[49], u512 = w2s[50];
        float u520 = w2s[51], u521 = w2s[52], u522 = w2s[53];
        float bo2 = b2s;
        for (int idx = tid; idx < 310; idx += 256) {
            const int tq = idx / 31;
            const int s0 = (idx - tq * 31) * 4;
            float acc0 = bo2, acc1 = bo2, acc2 = bo2, acc3 = bo2;
            C2SEG(0, 0, u000, u001, u002)
            C2SEG(0, 1, u010, u011, u012)
            C2SEG(0, 2, u020, u021, u022)
            C2SEG(1, 0, u100, u101, u102)
            C2SEG(1, 1, u110, u111, u112)
            C2SEG(1, 2, u120, u121, u122)
            C2SEG(2, 0, u200, u201, u202)
            C2SEG(2, 1, u210, u211, u212)
            C2SEG(2, 2, u220, u221, u222)
            C2SEG(3, 0, u300, u301, u302)
            C2SEG(3, 1, u310, u311, u312)
            C2SEG(3, 2, u320, u321, u322)
            C2SEG(4, 0, u400, u401, u402)
            C2SEG(4, 1, u410, u411, u412)
            C2SEG(4, 2, u420, u421, u422)
            C2SEG(5, 0, u500, u501, u502)
            C2SEG(5, 1, u510, u511, u512)
            C2SEG(5, 2, u520, u521, u522)
            float4 r;
            r.x = (acc0 >= 0.f) ? acc0 : 0.01f * acc0;
            r.y = (acc1 >= 0.f) ? acc1 : 0.01f * acc1;
            r.z = (acc2 >= 0.f) ? acc2 : 0.01f * acc2;
            r.w = (acc3 >= 0.f) ? acc3 : 0.01f * acc3;
            *(float4*)(seq + ((size_t)bb * 60 + T0 + tq) * 124 + s0) = r;
        }
    }
}

// ---------------------------------------------------------------------------
// Shared macro kit (R10 lesson: macro params must not be named x/y/z/w)
// ---------------------------------------------------------------------------
#define D4(acc_, hv4_, wv4_) acc_ += (hv4_).x*(wv4_).x + (hv4_).y*(wv4_).y + (hv4_).z*(wv4_).z + (hv4_).w*(wv4_).w;
#define RED(acc_) { acc_ += __shfl_xor(acc_, 1, 64); acc_ += __shfl_xor(acc_, 2, 64); }

// ---------------------------------------------------------------------------
// gi GEMM v5: 8 rows/block x 512 blocks; xs2 row = 4 chunks x 36 floats
// (32 data + 4 pad), stride 144. R16 lesson: kq*32-float offsets hit the
// SAME 4 banks for all kq (128 B = 32 banks) -> structural 4-way conflict
// on every ds_read_b128 (7.7e7 conflict cycles). kq*36 shifts banks by 4
// per kq -> conflict-free (same layout trick as gru's hs2).
// ---------------------------------------------------------------------------
#define GI_ROW(R, aA, aB, aC) { \
    const float4* hv_ = (const float4*)(xs2 + (R) * 144) + kqo9; \
    float4 h4_; \
    h4_ = hv_[0]; D4(aA, h4_, Va0) D4(aB, h4_, Vb0) D4(aC, h4_, Vc0) \
    h4_ = hv_[1]; D4(aA, h4_, Va1) D4(aB, h4_, Vb1) D4(aC, h4_, Vc1) \
    h4_ = hv_[2]; D4(aA, h4_, Va2) D4(aB, h4_, Vb2) D4(aC, h4_, Vc2) \
    h4_ = hv_[3]; D4(aA, h4_, Va3) D4(aB, h4_, Vb3) D4(aC, h4_, Vc3) \
    h4_ = hv_[4]; D4(aA, h4_, Va4) D4(aB, h4_, Vb4) D4(aC, h4_, Vc4) \
    h4_ = hv_[5]; D4(aA, h4_, Va5) D4(aB, h4_, Vb5) D4(aC, h4_, Vc5) \
    h4_ = hv_[6]; D4(aA, h4_, Va6) D4(aB, h4_, Vb6) D4(aC, h4_, Vc6) \
    h4_ = hv_[7]; D4(aA, h4_, Va7) D4(aB, h4_, Vb7) D4(aC, h4_, Vc7) }

#define GI_CHUNK(R0) { \
    float aA0 = 0.f, aB0 = 0.f, aC0 = 0.f, aA1 = 0.f, aB1 = 0.f, aC1 = 0.f; \
    float aA2 = 0.f, aB2 = 0.f, aC2 = 0.f, aA3 = 0.f, aB3 = 0.f, aC3 = 0.f; \
    GI_ROW((R0) + 0, aA0, aB0, aC0) \
    GI_ROW((R0) + 1, aA1, aB1, aC1) \
    GI_ROW((R0) + 2, aA2, aB2, aC2) \
    GI_ROW((R0) + 3, aA3, aB3, aC3) \
    RED(aA0) RED(aB0) RED(aC0) RED(aA1) RED(aB1) RED(aC1) \
    RED(aA2) RED(aB2) RED(aC2) RED(aA3) RED(aB3) RED(aC3) \
    float sA = (kq == 0) ? aA0 : (kq == 1) ? aA1 : (kq == 2) ? aA2 : aA3; \
    float sB = (kq == 0) ? aB0 : (kq == 1) ? aB1 : (kq == 2) ? aB2 : aB3; \
    float sC = (kq == 0) ? aC0 : (kq == 1) ? aC1 : (kq == 2) ? aC2 : aC3; \
    int rw_ = (R0) + kq; \
    GIb[rw_ * 389 + gq]       = sA; \
    GIb[rw_ * 389 + 129 + gq] = sB; \
    GIb[rw_ * 389 + 258 + gq] = sC; }

__global__ __launch_bounds__(576)
void gi_gemm2(
    const float* __restrict__ seq, const float* __restrict__ wir,  // [24][576][4]
    float* __restrict__ gic, int t0, int nt)
{
    __shared__ __attribute__((aligned(16))) float xs2[8 * 144];  // 4 chunks x 36
    __shared__ float GIb[8 * 389];

    const int tid    = threadIdx.x;
    const int kq     = tid & 3;
    const int kqo9   = kq * 9;           // f4 offset: kq*36 floats (bank-shift 4)
    const int b0     = blockIdx.x * 8;
    const bool isMain = (tid < 512);
    const int gq     = isMain ? (tid >> 2) : 0;      // [0,128)
    const int rsp8   = ((tid - 512) >> 2) & 7;       // special wave row (x2 dup)

    // lane-linear coalesced weight loads (L2-resident table)
    const float4* wir4 = (const float4*)wir;
    float4 Va0 = wir4[0*576+tid],  Va1 = wir4[1*576+tid],
           Va2 = wir4[2*576+tid],  Va3 = wir4[3*576+tid],
           Va4 = wir4[4*576+tid],  Va5 = wir4[5*576+tid],
           Va6 = wir4[6*576+tid],  Va7 = wir4[7*576+tid];
    float4 Vb0 = wir4[8*576+tid],  Vb1 = wir4[9*576+tid],
           Vb2 = wir4[10*576+tid], Vb3 = wir4[11*576+tid],
           Vb4 = wir4[12*576+tid], Vb5 = wir4[13*576+tid],
           Vb6 = wir4[14*576+tid], Vb7 = wir4[15*576+tid];
    float4 Vc0 = wir4[16*576+tid], Vc1 = wir4[17*576+tid],
           Vc2 = wir4[18*576+tid], Vc3 = wir4[19*576+tid],
           Vc4 = wir4[20*576+tid], Vc5 = wir4[21*576+tid],
           Vc6 = wir4[22*576+tid], Vc7 = wir4[23*576+tid];

    // zero the k-pad: data floats 124..127 live at chunk 3, pos 28..31
    if (tid < 32) xs2[(tid >> 2) * 144 + 3 * 36 + 28 + (tid & 3)] = 0.f;

    const int sr = tid / 31;             // row 0..7 (tid<248)
    const int sk = tid - sr * 31;        // f4 0..30
    const int sc = sk >> 3;              // chunk 0..3
    const int sp = sk & 7;               // pos in chunk

    for (int tt = 0; tt < nt; ++tt) {
        if (tid < 248) {
            const float4* srcf4 =
                (const float4*)(seq + ((size_t)(b0 + sr) * 60 + (t0 + tt)) * 124);
            ((float4*)(xs2 + sr * 144 + sc * 36))[sp] = srcf4[sk];
        }
        __syncthreads();

        if (isMain) {
            GI_CHUNK(0)
            GI_CHUNK(4)
        } else {
            #pragma unroll
            for (int rr = 0; rr < 8; ++rr) {
                float aA = 0.f, aB = 0.f, aC = 0.f;
                GI_ROW(rr, aA, aB, aC)
                RED(aA) RED(aB) RED(aC)
                if (rr == rsp8 && kq == 0) {
                    GIb[rr * 389 + 128] = aA;
                    GIb[rr * 389 + 257] = aB;
                    GIb[rr * 389 + 386] = aC;
                }
            }
        }
        __syncthreads();

        {
            float* gout = gic + (size_t)tt * 387 * 4096 + b0;
            for (int e = tid; e < 3096; e += 576) {
                int r = e & 7;
                int j = e >> 3;
                gout[(size_t)j * 4096 + r] = GIb[r * 389 + j];
            }
        }
        __syncthreads();
    }
}

// ---------------------------------------------------------------------------
// GRU recurrence v6: 8 rows/block x 512 blocks (2 blocks/CU) — passing R16.
// ---------------------------------------------------------------------------
#define GH_ROW(R, aA, aB, aC) { \
    const float4* hv_ = (const float4*)(hs2 + (R) * 148) + kqo; \
    float4 h4_; \
    h4_ = hv_[0]; D4(aA, h4_, Wa0) D4(aB, h4_, Wb0) D4(aC, h4_, Wc0) \
    h4_ = hv_[1]; D4(aA, h4_, Wa1) D4(aB, h4_, Wb1) D4(aC, h4_, Wc1) \
    h4_ = hv_[2]; D4(aA, h4_, Wa2) D4(aB, h4_, Wb2) D4(aC, h4_, Wc2) \
    h4_ = hv_[3]; D4(aA, h4_, Wa3) D4(aB, h4_, Wb3) D4(aC, h4_, Wc3) \
    h4_ = hv_[4]; D4(aA, h4_, Wa4) D4(aB, h4_, Wb4) D4(aC, h4_, Wc4) \
    h4_ = hv_[5]; D4(aA, h4_, Wa5) D4(aB, h4_, Wb5) D4(aC, h4_, Wc5) \
    h4_ = hv_[6]; D4(aA, h4_, Wa6) D4(aB, h4_, Wb6) D4(aC, h4_, Wc6) \
    h4_ = hv_[7]; D4(aA, h4_, Wa7) D4(aB, h4_, Wb7) D4(aC, h4_, Wc7) \
    h4_ = hv_[8]; D4(aA, h4_, Wa8) D4(aB, h4_, Wb8) D4(aC, h4_, Wc8) }

#define CHUNK(R0) { \
    float aA0 = 0.f, aB0 = 0.f, aC0 = 0.f, aA1 = 0.f, aB1 = 0.f, aC1 = 0.f; \
    float aA2 = 0.f, aB2 = 0.f, aC2 = 0.f, aA3 = 0.f, aB3 = 0.f, aC3 = 0.f; \
    GH_ROW((R0) + 0, aA0, aB0, aC0) \
    GH_ROW((R0) + 1, aA1, aB1, aC1) \
    GH_ROW((R0) + 2, aA2, aB2, aC2) \
    GH_ROW((R0) + 3, aA3, aB3, aC3) \
    RED(aA0) RED(aB0) RED(aC0) RED(aA1) RED(aB1) RED(aC1) \
    RED(aA2) RED(aB2) RED(aC2) RED(aA3) RED(aB3) RED(aC3) \
    float sA = (kq == 0) ? aA0 : (kq == 1) ? aA1 : (kq == 2) ? aA2 : aA3; \
    float sB = (kq == 0) ? aB0 : (kq == 1) ? aB1 : (kq == 2) ? aB2 : aB3; \
    float sC = (kq == 0) ? aC0 : (kq == 1) ? aC1 : (kq == 2) ? aC2 : aC3; \
    int rw_ = (R0) + kq; \
    GHb[rw_ * 388 + gq]       = sA; \
    GHb[rw_ * 388 + 129 + gq] = sB; \
    GHb[rw_ * 388 + 258 + gq] = sC; }

#define APPLY(E, PGA, PGB, PGC) { \
    int r_ = (E) & 7, j_ = (E) >> 3; \
    float pr_  = (PGA) + GHb[r_ * 388 + j_]       + bihS[j_]       + bhhS[j_]; \
    float pz_  = (PGB) + GHb[r_ * 388 + 129 + j_] + bihS[129 + j_] + bhhS[129 + j_]; \
    float gin_ = (PGC) + bihS[258 + j_]; \
    float ghn_ = GHb[r_ * 388 + 258 + j_] + bhhS[258 + j_]; \
    float rg_ = fast_sigmoid(pr_); \
    float zg_ = fast_sigmoid(pz_); \
    float nn_ = fast_tanh(gin_ + rg_ * ghn_); \
    hs2[r_ * 148 + j_] = (1.f - zg_) * nn_ + zg_ * hs2[r_ * 148 + j_]; }

__global__ __launch_bounds__(576)
void gru_rec(
    const float* __restrict__ gic, const float* __restrict__ whr,  // [27][576][4]
    const float* __restrict__ bih, const float* __restrict__ bhh,
    float* __restrict__ hstate, float* __restrict__ g_out,
    int t0, int nt)
{
    __shared__ __attribute__((aligned(16))) float hs2[8 * 148];  // stride 148
    __shared__ float GHb[8 * 388];
    __shared__ float bihS[387];
    __shared__ float bhhS[387];

    const int tid    = threadIdx.x;
    const int kq     = tid & 3;
    const int kqo    = kq * 9;           // f4 offset into a 36-float k-chunk
    const int b0     = blockIdx.x * 8;
    const bool isMain = (tid < 512);
    const int gq     = isMain ? (tid >> 2) : 0;      // [0,128)
    const int rsp8   = ((tid - 512) >> 2) & 7;       // special wave row (x2 dup)

    // lane-linear coalesced weight loads (L2-resident table)
    const float4* whr4 = (const float4*)whr;
    float4 Wa0 = whr4[0*576+tid],  Wa1 = whr4[1*576+tid],
           Wa2 = whr4[2*576+tid],  Wa3 = whr4[3*576+tid],
           Wa4 = whr4[4*576+tid],  Wa5 = whr4[5*576+tid],
           Wa6 = whr4[6*576+tid],  Wa7 = whr4[7*576+tid],
           Wa8 = whr4[8*576+tid];
    float4 Wb0 = whr4[9*576+tid],  Wb1 = whr4[10*576+tid],
           Wb2 = whr4[11*576+tid], Wb3 = whr4[12*576+tid],
           Wb4 = whr4[13*576+tid], Wb5 = whr4[14*576+tid],
           Wb6 = whr4[15*576+tid], Wb7 = whr4[16*576+tid],
           Wb8 = whr4[17*576+tid];
    float4 Wc0 = whr4[18*576+tid], Wc1 = whr4[19*576+tid],
           Wc2 = whr4[20*576+tid], Wc3 = whr4[21*576+tid],
           Wc4 = whr4[22*576+tid], Wc5 = whr4[23*576+tid],
           Wc6 = whr4[24*576+tid], Wc7 = whr4[25*576+tid],
           Wc8 = whr4[26*576+tid];

    if (tid < 387) { bihS[tid] = bih[tid]; bhhS[tid] = bhh[tid]; }
    if (t0 == 0) {
        for (int e = tid; e < 8 * 148; e += 576) hs2[e] = 0.f;
    } else {
        for (int e = tid; e < 8 * 148; e += 576) hs2[e] = hstate[(size_t)b0 * 148 + e];
    }
    __syncthreads();

    const int e0 = tid, e1 = tid + 576;   // gate elems: 8*129 = 1032

    for (int tt = 0; tt < nt; ++tt) {
        const float* gib = gic + (size_t)tt * 387 * 4096 + b0;
        float pa0, pb0, pc0;
        float pa1 = 0.f, pb1 = 0.f, pc1 = 0.f;
        {
            int r = e0 & 7, j = e0 >> 3;
            if (e0 < 1032) {
                pa0 = gib[(size_t)j * 4096 + r];
                pb0 = gib[(size_t)(129 + j) * 4096 + r];
                pc0 = gib[(size_t)(258 + j) * 4096 + r];
            } else { pa0 = pb0 = pc0 = 0.f; }
            if (e1 < 1032) {
                r = e1 & 7; j = e1 >> 3;
                pa1 = gib[(size_t)j * 4096 + r];
                pb1 = gib[(size_t)(129 + j) * 4096 + r];
                pc1 = gib[(size_t)(258 + j) * 4096 + r];
            }
        }

        if (isMain) {
            CHUNK(0)
            CHUNK(4)
        } else {
            float aA = 0.f, aB = 0.f, aC = 0.f;
            GH_ROW(rsp8, aA, aB, aC)
            RED(aA) RED(aB) RED(aC)
            if (kq == 0) {
                GHb[rsp8 * 388 + 128] = aA;
                GHb[rsp8 * 388 + 257] = aB;
                GHb[rsp8 * 388 + 386] = aC;
            }
        }
        __syncthreads();

        if (e0 < 1032) { APPLY(e0, pa0, pb0, pc0) }
        if (e1 < 1032) { APPLY(e1, pa1, pb1, pc1) }
        __syncthreads();
    }

    for (int e = tid; e < 8 * 148; e += 576) hstate[(size_t)b0 * 148 + e] = hs2[e];
    if (t0 + nt >= 60) {
        if (e0 < 1032) { int r = e0 & 7, j = e0 >> 3; float v = hs2[r * 148 + j];
            g_out[(size_t)(b0 + r) * 129 + j] = (v >= 0.f) ? v : 0.01f * v; }
        if (e1 < 1032) { int r = e1 & 7, j = e1 >> 3; float v = hs2[r * 148 + j];
            g_out[(size_t)(b0 + r) * 129 + j] = (v >= 0.f) ? v : 0.01f * v; }
    }
}

// ---------------------------------------------------------------------------
// Head: feat=[g,w] (258) -> mu, log_std -> sample, tanh, log_pi, normalize.
// ---------------------------------------------------------------------------
__global__ __launch_bounds__(256) void head_kernel(
    const float* __restrict__ gbuf, const float* __restrict__ wvec,
    const float* __restrict__ eps,
    const float* __restrict__ muwp, const float* __restrict__ lswp,
    const float* __restrict__ mub,  const float* __restrict__ lsb,
    float* __restrict__ out)
{
    __shared__ __attribute__((aligned(16))) float feat[16 * 260];
    __shared__ float PA[16 * 130];
    __shared__ float TERM[16 * 130];
    __shared__ float ROWSUM[16];
    __shared__ float ROWLOG[16];

    const int tid = threadIdx.x;
    const int b0  = blockIdx.x * 16;

    for (int i = tid; i < 16 * 260; i += 256) {
        int r = i / 260;
        int k = i - r * 260;
        float v = 0.f;
        if (k < 129)       v = gbuf[(size_t)(b0 + r) * 129 + k];
        else if (k < 258)  v = wvec[(size_t)(b0 + r) * 129 + (k - 129)];
        feat[i] = v;
    }
    __syncthreads();

    for (int idx = tid; idx < 16 * 129; idx += 256) {
        int r = idx & 15;
        int j = idx >> 4;
        const float4* fv = (const float4*)(feat + r * 260);
        const float4* mw = (const float4*)(muwp + (size_t)j * 260);
        const float4* lw = (const float4*)(lswp + (size_t)j * 260);
        float am = 0.f, al = 0.f;
        for (int k = 0; k < 65; ++k) {
            float4 f = fv[k];
            float4 m = mw[k];
            float4 l = lw[k];
            am += f.x * m.x + f.y * m.y + f.z * m.z + f.w * m.w;
            al += f.x * l.x + f.y * l.y + f.z * l.z + f.w * l.w;
        }
        float mu = am + mub[j];
        float ls = fminf(fmaxf(al + lsb[j], -20.f), 2.f);
        float sd = __expf(ls);
        float e  = eps[(size_t)(b0 + r) * 129 + j];
        float xv = mu + sd * e;
        float pa = fast_tanh(xv);
        float tt = (xv - mu) / sd;
        float term = -0.5f * tt * tt - ls - 0.91893853320467274f
                     - __logf(1.f - pa * pa + 1e-6f);
        PA[r * 130 + j]   = pa;
        TERM[r * 130 + j] = term;
    }
    __syncthreads();

    {
        int r = tid >> 4;
        int i = tid & 15;
        float sp = 0.f, st = 0.f;
        for (int j = i; j < 129; j += 16) {
            sp += PA[r * 130 + j];
            st += TERM[r * 130 + j];
        }
        for (int off = 8; off > 0; off >>= 1) {
            sp += __shfl_down(sp, off, 16);
            st += __shfl_down(st, off, 16);
        }
        if (i == 0) { ROWSUM[r] = sp + 129.f; ROWLOG[r] = st; }
    }
    __syncthreads();

    for (int idx = tid; idx < 16 * 129; idx += 256) {
        int r = idx & 15;
        int j = idx >> 4;
        out[(size_t)(b0 + r) * 129 + j] = (PA[r * 130 + j] + 1.f) / ROWSUM[r];
    }
    if (tid < 16)
        out[(size_t)4096 * 129 + b0 + tid] = ROWLOG[tid];
}

// ---------------------------------------------------------------------------
extern "C" void kernel_launch(void* const* d_in, const int* in_sizes, int n_in,
                              void* d_out, int out_size, void* d_ws, size_t ws_size,
                              hipStream_t stream)
{
    const float* x   = (const float*)d_in[0];
    const float* wv  = (const float*)d_in[1];
    const float* eps = (const float*)d_in[2];
    const float* c1w = (const float*)d_in[3];
    const float* c1b = (const float*)d_in[4];
    const float* c2w = (const float*)d_in[5];
    const float* c2b = (const float*)d_in[6];
    const float* Wih = (const float*)d_in[7];
    const float* Whh = (const float*)d_in[8];
    const float* bih = (const float*)d_in[9];
    const float* bhh = (const float*)d_in[10];
    const float* muw = (const float*)d_in[11];
    const float* mub = (const float*)d_in[12];
    const float* lsw = (const float*)d_in[13];
    const float* lsb = (const float*)d_in[14];

    float* ws     = (float*)d_ws;
    float* seq    = ws + SEQ_OFF;
    float* g      = ws + G_OFF;
    float* hstate = ws + HST_OFF;
    float* whr    = ws + WHR_OFF;
    float* wir    = ws + WIR_OFF;
    float* muwp   = ws + MUWP_OFF;
    float* lswp   = ws + LSWP_OFF;
    float* gic    = ws + GIC_OFF;
    float* outp   = (float*)d_out;

    // chunk size over t, limited by workspace (deterministic given ws_size)
    const long per_t = 387L * 4096;
    long avail = (long)(ws_size / 4) - (long)GIC_OFF;
    int CT = 60;
    if (avail < 60 * per_t) {
        CT = (int)(avail / per_t);
        if (CT < 1) CT = 1;
        if (CT > 60) CT = 60;
    }

    const int prep_elems = 27 * 576 * 4 + 24 * 576 * 4 + 2 * (129 * 260);
    prep_pad<<<(prep_elems + 255) / 256, 256, 0, stream>>>(Whh, Wih, muw, lsw, ws);
    conv_fused<<<dim3(6, BTOT), 256, 0, stream>>>(x, c1w, c1b, c2w, c2b, seq);

    for (int t0 = 0; t0 < 60; t0 += CT) {
        int nt = 60 - t0; if (nt > CT) nt = CT;
        gi_gemm2<<<512, 576, 0, stream>>>(seq, wir, gic, t0, nt);
        gru_rec<<<512, 576, 0, stream>>>(gic, whr, bih, bhh, hstate, g, t0, nt);
    }
    head_kernel<<<BTOT / 16, 256, 0, stream>>>(g, wv, eps, muwp, lswp, mub, lsb, outp);
}

// Round 18
// 2166.348 us; speedup vs baseline: 1.0130x; 1.0072x over previous
//
#include <hip/hip_runtime.h>
#include <math.h>

// Problem constants
#define BTOT   4096
#define CIN    3
#define TIN    64
#define SIN    128

// ws layout (float offsets)
#define SEQ_OFF    0                            // [4096][60][124]
#define G_OFF      (SEQ_OFF + 4096*60*124)      // [4096][129]
#define HST_OFF    (G_OFF + 4096*129)           // [4096][148] h state between chunks
#define WHR_OFF    (HST_OFF + 4096*148)         // [27][576][4] lane-linear Whh
#define AWIH_OFF   (WHR_OFF + 27*576*4)         // [25][4][2][64][8] bf16 Wih frags (102400 shorts = 51200 float slots)
#define MUWP_OFF   (AWIH_OFF + 51200)           // [129][260]
#define LSWP_OFF   (MUWP_OFF + 129*260)         // [129][260]
#define GIC_OFF    (LSWP_OFF + 129*260)         // [CT][387][4096] gi chunk

typedef __attribute__((ext_vector_type(8))) short bf16x8;
typedef __attribute__((ext_vector_type(4))) float f32x4;

// Inline transcendentals (no libm calls in hot loops)
__device__ __forceinline__ float fast_tanh(float x) {
    float ax = fabsf(x);
    float t  = __expf(-2.f * ax);
    float r  = (1.f - t) / (1.f + t);
    return copysignf(r, x);
}
__device__ __forceinline__ float fast_sigmoid(float x) {
    return 1.f / (1.f + __expf(-x));
}
// bf16 round-to-nearest-even helpers (bit ops only)
__device__ __forceinline__ unsigned short f2bf(float x) {
    unsigned int u = __float_as_uint(x);
    unsigned int r = u + 0x7FFFu + ((u >> 16) & 1u);
    return (unsigned short)(r >> 16);
}
__device__ __forceinline__ float bf2f(unsigned short b) {
    return __uint_as_float(((unsigned int)b) << 16);
}

// ---------------------------------------------------------------------------
// Prep: lane-linear Whh table, bf16 hi/lo Wih MFMA-fragment table, fc pads.
// AWIH layout (shorts): idx = jt*4096 + kt*1024 + half*512 + l*8 + c
//   lane l of a wave holds A[j = jt*16 + (l&15)][k = kt*32 + (l>>4)*8 + c]
//   half 0 = bf16(x) ; half 1 = bf16(x - f32(bf16(x)))   (split precision)
// ---------------------------------------------------------------------------
__global__ __launch_bounds__(256) void prep_pad(
    const float* __restrict__ Whh, const float* __restrict__ Wih,
    const float* __restrict__ muw, const float* __restrict__ lsw,
    float* __restrict__ ws)
{
    int idx = blockIdx.x * 256 + threadIdx.x;
    const int NH = 27 * 576 * 4;     // floats
    const int NA = 25 * 4096;        // shorts (102400)
    const int N2 = 129 * 260;
    if (idx < NH) {
        int m   = idx / 2304;
        int rem = idx - m * 2304;
        int l   = rem >> 2;
        int c   = rem & 3;
        int g   = m / 9;
        int i   = m - g * 9;
        int gq  = (l < 512) ? (l >> 2) : 128;
        int kq  = l & 3;
        int row = g * 129 + gq;
        int col = kq * 36 + i * 4 + c;
        ws[WHR_OFF + idx] = (col < 129) ? Whh[(size_t)row * 129 + col] : 0.f;
    } else if (idx < NH + NA) {
        int a    = idx - NH;
        int c    = a & 7;
        int l    = (a >> 3) & 63;
        int half = (a >> 9) & 1;
        int kt   = (a >> 10) & 3;
        int jt   = a >> 12;
        int j    = jt * 16 + (l & 15);
        int k    = kt * 32 + (l >> 4) * 8 + c;
        float v  = (j < 387 && k < 124) ? Wih[(size_t)j * 124 + k] : 0.f;
        unsigned short hb = f2bf(v);
        unsigned short outb = (half == 0) ? hb : f2bf(v - bf2f(hb));
        ((short*)(ws + AWIH_OFF))[a] = (short)outb;
    } else if (idx < NH + NA + N2) {
        int i = idx - NH - NA; int j = i / 260, k = i - j * 260;
        ws[MUWP_OFF + i] = (k < 258) ? muw[j * 258 + k] : 0.f;
    } else if (idx < NH + NA + 2 * N2) {
        int i = idx - NH - NA - N2; int j = i / 260, k = i - j * 260;
        ws[LSWP_OFF + i] = (k < 258) ? lsw[j * 258 + k] : 0.f;
    }
}

// ---------------------------------------------------------------------------
// Fused conv1+conv2 v2 (register-blocked, weight-resident) — passing R13.
// ---------------------------------------------------------------------------
#define C1SEG(c_, kt_, W0_, W1_, W2_) { \
    const float* rp_ = xt + ((c_) * 14 + tq + (kt_)) * 128 + s0; \
    float4 v4_ = *(const float4*)rp_; \
    float2 v2_ = *(const float2*)(rp_ + 4); \
    acc0 += v4_.x*(W0_) + v4_.y*(W1_) + v4_.z*(W2_); \
    acc1 += v4_.y*(W0_) + v4_.z*(W1_) + v4_.w*(W2_); \
    acc2 += v4_.z*(W0_) + v4_.w*(W1_) + v2_.x*(W2_); \
    acc3 += v4_.w*(W0_) + v2_.x*(W1_) + v2_.y*(W2_); }

#define C2SEG(o_, kt_, W0_, W1_, W2_) { \
    const float* rp_ = h1t + ((o_) * 12 + tq + (kt_)) * 128 + s0; \
    float4 v4_ = *(const float4*)rp_; \
    float2 v2_ = *(const float2*)(rp_ + 4); \
    acc0 += v4_.x*(W0_) + v4_.y*(W1_) + v4_.z*(W2_); \
    acc1 += v4_.y*(W0_) + v4_.z*(W1_) + v4_.w*(W2_); \
    acc2 += v4_.z*(W0_) + v4_.w*(W1_) + v2_.x*(W2_); \
    acc3 += v4_.w*(W0_) + v2_.x*(W1_) + v2_.y*(W2_); }

__global__ __launch_bounds__(256) void conv_fused(
    const float* __restrict__ x,
    const float* __restrict__ w1, const float* __restrict__ b1,
    const float* __restrict__ w2, const float* __restrict__ b2,
    float* __restrict__ seq)
{
    __shared__ __attribute__((aligned(16))) float xt[3 * 14 * 128 + 8];
    __shared__ __attribute__((aligned(16))) float h1t[6 * 12 * 128];
    __shared__ float w1s[162];
    __shared__ float w2s[54];
    __shared__ float b1s[6];
    __shared__ float b2s;

    const int tid  = threadIdx.x;
    const int tile = blockIdx.x;   // 0..5
    const int bb   = blockIdx.y;   // batch
    const int T0   = tile * 10;

    if (tid < 162)                  w1s[tid] = w1[tid];
    if (tid >= 192 && tid < 246)    w2s[tid - 192] = w2[tid - 192];
    if (tid >= 248 && tid < 254)    b1s[tid - 248] = b1[tid - 248];
    if (tid == 255)                 b2s = b2[0];

    {
        const float* xb = x + (size_t)bb * CIN * TIN * SIN;
        for (int i = tid; i < 3 * 14 * 32; i += 256) {
            int c   = i / (14 * 32);
            int rem = i - c * (14 * 32);
            int t   = rem >> 5;
            int k4  = rem & 31;
            ((float4*)(xt + (c * 14 + t) * 128))[k4] =
                *(const float4*)(xb + ((size_t)(c * TIN + T0 + t)) * SIN + k4 * 4);
        }
    }
    __syncthreads();

    if (tid < 192) {
        const int o  = tid >> 5;
        const int s0 = (tid & 31) * 4;
        const float* wb = w1s + o * 27;
        float w000 = wb[0],  w001 = wb[1],  w002 = wb[2];
        float w010 = wb[3],  w011 = wb[4],  w012 = wb[5];
        float w020 = wb[6],  w021 = wb[7],  w022 = wb[8];
        float w100 = wb[9],  w101 = wb[10], w102 = wb[11];
        float w110 = wb[12], w111 = wb[13], w112 = wb[14];
        float w120 = wb[15], w121 = wb[16], w122 = wb[17];
        float w200 = wb[18], w201 = wb[19], w202 = wb[20];
        float w210 = wb[21], w211 = wb[22], w212 = wb[23];
        float w220 = wb[24], w221 = wb[25], w222 = wb[26];
        float bo = b1s[o];
        for (int tq = 0; tq < 12; ++tq) {
            float acc0 = bo, acc1 = bo, acc2 = bo, acc3 = bo;
            C1SEG(0, 0, w000, w001, w002)
            C1SEG(0, 1, w010, w011, w012)
            C1SEG(0, 2, w020, w021, w022)
            C1SEG(1, 0, w100, w101, w102)
            C1SEG(1, 1, w110, w111, w112)
            C1SEG(1, 2, w120, w121, w122)
            C1SEG(2, 0, w200, w201, w202)
            C1SEG(2, 1, w210, w211, w212)
            C1SEG(2, 2, w220, w221, w222)
            float4 r;
            r.x = (acc0 >= 0.f) ? acc0 : 0.01f * acc0;
            r.y = (acc1 >= 0.f) ? acc1 : 0.01f * acc1;
            r.z = (acc2 >= 0.f) ? acc2 : 0.01f * acc2;
            r.w = (acc3 >= 0.f) ? acc3 : 0.01f * acc3;
            *(float4*)(h1t + (o * 12 + tq) * 128 + s0) = r;
        }
    }
    __syncthreads();

    {
        float u000 = w2s[0],  u001 = w2s[1],  u002 = w2s[2];
        float u010 = w2s[3],  u011 = w2s[4],  u012 = w2s[5];
        float u020 = w2s[6],  u021 = w2s[7],  u022 = w2s[8];
        float u100 = w2s[9],  u101 = w2s[10], u102 = w2s[11];
        float u110 = w2s[12], u111 = w2s[13], u112 = w2s[14];
        float u120 = w2s[15], u121 = w2s[16], u122 = w2s[17];
        float u200 = w2s[18], u201 = w2s[19], u202 = w2s[20];
        float u210 = w2s[21], u211 = w2s[22], u212 = w2s[23];
        float u220 = w2s[24], u221 = w2s[25], u222 = w2s[26];
        float u300 = w2s[27], u301 = w2s[28], u302 = w2s[29];
        float u310 = w2s[30], u311 = w2s[31], u312 = w2s[32];
        float u320 = w2s[33], u321 = w2s[34], u322 = w2s[35];
        float u400 = w2s[36], u401 = w2s[37], u402 = w2s[38];
        float u410 = w2s[39], u411 = w2s[40], u412 = w2s[41];
        float u420 = w2s[42], u421 = w2s[43], u422 = w2s[44];
        float u500 = w2s[45], u501 = w2s[46], u502 = w2s[47];
        float u510 = w2s[48], u511 = w2s[49], u512 = w2s[50];
        float u520 = w2s[51], u521 = w2s[52], u522 = w2s[53];
        float bo2 = b2s;
        for (int idx = tid; idx < 310; idx += 256) {
            const int tq = idx / 31;
            const int s0 = (idx - tq * 31) * 4;
            float acc0 = bo2, acc1 = bo2, acc2 = bo2, acc3 = bo2;
            C2SEG(0, 0, u000, u001, u002)
            C2SEG(0, 1, u010, u011, u012)
            C2SEG(0, 2, u020, u021, u022)
            C2SEG(1, 0, u100, u101, u102)
            C2SEG(1, 1, u110, u111, u112)
            C2SEG(1, 2, u120, u121, u122)
            C2SEG(2, 0, u200, u201, u202)
            C2SEG(2, 1, u210, u211, u212)
            C2SEG(2, 2, u220, u221, u222)
            C2SEG(3, 0, u300, u301, u302)
            C2SEG(3, 1, u310, u311, u312)
            C2SEG(3, 2, u320, u321, u322)
            C2SEG(4, 0, u400, u401, u402)
            C2SEG(4, 1, u410, u411, u412)
            C2SEG(4, 2, u420, u421, u422)
            C2SEG(5, 0, u500, u501, u502)
            C2SEG(5, 1, u510, u511, u512)
            C2SEG(5, 2, u520, u521, u522)
            float4 r;
            r.x = (acc0 >= 0.f) ? acc0 : 0.01f * acc0;
            r.y = (acc1 >= 0.f) ? acc1 : 0.01f * acc1;
            r.z = (acc2 >= 0.f) ? acc2 : 0.01f * acc2;
            r.w = (acc3 >= 0.f) ? acc3 : 0.01f * acc3;
            *(float4*)(seq + ((size_t)bb * 60 + T0 + tq) * 124 + s0) = r;
        }
    }
}

// ---------------------------------------------------------------------------
// gi via MFMA (split bf16, hh+hl+lh): gic[t][387][4096] = Wih @ seq[:,t,:]^T
// Grid: 25 j-tiles x 32 b-chunks(128). Block: 512 thr = 8 waves = 8 n-tiles.
// A-frags (one j-tile, 4 k-tiles x hi/lo = 8 frags = 32 VGPR) resident.
// Per t: stage seq hi/lo bf16 into LDS frag layout (ksub padded 4->5 slots
// to break bank alignment), 12 MFMA/wave, coalesced C-write.
// ---------------------------------------------------------------------------
__global__ __launch_bounds__(512) void gi_mfma(
    const float* __restrict__ seq, const short* __restrict__ awih,
    float* __restrict__ gic, int t0, int nt)
{
    // Bs layout (shorts): (((kt*2+half)*128 + bi)*5 + ksub)*8 + c   (80 KB)
    __shared__ __attribute__((aligned(16))) short Bs[4 * 2 * 128 * 5 * 8];

    const int tid = threadIdx.x;
    const int l   = tid & 63;
    const int w   = tid >> 6;          // n-tile 0..7
    const int jt  = blockIdx.y;        // 0..24
    const int b0  = blockIdx.x * 128;  // b-chunk base

    // A fragments, resident: frag(kt,half) at ((jt*4+kt)*2+half)*64 + l (bf16x8)
    const bf16x8* at = (const bf16x8*)awih;
    const int abase = jt * 8 * 64 + l;
    bf16x8 Ah0 = at[abase + 0 * 128];       // kt0 hi
    bf16x8 Al0 = at[abase + 0 * 128 + 64];  // kt0 lo
    bf16x8 Ah1 = at[abase + 1 * 128];
    bf16x8 Al1 = at[abase + 1 * 128 + 64];
    bf16x8 Ah2 = at[abase + 2 * 128];
    bf16x8 Al2 = at[abase + 2 * 128 + 64];
    bf16x8 Ah3 = at[abase + 3 * 128];
    bf16x8 Al3 = at[abase + 3 * 128 + 64];

    // zero k-pad (k=124..127 -> kt=3, ksub=3, c=4..7) for both halves
    if (tid < 128) {
        *(unsigned long long*)(Bs + ((6 * 128 + tid) * 5 + 3) * 8 + 4) = 0ull;
        *(unsigned long long*)(Bs + ((7 * 128 + tid) * 5 + 3) * 8 + 4) = 0ull;
    }
    __syncthreads();

    const int bi_s = tid >> 2;                 // unused helper (kept simple below)
    (void)bi_s;

    for (int tt = 0; tt < nt; ++tt) {
        const int t = t0 + tt;
        // stage: 128 rows x 31 float4 = 3968 f4
        for (int f = tid; f < 3968; f += 512) {
            int bi = f / 31;
            int kf = f - bi * 31;
            float4 v = *(const float4*)(seq + ((size_t)(b0 + bi) * 60 + t) * 124 + kf * 4);
            int k0   = kf * 4;
            int kt   = k0 >> 5;
            int ksub = (k0 >> 3) & 3;
            int c0   = k0 & 7;           // 0 or 4
            unsigned short h0 = f2bf(v.x), h1 = f2bf(v.y), h2 = f2bf(v.z), h3 = f2bf(v.w);
            unsigned short l0 = f2bf(v.x - bf2f(h0));
            unsigned short l1 = f2bf(v.y - bf2f(h1));
            unsigned short l2 = f2bf(v.z - bf2f(h2));
            unsigned short l3 = f2bf(v.w - bf2f(h3));
            unsigned long long hp = (unsigned long long)h0 | ((unsigned long long)h1 << 16)
                                  | ((unsigned long long)h2 << 32) | ((unsigned long long)h3 << 48);
            unsigned long long lp = (unsigned long long)l0 | ((unsigned long long)l1 << 16)
                                  | ((unsigned long long)l2 << 32) | ((unsigned long long)l3 << 48);
            int base_h = (((kt * 2 + 0) * 128 + bi) * 5 + ksub) * 8 + c0;
            int base_l = (((kt * 2 + 1) * 128 + bi) * 5 + ksub) * 8 + c0;
            *(unsigned long long*)(Bs + base_h) = hp;
            *(unsigned long long*)(Bs + base_l) = lp;
        }
        __syncthreads();

        f32x4 acc = {0.f, 0.f, 0.f, 0.f};
        const int bn   = w * 16 + (l & 15);    // column b within chunk
        const int ksub = l >> 4;
        #define GI_KT(KT, AH, AL) { \
            bf16x8 bh = *(const bf16x8*)(Bs + ((((KT) * 2 + 0) * 128 + bn) * 5 + ksub) * 8); \
            bf16x8 bl = *(const bf16x8*)(Bs + ((((KT) * 2 + 1) * 128 + bn) * 5 + ksub) * 8); \
            acc = __builtin_amdgcn_mfma_f32_16x16x32_bf16(AL, bh, acc, 0, 0, 0); \
            acc = __builtin_amdgcn_mfma_f32_16x16x32_bf16(AH, bl, acc, 0, 0, 0); \
            acc = __builtin_amdgcn_mfma_f32_16x16x32_bf16(AH, bh, acc, 0, 0, 0); }
        GI_KT(0, Ah0, Al0)
        GI_KT(1, Ah1, Al1)
        GI_KT(2, Ah2, Al2)
        GI_KT(3, Ah3, Al3)
        #undef GI_KT

        // C write: col = lane&15 (b), row = (lane>>4)*4 + i (j within tile)
        {
            float* gt = gic + (size_t)tt * 387 * 4096;
            int row0 = (l >> 4) * 4;
            #pragma unroll
            for (int i = 0; i < 4; ++i) {
                int j = jt * 16 + row0 + i;
                if (j < 387)
                    gt[(size_t)j * 4096 + b0 + bn] = acc[i];
            }
        }
        __syncthreads();
    }
}

// ---------------------------------------------------------------------------
// Shared macro kit
// ---------------------------------------------------------------------------
#define D4(acc_, hv4_, wv4_) acc_ += (hv4_).x*(wv4_).x + (hv4_).y*(wv4_).y + (hv4_).z*(wv4_).z + (hv4_).w*(wv4_).w;
#define RED(acc_) { acc_ += __shfl_xor(acc_, 1, 64); acc_ += __shfl_xor(acc_, 2, 64); }

// ---------------------------------------------------------------------------
// GRU recurrence v6: 8 rows/block x 512 blocks — passing R16/R17 (unchanged).
// ---------------------------------------------------------------------------
#define GH_ROW(R, aA, aB, aC) { \
    const float4* hv_ = (const float4*)(hs2 + (R) * 148) + kqo; \
    float4 h4_; \
    h4_ = hv_[0]; D4(aA, h4_, Wa0) D4(aB, h4_, Wb0) D4(aC, h4_, Wc0) \
    h4_ = hv_[1]; D4(aA, h4_, Wa1) D4(aB, h4_, Wb1) D4(aC, h4_, Wc1) \
    h4_ = hv_[2]; D4(aA, h4_, Wa2) D4(aB, h4_, Wb2) D4(aC, h4_, Wc2) \
    h4_ = hv_[3]; D4(aA, h4_, Wa3) D4(aB, h4_, Wb3) D4(aC, h4_, Wc3) \
    h4_ = hv_[4]; D4(aA, h4_, Wa4) D4(aB, h4_, Wb4) D4(aC, h4_, Wc4) \
    h4_ = hv_[5]; D4(aA, h4_, Wa5) D4(aB, h4_, Wb5) D4(aC, h4_, Wc5) \
    h4_ = hv_[6]; D4(aA, h4_, Wa6) D4(aB, h4_, Wb6) D4(aC, h4_, Wc6) \
    h4_ = hv_[7]; D4(aA, h4_, Wa7) D4(aB, h4_, Wb7) D4(aC, h4_, Wc7) \
    h4_ = hv_[8]; D4(aA, h4_, Wa8) D4(aB, h4_, Wb8) D4(aC, h4_, Wc8) }

#define CHUNK(R0) { \
    float aA0 = 0.f, aB0 = 0.f, aC0 = 0.f, aA1 = 0.f, aB1 = 0.f, aC1 = 0.f; \
    float aA2 = 0.f, aB2 = 0.f, aC2 = 0.f, aA3 = 0.f, aB3 = 0.f, aC3 = 0.f; \
    GH_ROW((R0) + 0, aA0, aB0, aC0) \
    GH_ROW((R0) + 1, aA1, aB1, aC1) \
    GH_ROW((R0) + 2, aA2, aB2, aC2) \
    GH_ROW((R0) + 3, aA3, aB3, aC3) \
    RED(aA0) RED(aB0) RED(aC0) RED(aA1) RED(aB1) RED(aC1) \
    RED(aA2) RED(aB2) RED(aC2) RED(aA3) RED(aB3) RED(aC3) \
    float sA = (kq == 0) ? aA0 : (kq == 1) ? aA1 : (kq == 2) ? aA2 : aA3; \
    float sB = (kq == 0) ? aB0 : (kq == 1) ? aB1 : (kq == 2) ? aB2 : aB3; \
    float sC = (kq == 0) ? aC0 : (kq == 1) ? aC1 : (kq == 2) ? aC2 : aC3; \
    int rw_ = (R0) + kq; \
    GHb[rw_ * 388 + gq]       = sA; \
    GHb[rw_ * 388 + 129 + gq] = sB; \
    GHb[rw_ * 388 + 258 + gq] = sC; }

#define APPLY(E, PGA, PGB, PGC) { \
    int r_ = (E) & 7, j_ = (E) >> 3; \
    float pr_  = (PGA) + GHb[r_ * 388 + j_]       + bihS[j_]       + bhhS[j_]; \
    float pz_  = (PGB) + GHb[r_ * 388 + 129 + j_] + bihS[129 + j_] + bhhS[129 + j_]; \
    float gin_ = (PGC) + bihS[258 + j_]; \
    float ghn_ = GHb[r_ * 388 + 258 + j_] + bhhS[258 + j_]; \
    float rg_ = fast_sigmoid(pr_); \
    float zg_ = fast_sigmoid(pz_); \
    float nn_ = fast_tanh(gin_ + rg_ * ghn_); \
    hs2[r_ * 148 + j_] = (1.f - zg_) * nn_ + zg_ * hs2[r_ * 148 + j_]; }

__global__ __launch_bounds__(576)
void gru_rec(
    const float* __restrict__ gic, const float* __restrict__ whr,  // [27][576][4]
    const float* __restrict__ bih, const float* __restrict__ bhh,
    float* __restrict__ hstate, float* __restrict__ g_out,
    int t0, int nt)
{
    __shared__ __attribute__((aligned(16))) float hs2[8 * 148];  // stride 148
    __shared__ float GHb[8 * 388];
    __shared__ float bihS[387];
    __shared__ float bhhS[387];

    const int tid    = threadIdx.x;
    const int kq     = tid & 3;
    const int kqo    = kq * 9;           // f4 offset into a 36-float k-chunk
    const int b0     = blockIdx.x * 8;
    const bool isMain = (tid < 512);
    const int gq     = isMain ? (tid >> 2) : 0;      // [0,128)
    const int rsp8   = ((tid - 512) >> 2) & 7;       // special wave row (x2 dup)

    const float4* whr4 = (const float4*)whr;
    float4 Wa0 = whr4[0*576+tid],  Wa1 = whr4[1*576+tid],
           Wa2 = whr4[2*576+tid],  Wa3 = whr4[3*576+tid],
           Wa4 = whr4[4*576+tid],  Wa5 = whr4[5*576+tid],
           Wa6 = whr4[6*576+tid],  Wa7 = whr4[7*576+tid],
           Wa8 = whr4[8*576+tid];
    float4 Wb0 = whr4[9*576+tid],  Wb1 = whr4[10*576+tid],
           Wb2 = whr4[11*576+tid], Wb3 = whr4[12*576+tid],
           Wb4 = whr4[13*576+tid], Wb5 = whr4[14*576+tid],
           Wb6 = whr4[15*576+tid], Wb7 = whr4[16*576+tid],
           Wb8 = whr4[17*576+tid];
    float4 Wc0 = whr4[18*576+tid], Wc1 = whr4[19*576+tid],
           Wc2 = whr4[20*576+tid], Wc3 = whr4[21*576+tid],
           Wc4 = whr4[22*576+tid], Wc5 = whr4[23*576+tid],
           Wc6 = whr4[24*576+tid], Wc7 = whr4[25*576+tid],
           Wc8 = whr4[26*576+tid];

    if (tid < 387) { bihS[tid] = bih[tid]; bhhS[tid] = bhh[tid]; }
    if (t0 == 0) {
        for (int e = tid; e < 8 * 148; e += 576) hs2[e] = 0.f;
    } else {
        for (int e = tid; e < 8 * 148; e += 576) hs2[e] = hstate[(size_t)b0 * 148 + e];
    }
    __syncthreads();

    const int e0 = tid, e1 = tid + 576;   // gate elems: 8*129 = 1032

    for (int tt = 0; tt < nt; ++tt) {
        const float* gib = gic + (size_t)tt * 387 * 4096 + b0;
        float pa0, pb0, pc0;
        float pa1 = 0.f, pb1 = 0.f, pc1 = 0.f;
        {
            int r = e0 & 7, j = e0 >> 3;
            if (e0 < 1032) {
                pa0 = gib[(size_t)j * 4096 + r];
                pb0 = gib[(size_t)(129 + j) * 4096 + r];
                pc0 = gib[(size_t)(258 + j) * 4096 + r];
            } else { pa0 = pb0 = pc0 = 0.f; }
            if (e1 < 1032) {
                r = e1 & 7; j = e1 >> 3;
                pa1 = gib[(size_t)j * 4096 + r];
                pb1 = gib[(size_t)(129 + j) * 4096 + r];
                pc1 = gib[(size_t)(258 + j) * 4096 + r];
            }
        }

        if (isMain) {
            CHUNK(0)
            CHUNK(4)
        } else {
            float aA = 0.f, aB = 0.f, aC = 0.f;
            GH_ROW(rsp8, aA, aB, aC)
            RED(aA) RED(aB) RED(aC)
            if (kq == 0) {
                GHb[rsp8 * 388 + 128] = aA;
                GHb[rsp8 * 388 + 257] = aB;
                GHb[rsp8 * 388 + 386] = aC;
            }
        }
        __syncthreads();

        if (e0 < 1032) { APPLY(e0, pa0, pb0, pc0) }
        if (e1 < 1032) { APPLY(e1, pa1, pb1, pc1) }
        __syncthreads();
    }

    for (int e = tid; e < 8 * 148; e += 576) hstate[(size_t)b0 * 148 + e] = hs2[e];
    if (t0 + nt >= 60) {
        if (e0 < 1032) { int r = e0 & 7, j = e0 >> 3; float v = hs2[r * 148 + j];
            g_out[(size_t)(b0 + r) * 129 + j] = (v >= 0.f) ? v : 0.01f * v; }
        if (e1 < 1032) { int r = e1 & 7, j = e1 >> 3; float v = hs2[r * 148 + j];
            g_out[(size_t)(b0 + r) * 129 + j] = (v >= 0.f) ? v : 0.01f * v; }
    }
}

// ---------------------------------------------------------------------------
// Head: feat=[g,w] (258) -> mu, log_std -> sample, tanh, log_pi, normalize.
// ---------------------------------------------------------------------------
__global__ __launch_bounds__(256) void head_kernel(
    const float* __restrict__ gbuf, const float* __restrict__ wvec,
    const float* __restrict__ eps,
    const float* __restrict__ muwp, const float* __restrict__ lswp,
    const float* __restrict__ mub,  const float* __restrict__ lsb,
    float* __restrict__ out)
{
    __shared__ __attribute__((aligned(16))) float feat[16 * 260];
    __shared__ float PA[16 * 130];
    __shared__ float TERM[16 * 130];
    __shared__ float ROWSUM[16];
    __shared__ float ROWLOG[16];

    const int tid = threadIdx.x;
    const int b0  = blockIdx.x * 16;

    for (int i = tid; i < 16 * 260; i += 256) {
        int r = i / 260;
        int k = i - r * 260;
        float v = 0.f;
        if (k < 129)       v = gbuf[(size_t)(b0 + r) * 129 + k];
        else if (k < 258)  v = wvec[(size_t)(b0 + r) * 129 + (k - 129)];
        feat[i] = v;
    }
    __syncthreads();

    for (int idx = tid; idx < 16 * 129; idx += 256) {
        int r = idx & 15;
        int j = idx >> 4;
        const float4* fv = (const float4*)(feat + r * 260);
        const float4* mw = (const float4*)(muwp + (size_t)j * 260);
        const float4* lw = (const float4*)(lswp + (size_t)j * 260);
        float am = 0.f, al = 0.f;
        for (int k = 0; k < 65; ++k) {
            float4 f = fv[k];
            float4 m = mw[k];
            float4 l = lw[k];
            am += f.x * m.x + f.y * m.y + f.z * m.z + f.w * m.w;
            al += f.x * l.x + f.y * l.y + f.z * l.z + f.w * l.w;
        }
        float mu = am + mub[j];
        float ls = fminf(fmaxf(al + lsb[j], -20.f), 2.f);
        float sd = __expf(ls);
        float e  = eps[(size_t)(b0 + r) * 129 + j];
        float xv = mu + sd * e;
        float pa = fast_tanh(xv);
        float tt = (xv - mu) / sd;
        float term = -0.5f * tt * tt - ls - 0.91893853320467274f
                     - __logf(1.f - pa * pa + 1e-6f);
        PA[r * 130 + j]   = pa;
        TERM[r * 130 + j] = term;
    }
    __syncthreads();

    {
        int r = tid >> 4;
        int i = tid & 15;
        float sp = 0.f, st = 0.f;
        for (int j = i; j < 129; j += 16) {
            sp += PA[r * 130 + j];
            st += TERM[r * 130 + j];
        }
        for (int off = 8; off > 0; off >>= 1) {
            sp += __shfl_down(sp, off, 16);
            st += __shfl_down(st, off, 16);
        }
        if (i == 0) { ROWSUM[r] = sp + 129.f; ROWLOG[r] = st; }
    }
    __syncthreads();

    for (int idx = tid; idx < 16 * 129; idx += 256) {
        int r = idx & 15;
        int j = idx >> 4;
        out[(size_t)(b0 + r) * 129 + j] = (PA[r * 130 + j] + 1.f) / ROWSUM[r];
    }
    if (tid < 16)
        out[(size_t)4096 * 129 + b0 + tid] = ROWLOG[tid];
}

// ---------------------------------------------------------------------------
extern "C" void kernel_launch(void* const* d_in, const int* in_sizes, int n_in,
                              void* d_out, int out_size, void* d_ws, size_t ws_size,
                              hipStream_t stream)
{
    const float* x   = (const float*)d_in[0];
    const float* wv  = (const float*)d_in[1];
    const float* eps = (const float*)d_in[2];
    const float* c1w = (const float*)d_in[3];
    const float* c1b = (const float*)d_in[4];
    const float* c2w = (const float*)d_in[5];
    const float* c2b = (const float*)d_in[6];
    const float* Wih = (const float*)d_in[7];
    const float* Whh = (const float*)d_in[8];
    const float* bih = (const float*)d_in[9];
    const float* bhh = (const float*)d_in[10];
    const float* muw = (const float*)d_in[11];
    const float* mub = (const float*)d_in[12];
    const float* lsw = (const float*)d_in[13];
    const float* lsb = (const float*)d_in[14];

    float* ws     = (float*)d_ws;
    float* seq    = ws + SEQ_OFF;
    float* g      = ws + G_OFF;
    float* hstate = ws + HST_OFF;
    float* whr    = ws + WHR_OFF;
    const short* awih = (const short*)(ws + AWIH_OFF);
    float* muwp   = ws + MUWP_OFF;
    float* lswp   = ws + LSWP_OFF;
    float* gic    = ws + GIC_OFF;
    float* outp   = (float*)d_out;

    // chunk size over t, limited by workspace (deterministic given ws_size)
    const long per_t = 387L * 4096;
    long avail = (long)(ws_size / 4) - (long)GIC_OFF;
    int CT = 60;
    if (avail < 60 * per_t) {
        CT = (int)(avail / per_t);
        if (CT < 1) CT = 1;
        if (CT > 60) CT = 60;
    }

    const int prep_elems = 27 * 576 * 4 + 25 * 4096 + 2 * (129 * 260);
    prep_pad<<<(prep_elems + 255) / 256, 256, 0, stream>>>(Whh, Wih, muw, lsw, ws);
    conv_fused<<<dim3(6, BTOT), 256, 0, stream>>>(x, c1w, c1b, c2w, c2b, seq);

    for (int t0 = 0; t0 < 60; t0 += CT) {
        int nt = 60 - t0; if (nt > CT) nt = CT;
        gi_mfma<<<dim3(32, 25), 512, 0, stream>>>(seq, awih, gic, t0, nt);
        gru_rec<<<512, 576, 0, stream>>>(gic, whr, bih, bhh, hstate, g, t0, nt);
    }
    head_kernel<<<BTOT / 16, 256, 0, stream>>>(g, wv, eps, muwp, lswp, mub, lsb, outp);
}

// Round 19
// 1729.402 us; speedup vs baseline: 1.2689x; 1.2527x over previous
//
#include <hip/hip_runtime.h>
#include <math.h>

// Problem constants
#define BTOT   4096
#define CIN    3
#define TIN    64
#define SIN    128

// ws layout (float offsets)
#define SEQ_OFF    0                            // [4096][60][124]
#define G_OFF      (SEQ_OFF + 4096*60*124)      // [4096][129]
#define HST_OFF    (G_OFF + 4096*129)           // [4096][132] h state between chunks
#define AWHH_OFF   (HST_OFF + 4096*132)         // [25][5][2][64][8] bf16 Whh frags (128000 shorts = 64000 float slots)
#define AWIH_OFF   (AWHH_OFF + 64000)           // [25][4][2][64][8] bf16 Wih frags (102400 shorts = 51200 float slots)
#define MUWP_OFF   (AWIH_OFF + 51200)           // [129][260]
#define LSWP_OFF   (MUWP_OFF + 129*260)         // [129][260]
#define GIC_OFF    (LSWP_OFF + 129*260)         // [CT][387][4096] gi chunk

typedef __attribute__((ext_vector_type(8))) short bf16x8;
typedef __attribute__((ext_vector_type(4))) float f32x4;

// Inline transcendentals (no libm calls in hot loops)
__device__ __forceinline__ float fast_tanh(float x) {
    float ax = fabsf(x);
    float t  = __expf(-2.f * ax);
    float r  = (1.f - t) / (1.f + t);
    return copysignf(r, x);
}
__device__ __forceinline__ float fast_sigmoid(float x) {
    return 1.f / (1.f + __expf(-x));
}
// bf16 round-to-nearest-even helpers (bit ops only)
__device__ __forceinline__ unsigned short f2bf(float x) {
    unsigned int u = __float_as_uint(x);
    unsigned int r = u + 0x7FFFu + ((u >> 16) & 1u);
    return (unsigned short)(r >> 16);
}
__device__ __forceinline__ float bf2f(unsigned short b) {
    return __uint_as_float(((unsigned int)b) << 16);
}

// ---------------------------------------------------------------------------
// Prep: bf16 hi/lo fragment tables for Whh (5 k-tiles) and Wih (4 k-tiles),
// plus fc weight padding. Fragment convention (validated by gi_mfma R18):
//   lane l holds A[jt*16 + (l&15)][kt*32 + (l>>4)*8 + c], c = 0..7
//   half 0 = bf16(x); half 1 = bf16(x - f32(bf16(x)))
// ---------------------------------------------------------------------------
__global__ __launch_bounds__(256) void prep_pad(
    const float* __restrict__ Whh, const float* __restrict__ Wih,
    const float* __restrict__ muw, const float* __restrict__ lsw,
    float* __restrict__ ws)
{
    int idx = blockIdx.x * 256 + threadIdx.x;
    const int NHH = 25 * 5 * 2 * 512;   // 128000 shorts
    const int NIA = 25 * 4 * 2 * 512;   // 102400 shorts
    const int N2  = 129 * 260;
    if (idx < NHH) {
        int a      = idx;
        int frag   = a >> 9;
        int within = a & 511;
        int l      = within >> 3;
        int c      = within & 7;
        int half   = frag & 1;
        int q      = frag >> 1;
        int kt     = q % 5;
        int jt     = q / 5;
        int j      = jt * 16 + (l & 15);
        int k      = kt * 32 + (l >> 4) * 8 + c;
        float v    = (j < 387 && k < 129) ? Whh[(size_t)j * 129 + k] : 0.f;
        unsigned short hb = f2bf(v);
        ((short*)(ws + AWHH_OFF))[a] = (short)((half == 0) ? hb : f2bf(v - bf2f(hb)));
    } else if (idx < NHH + NIA) {
        int a      = idx - NHH;
        int frag   = a >> 9;
        int within = a & 511;
        int l      = within >> 3;
        int c      = within & 7;
        int half   = frag & 1;
        int q      = frag >> 1;
        int kt     = q & 3;
        int jt     = q >> 2;
        int j      = jt * 16 + (l & 15);
        int k      = kt * 32 + (l >> 4) * 8 + c;
        float v    = (j < 387 && k < 124) ? Wih[(size_t)j * 124 + k] : 0.f;
        unsigned short hb = f2bf(v);
        ((short*)(ws + AWIH_OFF))[a] = (short)((half == 0) ? hb : f2bf(v - bf2f(hb)));
    } else if (idx < NHH + NIA + N2) {
        int i = idx - NHH - NIA; int j = i / 260, k = i - j * 260;
        ws[MUWP_OFF + i] = (k < 258) ? muw[j * 258 + k] : 0.f;
    } else if (idx < NHH + NIA + 2 * N2) {
        int i = idx - NHH - NIA - N2; int j = i / 260, k = i - j * 260;
        ws[LSWP_OFF + i] = (k < 258) ? lsw[j * 258 + k] : 0.f;
    }
}

// ---------------------------------------------------------------------------
// Fused conv1+conv2 v2 (register-blocked, weight-resident) — passing R13.
// ---------------------------------------------------------------------------
#define C1SEG(c_, kt_, W0_, W1_, W2_) { \
    const float* rp_ = xt + ((c_) * 14 + tq + (kt_)) * 128 + s0; \
    float4 v4_ = *(const float4*)rp_; \
    float2 v2_ = *(const float2*)(rp_ + 4); \
    acc0 += v4_.x*(W0_) + v4_.y*(W1_) + v4_.z*(W2_); \
    acc1 += v4_.y*(W0_) + v4_.z*(W1_) + v4_.w*(W2_); \
    acc2 += v4_.z*(W0_) + v4_.w*(W1_) + v2_.x*(W2_); \
    acc3 += v4_.w*(W0_) + v2_.x*(W1_) + v2_.y*(W2_); }

#define C2SEG(o_, kt_, W0_, W1_, W2_) { \
    const float* rp_ = h1t + ((o_) * 12 + tq + (kt_)) * 128 + s0; \
    float4 v4_ = *(const float4*)rp_; \
    float2 v2_ = *(const float2*)(rp_ + 4); \
    acc0 += v4_.x*(W0_) + v4_.y*(W1_) + v4_.z*(W2_); \
    acc1 += v4_.y*(W0_) + v4_.z*(W1_) + v4_.w*(W2_); \
    acc2 += v4_.z*(W0_) + v4_.w*(W1_) + v2_.x*(W2_); \
    acc3 += v4_.w*(W0_) + v2_.x*(W1_) + v2_.y*(W2_); }

__global__ __launch_bounds__(256) void conv_fused(
    const float* __restrict__ x,
    const float* __restrict__ w1, const float* __restrict__ b1,
    const float* __restrict__ w2, const float* __restrict__ b2,
    float* __restrict__ seq)
{
    __shared__ __attribute__((aligned(16))) float xt[3 * 14 * 128 + 8];
    __shared__ __attribute__((aligned(16))) float h1t[6 * 12 * 128];
    __shared__ float w1s[162];
    __shared__ float w2s[54];
    __shared__ float b1s[6];
    __shared__ float b2s;

    const int tid  = threadIdx.x;
    const int tile = blockIdx.x;   // 0..5
    const int bb   = blockIdx.y;   // batch
    const int T0   = tile * 10;

    if (tid < 162)                  w1s[tid] = w1[tid];
    if (tid >= 192 && tid < 246)    w2s[tid - 192] = w2[tid - 192];
    if (tid >= 248 && tid < 254)    b1s[tid - 248] = b1[tid - 248];
    if (tid == 255)                 b2s = b2[0];

    {
        const float* xb = x + (size_t)bb * CIN * TIN * SIN;
        for (int i = tid; i < 3 * 14 * 32; i += 256) {
            int c   = i / (14 * 32);
            int rem = i - c * (14 * 32);
            int t   = rem >> 5;
            int k4  = rem & 31;
            ((float4*)(xt + (c * 14 + t) * 128))[k4] =
                *(const float4*)(xb + ((size_t)(c * TIN + T0 + t)) * SIN + k4 * 4);
        }
    }
    __syncthreads();

    if (tid < 192) {
        const int o  = tid >> 5;
        const int s0 = (tid & 31) * 4;
        const float* wb = w1s + o * 27;
        float w000 = wb[0],  w001 = wb[1],  w002 = wb[2];
        float w010 = wb[3],  w011 = wb[4],  w012 = wb[5];
        float w020 = wb[6],  w021 = wb[7],  w022 = wb[8];
        float w100 = wb[9],  w101 = wb[10], w102 = wb[11];
        float w110 = wb[12], w111 = wb[13], w112 = wb[14];
        float w120 = wb[15], w121 = wb[16], w122 = wb[17];
        float w200 = wb[18], w201 = wb[19], w202 = wb[20];
        float w210 = wb[21], w211 = wb[22], w212 = wb[23];
        float w220 = wb[24], w221 = wb[25], w222 = wb[26];
        float bo = b1s[o];
        for (int tq = 0; tq < 12; ++tq) {
            float acc0 = bo, acc1 = bo, acc2 = bo, acc3 = bo;
            C1SEG(0, 0, w000, w001, w002)
            C1SEG(0, 1, w010, w011, w012)
            C1SEG(0, 2, w020, w021, w022)
            C1SEG(1, 0, w100, w101, w102)
            C1SEG(1, 1, w110, w111, w112)
            C1SEG(1, 2, w120, w121, w122)
            C1SEG(2, 0, w200, w201, w202)
            C1SEG(2, 1, w210, w211, w212)
            C1SEG(2, 2, w220, w221, w222)
            float4 r;
            r.x = (acc0 >= 0.f) ? acc0 : 0.01f * acc0;
            r.y = (acc1 >= 0.f) ? acc1 : 0.01f * acc1;
            r.z = (acc2 >= 0.f) ? acc2 : 0.01f * acc2;
            r.w = (acc3 >= 0.f) ? acc3 : 0.01f * acc3;
            *(float4*)(h1t + (o * 12 + tq) * 128 + s0) = r;
        }
    }
    __syncthreads();

    {
        float u000 = w2s[0],  u001 = w2s[1],  u002 = w2s[2];
        float u010 = w2s[3],  u011 = w2s[4],  u012 = w2s[5];
        float u020 = w2s[6],  u021 = w2s[7],  u022 = w2s[8];
        float u100 = w2s[9],  u101 = w2s[10], u102 = w2s[11];
        float u110 = w2s[12], u111 = w2s[13], u112 = w2s[14];
        float u120 = w2s[15], u121 = w2s[16], u122 = w2s[17];
        float u200 = w2s[18], u201 = w2s[19], u202 = w2s[20];
        float u210 = w2s[21], u211 = w2s[22], u212 = w2s[23];
        float u220 = w2s[24], u221 = w2s[25], u222 = w2s[26];
        float u300 = w2s[27], u301 = w2s[28], u302 = w2s[29];
        float u310 = w2s[30], u311 = w2s[31], u312 = w2s[32];
        float u320 = w2s[33], u321 = w2s[34], u322 = w2s[35];
        float u400 = w2s[36], u401 = w2s[37], u402 = w2s[38];
        float u410 = w2s[39], u411 = w2s[40], u412 = w2s[41];
        float u420 = w2s[42], u421 = w2s[43], u422 = w2s[44];
        float u500 = w2s[45], u501 = w2s[46], u502 = w2s[47];
        float u510 = w2s[48], u511 = w2s[49], u512 = w2s[50];
        float u520 = w2s[51], u521 = w2s[52], u522 = w2s[53];
        float bo2 = b2s;
        for (int idx = tid; idx < 310; idx += 256) {
            const int tq = idx / 31;
            const int s0 = (idx - tq * 31) * 4;
            float acc0 = bo2, acc1 = bo2, acc2 = bo2, acc3 = bo2;
            C2SEG(0, 0, u000, u001, u002)
            C2SEG(0, 1, u010, u011, u012)
            C2SEG(0, 2, u020, u021, u022)
            C2SEG(1, 0, u100, u101, u102)
            C2SEG(1, 1, u110, u111, u112)
            C2SEG(1, 2, u120, u121, u122)
            C2SEG(2, 0, u200, u201, u202)
            C2SEG(2, 1, u210, u211, u212)
            C2SEG(2, 2, u220, u221, u222)
            C2SEG(3, 0, u300, u301, u302)
            C2SEG(3, 1, u310, u311, u312)
            C2SEG(3, 2, u320, u321, u322)
            C2SEG(4, 0, u400, u401, u402)
            C2SEG(4, 1, u410, u411, u412)
            C2SEG(4, 2, u420, u421, u422)
            C2SEG(5, 0, u500, u501, u502)
            C2SEG(5, 1, u510, u511, u512)
            C2SEG(5, 2, u520, u521, u522)
            float4 r;
            r.x = (acc0 >= 0.f) ? acc0 : 0.01f * acc0;
            r.y = (acc1 >= 0.f) ? acc1 : 0.01f * acc1;
            r.z = (acc2 >= 0.f) ? acc2 : 0.01f * acc2;
            r.w = (acc3 >= 0.f) ? acc3 : 0.01f * acc3;
            *(float4*)(seq + ((size_t)bb * 60 + T0 + tq) * 124 + s0) = r;
        }
    }
}

// ---------------------------------------------------------------------------
// gi via MFMA (split bf16, hh+hl+lh) — passing R18, offsets updated only.
// ---------------------------------------------------------------------------
__global__ __launch_bounds__(512) void gi_mfma(
    const float* __restrict__ seq, const short* __restrict__ awih,
    float* __restrict__ gic, int t0, int nt)
{
    __shared__ __attribute__((aligned(16))) short Bs[4 * 2 * 128 * 5 * 8];

    const int tid = threadIdx.x;
    const int l   = tid & 63;
    const int w   = tid >> 6;          // n-tile 0..7
    const int jt  = blockIdx.y;        // 0..24
    const int b0  = blockIdx.x * 128;  // b-chunk base

    const bf16x8* at = (const bf16x8*)awih;
    const int abase = jt * 8 * 64 + l;
    bf16x8 Ah0 = at[abase + 0 * 128];
    bf16x8 Al0 = at[abase + 0 * 128 + 64];
    bf16x8 Ah1 = at[abase + 1 * 128];
    bf16x8 Al1 = at[abase + 1 * 128 + 64];
    bf16x8 Ah2 = at[abase + 2 * 128];
    bf16x8 Al2 = at[abase + 2 * 128 + 64];
    bf16x8 Ah3 = at[abase + 3 * 128];
    bf16x8 Al3 = at[abase + 3 * 128 + 64];

    if (tid < 128) {
        *(unsigned long long*)(Bs + ((6 * 128 + tid) * 5 + 3) * 8 + 4) = 0ull;
        *(unsigned long long*)(Bs + ((7 * 128 + tid) * 5 + 3) * 8 + 4) = 0ull;
    }
    __syncthreads();

    for (int tt = 0; tt < nt; ++tt) {
        const int t = t0 + tt;
        for (int f = tid; f < 3968; f += 512) {
            int bi = f / 31;
            int kf = f - bi * 31;
            float4 v = *(const float4*)(seq + ((size_t)(b0 + bi) * 60 + t) * 124 + kf * 4);
            int k0   = kf * 4;
            int kt   = k0 >> 5;
            int ksub = (k0 >> 3) & 3;
            int c0   = k0 & 7;
            unsigned short h0 = f2bf(v.x), h1 = f2bf(v.y), h2 = f2bf(v.z), h3 = f2bf(v.w);
            unsigned short l0 = f2bf(v.x - bf2f(h0));
            unsigned short l1 = f2bf(v.y - bf2f(h1));
            unsigned short l2 = f2bf(v.z - bf2f(h2));
            unsigned short l3 = f2bf(v.w - bf2f(h3));
            unsigned long long hp = (unsigned long long)h0 | ((unsigned long long)h1 << 16)
                                  | ((unsigned long long)h2 << 32) | ((unsigned long long)h3 << 48);
            unsigned long long lp = (unsigned long long)l0 | ((unsigned long long)l1 << 16)
                                  | ((unsigned long long)l2 << 32) | ((unsigned long long)l3 << 48);
            *(unsigned long long*)(Bs + (((kt * 2 + 0) * 128 + bi) * 5 + ksub) * 8 + c0) = hp;
            *(unsigned long long*)(Bs + (((kt * 2 + 1) * 128 + bi) * 5 + ksub) * 8 + c0) = lp;
        }
        __syncthreads();

        f32x4 acc = {0.f, 0.f, 0.f, 0.f};
        const int bn   = w * 16 + (l & 15);
        const int ksub = l >> 4;
        #define GI_KT(KT, AH, AL) { \
            bf16x8 bh = *(const bf16x8*)(Bs + ((((KT) * 2 + 0) * 128 + bn) * 5 + ksub) * 8); \
            bf16x8 bl = *(const bf16x8*)(Bs + ((((KT) * 2 + 1) * 128 + bn) * 5 + ksub) * 8); \
            acc = __builtin_amdgcn_mfma_f32_16x16x32_bf16(AL, bh, acc, 0, 0, 0); \
            acc = __builtin_amdgcn_mfma_f32_16x16x32_bf16(AH, bl, acc, 0, 0, 0); \
            acc = __builtin_amdgcn_mfma_f32_16x16x32_bf16(AH, bh, acc, 0, 0, 0); }
        GI_KT(0, Ah0, Al0)
        GI_KT(1, Ah1, Al1)
        GI_KT(2, Ah2, Al2)
        GI_KT(3, Ah3, Al3)
        #undef GI_KT

        {
            float* gt = gic + (size_t)tt * 387 * 4096;
            int row0 = (l >> 4) * 4;
            #pragma unroll
            for (int i = 0; i < 4; ++i) {
                int j = jt * 16 + row0 + i;
                if (j < 387)
                    gt[(size_t)j * 4096 + b0 + bn] = acc[i];
            }
        }
        __syncthreads();
    }
}

// ---------------------------------------------------------------------------
// GRU recurrence via MFMA (split bf16): 256 blocks x 512 thr, 16 rows/block.
// h kept in LDS as hi/lo bf16 B-frags (hbf[2][16][168], 168-short stride =
// 336B = 16B-aligned, bank-shifted). Whh streamed per step from lane-linear
// A-frag table (L2-resident, coalesced). Wave w owns j-tiles {w, 8+w, 16+w}
// (+ jt24 on wave 0). Per step: 10 LDS B-reads/thread (shared over j-tiles),
// 45-60 MFMA/wave, GHb stride 390 (conflict-checked), then gates in phase2
// write h back as fp32 (hs2) + hi/lo bf16 (hbf).
// ---------------------------------------------------------------------------
__global__ __launch_bounds__(512) void gru_mfma(
    const float* __restrict__ gic, const short* __restrict__ awhh,
    const float* __restrict__ bih, const float* __restrict__ bhh,
    float* __restrict__ hstate, float* __restrict__ g_out,
    int t0, int nt)
{
    __shared__ __attribute__((aligned(16))) short hbf[2 * 16 * 168];
    __shared__ float hs2[16 * 132];
    __shared__ float GHb[16 * 390];
    __shared__ float bihS[387];
    __shared__ float bhhS[387];

    const int tid  = threadIdx.x;
    const int l    = tid & 63;
    const int w    = tid >> 6;        // wave 0..7
    const int b0   = blockIdx.x * 16;
    const int bcol = l & 15;
    const int krow = l >> 4;

    if (tid < 387) { bihS[tid] = bih[tid]; bhhS[tid] = bhh[tid]; }
    for (int e = tid; e < 2688; e += 512) ((unsigned int*)hbf)[e] = 0u;
    if (t0 == 0) {
        for (int e = tid; e < 16 * 132; e += 512) hs2[e] = 0.f;
        __syncthreads();
    } else {
        for (int e = tid; e < 16 * 132; e += 512) hs2[e] = hstate[(size_t)b0 * 132 + e];
        __syncthreads();
        for (int e = tid; e < 2064; e += 512) {
            int r = e & 15, j = e >> 4;
            float v = hs2[r * 132 + j];
            unsigned short hb = f2bf(v);
            hbf[r * 168 + j]        = (short)hb;
            hbf[2688 + r * 168 + j] = (short)f2bf(v - bf2f(hb));
        }
        __syncthreads();
    }

    const bf16x8* at = (const bf16x8*)awhh;

    #define GATE(E, PGA, PGB, PGC) { \
        int r_ = (E) & 15, j_ = (E) >> 4; \
        float pr_  = (PGA) + GHb[r_ * 390 + j_]       + bihS[j_]       + bhhS[j_]; \
        float pz_  = (PGB) + GHb[r_ * 390 + 129 + j_] + bihS[129 + j_] + bhhS[129 + j_]; \
        float gin_ = (PGC) + bihS[258 + j_]; \
        float ghn_ = GHb[r_ * 390 + 258 + j_] + bhhS[258 + j_]; \
        float rg_ = fast_sigmoid(pr_); \
        float zg_ = fast_sigmoid(pz_); \
        float nn_ = fast_tanh(gin_ + rg_ * ghn_); \
        float hn_ = (1.f - zg_) * nn_ + zg_ * hs2[r_ * 132 + j_]; \
        hs2[r_ * 132 + j_] = hn_; \
        unsigned short hb_ = f2bf(hn_); \
        hbf[r_ * 168 + j_]        = (short)hb_; \
        hbf[2688 + r_ * 168 + j_] = (short)f2bf(hn_ - bf2f(hb_)); }

    for (int tt = 0; tt < nt; ++tt) {
        // gic prefetch (4 full strides; 16-elem tail read in phase2)
        const float* gib = gic + (size_t)tt * 387 * 4096 + b0;
        float pa0, pb0, pc0, pa1, pb1, pc1, pa2, pb2, pc2, pa3, pb3, pc3;
        {
            int r = tid & 15, j = tid >> 4;
            pa0 = gib[(size_t)j * 4096 + r];
            pb0 = gib[(size_t)(129 + j) * 4096 + r];
            pc0 = gib[(size_t)(258 + j) * 4096 + r];
            int e = tid + 512; r = e & 15; j = e >> 4;
            pa1 = gib[(size_t)j * 4096 + r];
            pb1 = gib[(size_t)(129 + j) * 4096 + r];
            pc1 = gib[(size_t)(258 + j) * 4096 + r];
            e = tid + 1024; r = e & 15; j = e >> 4;
            pa2 = gib[(size_t)j * 4096 + r];
            pb2 = gib[(size_t)(129 + j) * 4096 + r];
            pc2 = gib[(size_t)(258 + j) * 4096 + r];
            e = tid + 1536; r = e & 15; j = e >> 4;
            pa3 = gib[(size_t)j * 4096 + r];
            pb3 = gib[(size_t)(129 + j) * 4096 + r];
            pc3 = gib[(size_t)(258 + j) * 4096 + r];
        }

        // MFMA phase: gh for all 387 gate rows x 16 batch cols
        f32x4 acc0 = {0.f,0.f,0.f,0.f}, acc1 = {0.f,0.f,0.f,0.f};
        f32x4 acc2 = {0.f,0.f,0.f,0.f}, acc3 = {0.f,0.f,0.f,0.f};
        #pragma unroll
        for (int kt = 0; kt < 5; ++kt) {
            bf16x8 bh = *(const bf16x8*)(hbf + bcol * 168 + kt * 32 + krow * 8);
            bf16x8 bl = *(const bf16x8*)(hbf + 2688 + bcol * 168 + kt * 32 + krow * 8);
            {
                int fb = ((w * 5 + kt) * 2) * 64 + l;
                bf16x8 Ah = at[fb], Al = at[fb + 64];
                acc0 = __builtin_amdgcn_mfma_f32_16x16x32_bf16(Al, bh, acc0, 0, 0, 0);
                acc0 = __builtin_amdgcn_mfma_f32_16x16x32_bf16(Ah, bl, acc0, 0, 0, 0);
                acc0 = __builtin_amdgcn_mfma_f32_16x16x32_bf16(Ah, bh, acc0, 0, 0, 0);
            }
            {
                int fb = (((8 + w) * 5 + kt) * 2) * 64 + l;
                bf16x8 Ah = at[fb], Al = at[fb + 64];
                acc1 = __builtin_amdgcn_mfma_f32_16x16x32_bf16(Al, bh, acc1, 0, 0, 0);
                acc1 = __builtin_amdgcn_mfma_f32_16x16x32_bf16(Ah, bl, acc1, 0, 0, 0);
                acc1 = __builtin_amdgcn_mfma_f32_16x16x32_bf16(Ah, bh, acc1, 0, 0, 0);
            }
            {
                int fb = (((16 + w) * 5 + kt) * 2) * 64 + l;
                bf16x8 Ah = at[fb], Al = at[fb + 64];
                acc2 = __builtin_amdgcn_mfma_f32_16x16x32_bf16(Al, bh, acc2, 0, 0, 0);
                acc2 = __builtin_amdgcn_mfma_f32_16x16x32_bf16(Ah, bl, acc2, 0, 0, 0);
                acc2 = __builtin_amdgcn_mfma_f32_16x16x32_bf16(Ah, bh, acc2, 0, 0, 0);
            }
            if (w == 0) {
                int fb = ((24 * 5 + kt) * 2) * 64 + l;
                bf16x8 Ah = at[fb], Al = at[fb + 64];
                acc3 = __builtin_amdgcn_mfma_f32_16x16x32_bf16(Al, bh, acc3, 0, 0, 0);
                acc3 = __builtin_amdgcn_mfma_f32_16x16x32_bf16(Ah, bl, acc3, 0, 0, 0);
                acc3 = __builtin_amdgcn_mfma_f32_16x16x32_bf16(Ah, bh, acc3, 0, 0, 0);
            }
        }
        // write GHb[b][j] (C layout: col b = l&15, row j = jt*16 + krow*4 + i)
        {
            int rb = bcol * 390;
            int j0 = w * 16 + krow * 4;
            GHb[rb + j0 + 0] = acc0[0];
            GHb[rb + j0 + 1] = acc0[1];
            GHb[rb + j0 + 2] = acc0[2];
            GHb[rb + j0 + 3] = acc0[3];
            int j1 = (8 + w) * 16 + krow * 4;
            GHb[rb + j1 + 0] = acc1[0];
            GHb[rb + j1 + 1] = acc1[1];
            GHb[rb + j1 + 2] = acc1[2];
            GHb[rb + j1 + 3] = acc1[3];
            int j2 = (16 + w) * 16 + krow * 4;
            GHb[rb + j2 + 0] = acc2[0];
            GHb[rb + j2 + 1] = acc2[1];
            GHb[rb + j2 + 2] = acc2[2];
            GHb[rb + j2 + 3] = acc2[3];
            if (w == 0 && krow == 0) {
                GHb[rb + 384] = acc3[0];
                GHb[rb + 385] = acc3[1];
                GHb[rb + 386] = acc3[2];
            }
        }
        __syncthreads();

        // phase2: gates + h update (fp32 + hi/lo bf16 writeback)
        GATE(tid,        pa0, pb0, pc0)
        GATE(tid + 512,  pa1, pb1, pc1)
        GATE(tid + 1024, pa2, pb2, pc2)
        GATE(tid + 1536, pa3, pb3, pc3)
        if (tid < 16) {   // tail e = 2048+tid -> r = tid, j = 128
            float ta = gib[(size_t)128 * 4096 + tid];
            float tb = gib[(size_t)257 * 4096 + tid];
            float tc = gib[(size_t)386 * 4096 + tid];
            GATE(2048 + tid, ta, tb, tc)
        }
        __syncthreads();
    }

    for (int e = tid; e < 16 * 132; e += 512) hstate[(size_t)b0 * 132 + e] = hs2[e];
    if (t0 + nt >= 60) {
        for (int e = tid; e < 2064; e += 512) {
            int r = e & 15, j = e >> 4;
            float v = hs2[r * 132 + j];
            g_out[(size_t)(b0 + r) * 129 + j] = (v >= 0.f) ? v : 0.01f * v;
        }
        if (tid < 16) {
            float v = hs2[tid * 132 + 128];
            g_out[(size_t)(b0 + tid) * 129 + 128] = (v >= 0.f) ? v : 0.01f * v;
        }
    }
    #undef GATE
}

// ---------------------------------------------------------------------------
// Head: feat=[g,w] (258) -> mu, log_std -> sample, tanh, log_pi, normalize.
// ---------------------------------------------------------------------------
__global__ __launch_bounds__(256) void head_kernel(
    const float* __restrict__ gbuf, const float* __restrict__ wvec,
    const float* __restrict__ eps,
    const float* __restrict__ muwp, const float* __restrict__ lswp,
    const float* __restrict__ mub,  const float* __restrict__ lsb,
    float* __restrict__ out)
{
    __shared__ __attribute__((aligned(16))) float feat[16 * 260];
    __shared__ float PA[16 * 130];
    __shared__ float TERM[16 * 130];
    __shared__ float ROWSUM[16];
    __shared__ float ROWLOG[16];

    const int tid = threadIdx.x;
    const int b0  = blockIdx.x * 16;

    for (int i = tid; i < 16 * 260; i += 256) {
        int r = i / 260;
        int k = i - r * 260;
        float v = 0.f;
        if (k < 129)       v = gbuf[(size_t)(b0 + r) * 129 + k];
        else if (k < 258)  v = wvec[(size_t)(b0 + r) * 129 + (k - 129)];
        feat[i] = v;
    }
    __syncthreads();

    for (int idx = tid; idx < 16 * 129; idx += 256) {
        int r = idx & 15;
        int j = idx >> 4;
        const float4* fv = (const float4*)(feat + r * 260);
        const float4* mw = (const float4*)(muwp + (size_t)j * 260);
        const float4* lw = (const float4*)(lswp + (size_t)j * 260);
        float am = 0.f, al = 0.f;
        for (int k = 0; k < 65; ++k) {
            float4 f = fv[k];
            float4 m = mw[k];
            float4 l = lw[k];
            am += f.x * m.x + f.y * m.y + f.z * m.z + f.w * m.w;
            al += f.x * l.x + f.y * l.y + f.z * l.z + f.w * l.w;
        }
        float mu = am + mub[j];
        float ls = fminf(fmaxf(al + lsb[j], -20.f), 2.f);
        float sd = __expf(ls);
        float e  = eps[(size_t)(b0 + r) * 129 + j];
        float xv = mu + sd * e;
        float pa = fast_tanh(xv);
        float tt = (xv - mu) / sd;
        float term = -0.5f * tt * tt - ls - 0.91893853320467274f
                     - __logf(1.f - pa * pa + 1e-6f);
        PA[r * 130 + j]   = pa;
        TERM[r * 130 + j] = term;
    }
    __syncthreads();

    {
        int r = tid >> 4;
        int i = tid & 15;
        float sp = 0.f, st = 0.f;
        for (int j = i; j < 129; j += 16) {
            sp += PA[r * 130 + j];
            st += TERM[r * 130 + j];
        }
        for (int off = 8; off > 0; off >>= 1) {
            sp += __shfl_down(sp, off, 16);
            st += __shfl_down(st, off, 16);
        }
        if (i == 0) { ROWSUM[r] = sp + 129.f; ROWLOG[r] = st; }
    }
    __syncthreads();

    for (int idx = tid; idx < 16 * 129; idx += 256) {
        int r = idx & 15;
        int j = idx >> 4;
        out[(size_t)(b0 + r) * 129 + j] = (PA[r * 130 + j] + 1.f) / ROWSUM[r];
    }
    if (tid < 16)
        out[(size_t)4096 * 129 + b0 + tid] = ROWLOG[tid];
}

// ---------------------------------------------------------------------------
extern "C" void kernel_launch(void* const* d_in, const int* in_sizes, int n_in,
                              void* d_out, int out_size, void* d_ws, size_t ws_size,
                              hipStream_t stream)
{
    const float* x   = (const float*)d_in[0];
    const float* wv  = (const float*)d_in[1];
    const float* eps = (const float*)d_in[2];
    const float* c1w = (const float*)d_in[3];
    const float* c1b = (const float*)d_in[4];
    const float* c2w = (const float*)d_in[5];
    const float* c2b = (const float*)d_in[6];
    const float* Wih = (const float*)d_in[7];
    const float* Whh = (const float*)d_in[8];
    const float* bih = (const float*)d_in[9];
    const float* bhh = (const float*)d_in[10];
    const float* muw = (const float*)d_in[11];
    const float* mub = (const float*)d_in[12];
    const float* lsw = (const float*)d_in[13];
    const float* lsb = (const float*)d_in[14];

    float* ws     = (float*)d_ws;
    float* seq    = ws + SEQ_OFF;
    float* g      = ws + G_OFF;
    float* hstate = ws + HST_OFF;
    const short* awhh = (const short*)(ws + AWHH_OFF);
    const short* awih = (const short*)(ws + AWIH_OFF);
    float* muwp   = ws + MUWP_OFF;
    float* lswp   = ws + LSWP_OFF;
    float* gic    = ws + GIC_OFF;
    float* outp   = (float*)d_out;

    // chunk size over t, limited by workspace (deterministic given ws_size)
    const long per_t = 387L * 4096;
    long avail = (long)(ws_size / 4) - (long)GIC_OFF;
    int CT = 60;
    if (avail < 60 * per_t) {
        CT = (int)(avail / per_t);
        if (CT < 1) CT = 1;
        if (CT > 60) CT = 60;
    }

    const int prep_elems = 25 * 5 * 2 * 512 + 25 * 4 * 2 * 512 + 2 * (129 * 260);
    prep_pad<<<(prep_elems + 255) / 256, 256, 0, stream>>>(Whh, Wih, muw, lsw, ws);
    conv_fused<<<dim3(6, BTOT), 256, 0, stream>>>(x, c1w, c1b, c2w, c2b, seq);

    for (int t0 = 0; t0 < 60; t0 += CT) {
        int nt = 60 - t0; if (nt > CT) nt = CT;
        gi_mfma<<<dim3(32, 25), 512, 0, stream>>>(seq, awih, gic, t0, nt);
        gru_mfma<<<256, 512, 0, stream>>>(gic, awhh, bih, bhh, hstate, g, t0, nt);
    }
    head_kernel<<<BTOT / 16, 256, 0, stream>>>(g, wv, eps, muwp, lswp, mub, lsb, outp);
}

// Round 20
// 1641.999 us; speedup vs baseline: 1.3364x; 1.0532x over previous
//
#include <hip/hip_runtime.h>
#include <math.h>

// Problem constants
#define BTOT   4096
#define CIN    3
#define TIN    64
#define SIN    128

// ws layout (float offsets)
#define SEQ_OFF    0                            // [4096][60][124]
#define G_OFF      (SEQ_OFF + 4096*60*124)      // [4096][129]
#define HST_OFF    (G_OFF + 4096*129)           // [4096][132] h state between chunks
#define AWHH_OFF   (HST_OFF + 4096*132)         // [25][5][2][64][8] bf16 Whh frags
#define AWIH_OFF   (AWHH_OFF + 64000)           // [25][4][2][64][8] bf16 Wih frags
#define MUWP_OFF   (AWIH_OFF + 51200)           // [129][260]
#define LSWP_OFF   (MUWP_OFF + 129*260)         // [129][260]
#define GIC_OFF    (LSWP_OFF + 129*260)         // [CT][387][4096] gi chunk

typedef __attribute__((ext_vector_type(8))) short bf16x8;
typedef __attribute__((ext_vector_type(4))) float f32x4;

// Inline transcendentals (no libm calls in hot loops)
__device__ __forceinline__ float fast_tanh(float x) {
    float ax = fabsf(x);
    float t  = __expf(-2.f * ax);
    float r  = (1.f - t) / (1.f + t);
    return copysignf(r, x);
}
__device__ __forceinline__ float fast_sigmoid(float x) {
    return 1.f / (1.f + __expf(-x));
}
// bf16 round-to-nearest-even helpers (bit ops only)
__device__ __forceinline__ unsigned short f2bf(float x) {
    unsigned int u = __float_as_uint(x);
    unsigned int r = u + 0x7FFFu + ((u >> 16) & 1u);
    return (unsigned short)(r >> 16);
}
__device__ __forceinline__ float bf2f(unsigned short b) {
    return __uint_as_float(((unsigned int)b) << 16);
}

// ---------------------------------------------------------------------------
// Prep: bf16 hi/lo fragment tables for Whh (5 k-tiles) and Wih (4 k-tiles),
// plus fc weight padding. (Passing R18/R19.)
// ---------------------------------------------------------------------------
__global__ __launch_bounds__(256) void prep_pad(
    const float* __restrict__ Whh, const float* __restrict__ Wih,
    const float* __restrict__ muw, const float* __restrict__ lsw,
    float* __restrict__ ws)
{
    int idx = blockIdx.x * 256 + threadIdx.x;
    const int NHH = 25 * 5 * 2 * 512;   // 128000 shorts
    const int NIA = 25 * 4 * 2 * 512;   // 102400 shorts
    const int N2  = 129 * 260;
    if (idx < NHH) {
        int a      = idx;
        int frag   = a >> 9;
        int within = a & 511;
        int l      = within >> 3;
        int c      = within & 7;
        int half   = frag & 1;
        int q      = frag >> 1;
        int kt     = q % 5;
        int jt     = q / 5;
        int j      = jt * 16 + (l & 15);
        int k      = kt * 32 + (l >> 4) * 8 + c;
        float v    = (j < 387 && k < 129) ? Whh[(size_t)j * 129 + k] : 0.f;
        unsigned short hb = f2bf(v);
        ((short*)(ws + AWHH_OFF))[a] = (short)((half == 0) ? hb : f2bf(v - bf2f(hb)));
    } else if (idx < NHH + NIA) {
        int a      = idx - NHH;
        int frag   = a >> 9;
        int within = a & 511;
        int l      = within >> 3;
        int c      = within & 7;
        int half   = frag & 1;
        int q      = frag >> 1;
        int kt     = q & 3;
        int jt     = q >> 2;
        int j      = jt * 16 + (l & 15);
        int k      = kt * 32 + (l >> 4) * 8 + c;
        float v    = (j < 387 && k < 124) ? Wih[(size_t)j * 124 + k] : 0.f;
        unsigned short hb = f2bf(v);
        ((short*)(ws + AWIH_OFF))[a] = (short)((half == 0) ? hb : f2bf(v - bf2f(hb)));
    } else if (idx < NHH + NIA + N2) {
        int i = idx - NHH - NIA; int j = i / 260, k = i - j * 260;
        ws[MUWP_OFF + i] = (k < 258) ? muw[j * 258 + k] : 0.f;
    } else if (idx < NHH + NIA + 2 * N2) {
        int i = idx - NHH - NIA - N2; int j = i / 260, k = i - j * 260;
        ws[LSWP_OFF + i] = (k < 258) ? lsw[j * 258 + k] : 0.f;
    }
}

// ---------------------------------------------------------------------------
// conv_fused v3 (R20): conv1 reads x DIRECT from global (L1-cached,
// coalesced 512B/wave) into a register-resident rolling 3-row window
// (named scalars, period-3 rotation, 12x unrolled). No xt LDS stage:
// LDS holds only h1t (37 KB) -> 4 blocks/CU (was 2). conv1 LDS ops
// drop ~650 -> 36 wave-instr/block. conv2 unchanged (reads h1t).
// f2 halo at s0=124 clamped to col 122 (feeds only junk cols 126/127,
// which conv2 never reads; avoids cross-row/OOB reads).
// ---------------------------------------------------------------------------
#define RACC(F4_, F2_, W0_, W1_, W2_) \
    acc0 += (F4_).x*(W0_) + (F4_).y*(W1_) + (F4_).z*(W2_); \
    acc1 += (F4_).y*(W0_) + (F4_).z*(W1_) + (F4_).w*(W2_); \
    acc2 += (F4_).z*(W0_) + (F4_).w*(W1_) + (F2_).x*(W2_); \
    acc3 += (F4_).w*(W0_) + (F2_).x*(W1_) + (F2_).y*(W2_);

#define LDSET(S, TR_) { \
    S##0_4 = *(const float4*)(xc0 + (TR_) * 128 + s0); \
    S##0_2 = *(const float2*)(xc0 + (TR_) * 128 + f2c); \
    S##1_4 = *(const float4*)(xc1 + (TR_) * 128 + s0); \
    S##1_2 = *(const float2*)(xc1 + (TR_) * 128 + f2c); \
    S##2_4 = *(const float4*)(xc2 + (TR_) * 128 + s0); \
    S##2_2 = *(const float2*)(xc2 + (TR_) * 128 + f2c); }

#define C1STEP(SA, SB, SC, TQ_) { \
    float acc0 = bo, acc1 = bo, acc2 = bo, acc3 = bo; \
    RACC(SA##0_4, SA##0_2, w000, w001, w002) \
    RACC(SA##1_4, SA##1_2, w100, w101, w102) \
    RACC(SA##2_4, SA##2_2, w200, w201, w202) \
    RACC(SB##0_4, SB##0_2, w010, w011, w012) \
    RACC(SB##1_4, SB##1_2, w110, w111, w112) \
    RACC(SB##2_4, SB##2_2, w210, w211, w212) \
    RACC(SC##0_4, SC##0_2, w020, w021, w022) \
    RACC(SC##1_4, SC##1_2, w120, w121, w122) \
    RACC(SC##2_4, SC##2_2, w220, w221, w222) \
    float4 r_; \
    r_.x = (acc0 >= 0.f) ? acc0 : 0.01f * acc0; \
    r_.y = (acc1 >= 0.f) ? acc1 : 0.01f * acc1; \
    r_.z = (acc2 >= 0.f) ? acc2 : 0.01f * acc2; \
    r_.w = (acc3 >= 0.f) ? acc3 : 0.01f * acc3; \
    *(float4*)(h1t + (o * 12 + (TQ_)) * 128 + s0) = r_; }

#define C2SEG(o_, kt_, W0_, W1_, W2_) { \
    const float* rp_ = h1t + ((o_) * 12 + tq + (kt_)) * 128 + s0; \
    float4 v4_ = *(const float4*)rp_; \
    float2 v2_ = *(const float2*)(rp_ + 4); \
    acc0 += v4_.x*(W0_) + v4_.y*(W1_) + v4_.z*(W2_); \
    acc1 += v4_.y*(W0_) + v4_.z*(W1_) + v4_.w*(W2_); \
    acc2 += v4_.z*(W0_) + v4_.w*(W1_) + v2_.x*(W2_); \
    acc3 += v4_.w*(W0_) + v2_.x*(W1_) + v2_.y*(W2_); }

__global__ __launch_bounds__(256) void conv_fused(
    const float* __restrict__ x,
    const float* __restrict__ w1, const float* __restrict__ b1,
    const float* __restrict__ w2, const float* __restrict__ b2,
    float* __restrict__ seq)
{
    __shared__ __attribute__((aligned(16))) float h1t[6 * 12 * 128];
    __shared__ float w1s[162];
    __shared__ float w2s[54];
    __shared__ float b1s[6];
    __shared__ float b2s;

    const int tid  = threadIdx.x;
    const int tile = blockIdx.x;   // 0..5
    const int bb   = blockIdx.y;   // batch
    const int T0   = tile * 10;

    if (tid < 162)                  w1s[tid] = w1[tid];
    if (tid >= 192 && tid < 246)    w2s[tid - 192] = w2[tid - 192];
    if (tid >= 248 && tid < 254)    b1s[tid - 248] = b1[tid - 248];
    if (tid == 255)                 b2s = b2[0];
    __syncthreads();

    // ---- conv1 + leaky: tid<192, thread = (o, 4-col group), rolling window --
    if (tid < 192) {
        const int o   = tid >> 5;
        const int s0  = (tid & 31) * 4;
        const int f2c = (s0 < 124) ? (s0 + 4) : 122;   // clamp: junk cols only
        const float* wb = w1s + o * 27;
        float w000 = wb[0],  w001 = wb[1],  w002 = wb[2];
        float w010 = wb[3],  w011 = wb[4],  w012 = wb[5];
        float w020 = wb[6],  w021 = wb[7],  w022 = wb[8];
        float w100 = wb[9],  w101 = wb[10], w102 = wb[11];
        float w110 = wb[12], w111 = wb[13], w112 = wb[14];
        float w120 = wb[15], w121 = wb[16], w122 = wb[17];
        float w200 = wb[18], w201 = wb[19], w202 = wb[20];
        float w210 = wb[21], w211 = wb[22], w212 = wb[23];
        float w220 = wb[24], w221 = wb[25], w222 = wb[26];
        float bo = b1s[o];

        const float* xc0 = x + (size_t)bb * (3 * 64 * 128) + (size_t)T0 * 128;
        const float* xc1 = xc0 + 64 * 128;
        const float* xc2 = xc0 + 2 * 64 * 128;

        float4 A0_4, A1_4, A2_4, B0_4, B1_4, B2_4, C0_4, C1_4, C2_4;
        float2 A0_2, A1_2, A2_2, B0_2, B1_2, B2_2, C0_2, C1_2, C2_2;

        LDSET(A, 0)
        LDSET(B, 1)
        LDSET(C, 2)  C1STEP(A, B, C, 0)
        LDSET(A, 3)  C1STEP(B, C, A, 1)
        LDSET(B, 4)  C1STEP(C, A, B, 2)
        LDSET(C, 5)  C1STEP(A, B, C, 3)
        LDSET(A, 6)  C1STEP(B, C, A, 4)
        LDSET(B, 7)  C1STEP(C, A, B, 5)
        LDSET(C, 8)  C1STEP(A, B, C, 6)
        LDSET(A, 9)  C1STEP(B, C, A, 7)
        LDSET(B, 10) C1STEP(C, A, B, 8)
        LDSET(C, 11) C1STEP(A, B, C, 9)
        LDSET(A, 12) C1STEP(B, C, A, 10)
        LDSET(B, 13) C1STEP(C, A, B, 11)
    }
    __syncthreads();

    // ---- conv2 + leaky: 310 tasks = (t in [0,10), sg in [0,31)) ----
    {
        float u000 = w2s[0],  u001 = w2s[1],  u002 = w2s[2];
        float u010 = w2s[3],  u011 = w2s[4],  u012 = w2s[5];
        float u020 = w2s[6],  u021 = w2s[7],  u022 = w2s[8];
        float u100 = w2s[9],  u101 = w2s[10], u102 = w2s[11];
        float u110 = w2s[12], u111 = w2s[13], u112 = w2s[14];
        float u120 = w2s[15], u121 = w2s[16], u122 = w2s[17];
        float u200 = w2s[18], u201 = w2s[19], u202 = w2s[20];
        float u210 = w2s[21], u211 = w2s[22], u212 = w2s[23];
        float u220 = w2s[24], u221 = w2s[25], u222 = w2s[26];
        float u300 = w2s[27], u301 = w2s[28], u302 = w2s[29];
        float u310 = w2s[30], u311 = w2s[31], u312 = w2s[32];
        float u320 = w2s[33], u321 = w2s[34], u322 = w2s[35];
        float u400 = w2s[36], u401 = w2s[37], u402 = w2s[38];
        float u410 = w2s[39], u411 = w2s[40], u412 = w2s[41];
        float u420 = w2s[42], u421 = w2s[43], u422 = w2s[44];
        float u500 = w2s[45], u501 = w2s[46], u502 = w2s[47];
        float u510 = w2s[48], u511 = w2s[49], u512 = w2s[50];
        float u520 = w2s[51], u521 = w2s[52], u522 = w2s[53];
        float bo2 = b2s;
        for (int idx = tid; idx < 310; idx += 256) {
            const int tq = idx / 31;
            const int s0 = (idx - tq * 31) * 4;
            float acc0 = bo2, acc1 = bo2, acc2 = bo2, acc3 = bo2;
            C2SEG(0, 0, u000, u001, u002)
            C2SEG(0, 1, u010, u011, u012)
            C2SEG(0, 2, u020, u021, u022)
            C2SEG(1, 0, u100, u101, u102)
            C2SEG(1, 1, u110, u111, u112)
            C2SEG(1, 2, u120, u121, u122)
            C2SEG(2, 0, u200, u201, u202)
            C2SEG(2, 1, u210, u211, u212)
            C2SEG(2, 2, u220, u221, u222)
            C2SEG(3, 0, u300, u301, u302)
            C2SEG(3, 1, u310, u311, u312)
            C2SEG(3, 2, u320, u321, u322)
            C2SEG(4, 0, u400, u401, u402)
            C2SEG(4, 1, u410, u411, u412)
            C2SEG(4, 2, u420, u421, u422)
            C2SEG(5, 0, u500, u501, u502)
            C2SEG(5, 1, u510, u511, u512)
            C2SEG(5, 2, u520, u521, u522)
            float4 r;
            r.x = (acc0 >= 0.f) ? acc0 : 0.01f * acc0;
            r.y = (acc1 >= 0.f) ? acc1 : 0.01f * acc1;
            r.z = (acc2 >= 0.f) ? acc2 : 0.01f * acc2;
            r.w = (acc3 >= 0.f) ? acc3 : 0.01f * acc3;
            *(float4*)(seq + ((size_t)bb * 60 + T0 + tq) * 124 + s0) = r;
        }
    }
}

// ---------------------------------------------------------------------------
// gi via MFMA (split bf16, hh+hl+lh) — passing R18/R19 (unchanged).
// ---------------------------------------------------------------------------
__global__ __launch_bounds__(512) void gi_mfma(
    const float* __restrict__ seq, const short* __restrict__ awih,
    float* __restrict__ gic, int t0, int nt)
{
    __shared__ __attribute__((aligned(16))) short Bs[4 * 2 * 128 * 5 * 8];

    const int tid = threadIdx.x;
    const int l   = tid & 63;
    const int w   = tid >> 6;          // n-tile 0..7
    const int jt  = blockIdx.y;        // 0..24
    const int b0  = blockIdx.x * 128;  // b-chunk base

    const bf16x8* at = (const bf16x8*)awih;
    const int abase = jt * 8 * 64 + l;
    bf16x8 Ah0 = at[abase + 0 * 128];
    bf16x8 Al0 = at[abase + 0 * 128 + 64];
    bf16x8 Ah1 = at[abase + 1 * 128];
    bf16x8 Al1 = at[abase + 1 * 128 + 64];
    bf16x8 Ah2 = at[abase + 2 * 128];
    bf16x8 Al2 = at[abase + 2 * 128 + 64];
    bf16x8 Ah3 = at[abase + 3 * 128];
    bf16x8 Al3 = at[abase + 3 * 128 + 64];

    if (tid < 128) {
        *(unsigned long long*)(Bs + ((6 * 128 + tid) * 5 + 3) * 8 + 4) = 0ull;
        *(unsigned long long*)(Bs + ((7 * 128 + tid) * 5 + 3) * 8 + 4) = 0ull;
    }
    __syncthreads();

    for (int tt = 0; tt < nt; ++tt) {
        const int t = t0 + tt;
        for (int f = tid; f < 3968; f += 512) {
            int bi = f / 31;
            int kf = f - bi * 31;
            float4 v = *(const float4*)(seq + ((size_t)(b0 + bi) * 60 + t) * 124 + kf * 4);
            int k0   = kf * 4;
            int kt   = k0 >> 5;
            int ksub = (k0 >> 3) & 3;
            int c0   = k0 & 7;
            unsigned short h0 = f2bf(v.x), h1 = f2bf(v.y), h2 = f2bf(v.z), h3 = f2bf(v.w);
            unsigned short l0 = f2bf(v.x - bf2f(h0));
            unsigned short l1 = f2bf(v.y - bf2f(h1));
            unsigned short l2 = f2bf(v.z - bf2f(h2));
            unsigned short l3 = f2bf(v.w - bf2f(h3));
            unsigned long long hp = (unsigned long long)h0 | ((unsigned long long)h1 << 16)
                                  | ((unsigned long long)h2 << 32) | ((unsigned long long)h3 << 48);
            unsigned long long lp = (unsigned long long)l0 | ((unsigned long long)l1 << 16)
                                  | ((unsigned long long)l2 << 32) | ((unsigned long long)l3 << 48);
            *(unsigned long long*)(Bs + (((kt * 2 + 0) * 128 + bi) * 5 + ksub) * 8 + c0) = hp;
            *(unsigned long long*)(Bs + (((kt * 2 + 1) * 128 + bi) * 5 + ksub) * 8 + c0) = lp;
        }
        __syncthreads();

        f32x4 acc = {0.f, 0.f, 0.f, 0.f};
        const int bn   = w * 16 + (l & 15);
        const int ksub = l >> 4;
        #define GI_KT(KT, AH, AL) { \
            bf16x8 bh = *(const bf16x8*)(Bs + ((((KT) * 2 + 0) * 128 + bn) * 5 + ksub) * 8); \
            bf16x8 bl = *(const bf16x8*)(Bs + ((((KT) * 2 + 1) * 128 + bn) * 5 + ksub) * 8); \
            acc = __builtin_amdgcn_mfma_f32_16x16x32_bf16(AL, bh, acc, 0, 0, 0); \
            acc = __builtin_amdgcn_mfma_f32_16x16x32_bf16(AH, bl, acc, 0, 0, 0); \
            acc = __builtin_amdgcn_mfma_f32_16x16x32_bf16(AH, bh, acc, 0, 0, 0); }
        GI_KT(0, Ah0, Al0)
        GI_KT(1, Ah1, Al1)
        GI_KT(2, Ah2, Al2)
        GI_KT(3, Ah3, Al3)
        #undef GI_KT

        {
            float* gt = gic + (size_t)tt * 387 * 4096;
            int row0 = (l >> 4) * 4;
            #pragma unroll
            for (int i = 0; i < 4; ++i) {
                int j = jt * 16 + row0 + i;
                if (j < 387)
                    gt[(size_t)j * 4096 + b0 + bn] = acc[i];
            }
        }
        __syncthreads();
    }
}

// ---------------------------------------------------------------------------
// GRU recurrence via MFMA (split bf16) — passing R19 (unchanged).
// ---------------------------------------------------------------------------
__global__ __launch_bounds__(512) void gru_mfma(
    const float* __restrict__ gic, const short* __restrict__ awhh,
    const float* __restrict__ bih, const float* __restrict__ bhh,
    float* __restrict__ hstate, float* __restrict__ g_out,
    int t0, int nt)
{
    __shared__ __attribute__((aligned(16))) short hbf[2 * 16 * 168];
    __shared__ float hs2[16 * 132];
    __shared__ float GHb[16 * 390];
    __shared__ float bihS[387];
    __shared__ float bhhS[387];

    const int tid  = threadIdx.x;
    const int l    = tid & 63;
    const int w    = tid >> 6;        // wave 0..7
    const int b0   = blockIdx.x * 16;
    const int bcol = l & 15;
    const int krow = l >> 4;

    if (tid < 387) { bihS[tid] = bih[tid]; bhhS[tid] = bhh[tid]; }
    for (int e = tid; e < 2688; e += 512) ((unsigned int*)hbf)[e] = 0u;
    if (t0 == 0) {
        for (int e = tid; e < 16 * 132; e += 512) hs2[e] = 0.f;
        __syncthreads();
    } else {
        for (int e = tid; e < 16 * 132; e += 512) hs2[e] = hstate[(size_t)b0 * 132 + e];
        __syncthreads();
        for (int e = tid; e < 2064; e += 512) {
            int r = e & 15, j = e >> 4;
            float v = hs2[r * 132 + j];
            unsigned short hb = f2bf(v);
            hbf[r * 168 + j]        = (short)hb;
            hbf[2688 + r * 168 + j] = (short)f2bf(v - bf2f(hb));
        }
        __syncthreads();
    }

    const bf16x8* at = (const bf16x8*)awhh;

    #define GATE(E, PGA, PGB, PGC) { \
        int r_ = (E) & 15, j_ = (E) >> 4; \
        float pr_  = (PGA) + GHb[r_ * 390 + j_]       + bihS[j_]       + bhhS[j_]; \
        float pz_  = (PGB) + GHb[r_ * 390 + 129 + j_] + bihS[129 + j_] + bhhS[129 + j_]; \
        float gin_ = (PGC) + bihS[258 + j_]; \
        float ghn_ = GHb[r_ * 390 + 258 + j_] + bhhS[258 + j_]; \
        float rg_ = fast_sigmoid(pr_); \
        float zg_ = fast_sigmoid(pz_); \
        float nn_ = fast_tanh(gin_ + rg_ * ghn_); \
        float hn_ = (1.f - zg_) * nn_ + zg_ * hs2[r_ * 132 + j_]; \
        hs2[r_ * 132 + j_] = hn_; \
        unsigned short hb_ = f2bf(hn_); \
        hbf[r_ * 168 + j_]        = (short)hb_; \
        hbf[2688 + r_ * 168 + j_] = (short)f2bf(hn_ - bf2f(hb_)); }

    for (int tt = 0; tt < nt; ++tt) {
        const float* gib = gic + (size_t)tt * 387 * 4096 + b0;
        float pa0, pb0, pc0, pa1, pb1, pc1, pa2, pb2, pc2, pa3, pb3, pc3;
        {
            int r = tid & 15, j = tid >> 4;
            pa0 = gib[(size_t)j * 4096 + r];
            pb0 = gib[(size_t)(129 + j) * 4096 + r];
            pc0 = gib[(size_t)(258 + j) * 4096 + r];
            int e = tid + 512; r = e & 15; j = e >> 4;
            pa1 = gib[(size_t)j * 4096 + r];
            pb1 = gib[(size_t)(129 + j) * 4096 + r];
            pc1 = gib[(size_t)(258 + j) * 4096 + r];
            e = tid + 1024; r = e & 15; j = e >> 4;
            pa2 = gib[(size_t)j * 4096 + r];
            pb2 = gib[(size_t)(129 + j) * 4096 + r];
            pc2 = gib[(size_t)(258 + j) * 4096 + r];
            e = tid + 1536; r = e & 15; j = e >> 4;
            pa3 = gib[(size_t)j * 4096 + r];
            pb3 = gib[(size_t)(129 + j) * 4096 + r];
            pc3 = gib[(size_t)(258 + j) * 4096 + r];
        }

        f32x4 acc0 = {0.f,0.f,0.f,0.f}, acc1 = {0.f,0.f,0.f,0.f};
        f32x4 acc2 = {0.f,0.f,0.f,0.f}, acc3 = {0.f,0.f,0.f,0.f};
        #pragma unroll
        for (int kt = 0; kt < 5; ++kt) {
            bf16x8 bh = *(const bf16x8*)(hbf + bcol * 168 + kt * 32 + krow * 8);
            bf16x8 bl = *(const bf16x8*)(hbf + 2688 + bcol * 168 + kt * 32 + krow * 8);
            {
                int fb = ((w * 5 + kt) * 2) * 64 + l;
                bf16x8 Ah = at[fb], Al = at[fb + 64];
                acc0 = __builtin_amdgcn_mfma_f32_16x16x32_bf16(Al, bh, acc0, 0, 0, 0);
                acc0 = __builtin_amdgcn_mfma_f32_16x16x32_bf16(Ah, bl, acc0, 0, 0, 0);
                acc0 = __builtin_amdgcn_mfma_f32_16x16x32_bf16(Ah, bh, acc0, 0, 0, 0);
            }
            {
                int fb = (((8 + w) * 5 + kt) * 2) * 64 + l;
                bf16x8 Ah = at[fb], Al = at[fb + 64];
                acc1 = __builtin_amdgcn_mfma_f32_16x16x32_bf16(Al, bh, acc1, 0, 0, 0);
                acc1 = __builtin_amdgcn_mfma_f32_16x16x32_bf16(Ah, bl, acc1, 0, 0, 0);
                acc1 = __builtin_amdgcn_mfma_f32_16x16x32_bf16(Ah, bh, acc1, 0, 0, 0);
            }
            {
                int fb = (((16 + w) * 5 + kt) * 2) * 64 + l;
                bf16x8 Ah = at[fb], Al = at[fb + 64];
                acc2 = __builtin_amdgcn_mfma_f32_16x16x32_bf16(Al, bh, acc2, 0, 0, 0);
                acc2 = __builtin_amdgcn_mfma_f32_16x16x32_bf16(Ah, bl, acc2, 0, 0, 0);
                acc2 = __builtin_amdgcn_mfma_f32_16x16x32_bf16(Ah, bh, acc2, 0, 0, 0);
            }
            if (w == 0) {
                int fb = ((24 * 5 + kt) * 2) * 64 + l;
                bf16x8 Ah = at[fb], Al = at[fb + 64];
                acc3 = __builtin_amdgcn_mfma_f32_16x16x32_bf16(Al, bh, acc3, 0, 0, 0);
                acc3 = __builtin_amdgcn_mfma_f32_16x16x32_bf16(Ah, bl, acc3, 0, 0, 0);
                acc3 = __builtin_amdgcn_mfma_f32_16x16x32_bf16(Ah, bh, acc3, 0, 0, 0);
            }
        }
        {
            int rb = bcol * 390;
            int j0 = w * 16 + krow * 4;
            GHb[rb + j0 + 0] = acc0[0];
            GHb[rb + j0 + 1] = acc0[1];
            GHb[rb + j0 + 2] = acc0[2];
            GHb[rb + j0 + 3] = acc0[3];
            int j1 = (8 + w) * 16 + krow * 4;
            GHb[rb + j1 + 0] = acc1[0];
            GHb[rb + j1 + 1] = acc1[1];
            GHb[rb + j1 + 2] = acc1[2];
            GHb[rb + j1 + 3] = acc1[3];
            int j2 = (16 + w) * 16 + krow * 4;
            GHb[rb + j2 + 0] = acc2[0];
            GHb[rb + j2 + 1] = acc2[1];
            GHb[rb + j2 + 2] = acc2[2];
            GHb[rb + j2 + 3] = acc2[3];
            if (w == 0 && krow == 0) {
                GHb[rb + 384] = acc3[0];
                GHb[rb + 385] = acc3[1];
                GHb[rb + 386] = acc3[2];
            }
        }
        __syncthreads();

        GATE(tid,        pa0, pb0, pc0)
        GATE(tid + 512,  pa1, pb1, pc1)
        GATE(tid + 1024, pa2, pb2, pc2)
        GATE(tid + 1536, pa3, pb3, pc3)
        if (tid < 16) {
            float ta = gib[(size_t)128 * 4096 + tid];
            float tb = gib[(size_t)257 * 4096 + tid];
            float tc = gib[(size_t)386 * 4096 + tid];
            GATE(2048 + tid, ta, tb, tc)
        }
        __syncthreads();
    }

    for (int e = tid; e < 16 * 132; e += 512) hstate[(size_t)b0 * 132 + e] = hs2[e];
    if (t0 + nt >= 60) {
        for (int e = tid; e < 2064; e += 512) {
            int r = e & 15, j = e >> 4;
            float v = hs2[r * 132 + j];
            g_out[(size_t)(b0 + r) * 129 + j] = (v >= 0.f) ? v : 0.01f * v;
        }
        if (tid < 16) {
            float v = hs2[tid * 132 + 128];
            g_out[(size_t)(b0 + tid) * 129 + 128] = (v >= 0.f) ? v : 0.01f * v;
        }
    }
    #undef GATE
}

// ---------------------------------------------------------------------------
// Head: feat=[g,w] (258) -> mu, log_std -> sample, tanh, log_pi, normalize.
// ---------------------------------------------------------------------------
__global__ __launch_bounds__(256) void head_kernel(
    const float* __restrict__ gbuf, const float* __restrict__ wvec,
    const float* __restrict__ eps,
    const float* __restrict__ muwp, const float* __restrict__ lswp,
    const float* __restrict__ mub,  const float* __restrict__ lsb,
    float* __restrict__ out)
{
    __shared__ __attribute__((aligned(16))) float feat[16 * 260];
    __shared__ float PA[16 * 130];
    __shared__ float TERM[16 * 130];
    __shared__ float ROWSUM[16];
    __shared__ float ROWLOG[16];

    const int tid = threadIdx.x;
    const int b0  = blockIdx.x * 16;

    for (int i = tid; i < 16 * 260; i += 256) {
        int r = i / 260;
        int k = i - r * 260;
        float v = 0.f;
        if (k < 129)       v = gbuf[(size_t)(b0 + r) * 129 + k];
        else if (k < 258)  v = wvec[(size_t)(b0 + r) * 129 + (k - 129)];
        feat[i] = v;
    }
    __syncthreads();

    for (int idx = tid; idx < 16 * 129; idx += 256) {
        int r = idx & 15;
        int j = idx >> 4;
        const float4* fv = (const float4*)(feat + r * 260);
        const float4* mw = (const float4*)(muwp + (size_t)j * 260);
        const float4* lw = (const float4*)(lswp + (size_t)j * 260);
        float am = 0.f, al = 0.f;
        for (int k = 0; k < 65; ++k) {
            float4 f = fv[k];
            float4 m = mw[k];
            float4 l = lw[k];
            am += f.x * m.x + f.y * m.y + f.z * m.z + f.w * m.w;
            al += f.x * l.x + f.y * l.y + f.z * l.z + f.w * l.w;
        }
        float mu = am + mub[j];
        float ls = fminf(fmaxf(al + lsb[j], -20.f), 2.f);
        float sd = __expf(ls);
        float e  = eps[(size_t)(b0 + r) * 129 + j];
        float xv = mu + sd * e;
        float pa = fast_tanh(xv);
        float tt = (xv - mu) / sd;
        float term = -0.5f * tt * tt - ls - 0.91893853320467274f
                     - __logf(1.f - pa * pa + 1e-6f);
        PA[r * 130 + j]   = pa;
        TERM[r * 130 + j] = term;
    }
    __syncthreads();

    {
        int r = tid >> 4;
        int i = tid & 15;
        float sp = 0.f, st = 0.f;
        for (int j = i; j < 129; j += 16) {
            sp += PA[r * 130 + j];
            st += TERM[r * 130 + j];
        }
        for (int off = 8; off > 0; off >>= 1) {
            sp += __shfl_down(sp, off, 16);
            st += __shfl_down(st, off, 16);
        }
        if (i == 0) { ROWSUM[r] = sp + 129.f; ROWLOG[r] = st; }
    }
    __syncthreads();

    for (int idx = tid; idx < 16 * 129; idx += 256) {
        int r = idx & 15;
        int j = idx >> 4;
        out[(size_t)(b0 + r) * 129 + j] = (PA[r * 130 + j] + 1.f) / ROWSUM[r];
    }
    if (tid < 16)
        out[(size_t)4096 * 129 + b0 + tid] = ROWLOG[tid];
}

// ---------------------------------------------------------------------------
extern "C" void kernel_launch(void* const* d_in, const int* in_sizes, int n_in,
                              void* d_out, int out_size, void* d_ws, size_t ws_size,
                              hipStream_t stream)
{
    const float* x   = (const float*)d_in[0];
    const float* wv  = (const float*)d_in[1];
    const float* eps = (const float*)d_in[2];
    const float* c1w = (const float*)d_in[3];
    const float* c1b = (const float*)d_in[4];
    const float* c2w = (const float*)d_in[5];
    const float* c2b = (const float*)d_in[6];
    const float* Wih = (const float*)d_in[7];
    const float* Whh = (const float*)d_in[8];
    const float* bih = (const float*)d_in[9];
    const float* bhh = (const float*)d_in[10];
    const float* muw = (const float*)d_in[11];
    const float* mub = (const float*)d_in[12];
    const float* lsw = (const float*)d_in[13];
    const float* lsb = (const float*)d_in[14];

    float* ws     = (float*)d_ws;
    float* seq    = ws + SEQ_OFF;
    float* g      = ws + G_OFF;
    float* hstate = ws + HST_OFF;
    const short* awhh = (const short*)(ws + AWHH_OFF);
    const short* awih = (const short*)(ws + AWIH_OFF);
    float* muwp   = ws + MUWP_OFF;
    float* lswp   = ws + LSWP_OFF;
    float* gic    = ws + GIC_OFF;
    float* outp   = (float*)d_out;

    // chunk size over t, limited by workspace (deterministic given ws_size)
    const long per_t = 387L * 4096;
    long avail = (long)(ws_size / 4) - (long)GIC_OFF;
    int CT = 60;
    if (avail < 60 * per_t) {
        CT = (int)(avail / per_t);
        if (CT < 1) CT = 1;
        if (CT > 60) CT = 60;
    }

    const int prep_elems = 25 * 5 * 2 * 512 + 25 * 4 * 2 * 512 + 2 * (129 * 260);
    prep_pad<<<(prep_elems + 255) / 256, 256, 0, stream>>>(Whh, Wih, muw, lsw, ws);
    conv_fused<<<dim3(6, BTOT), 256, 0, stream>>>(x, c1w, c1b, c2w, c2b, seq);

    for (int t0 = 0; t0 < 60; t0 += CT) {
        int nt = 60 - t0; if (nt > CT) nt = CT;
        gi_mfma<<<dim3(32, 25), 512, 0, stream>>>(seq, awih, gic, t0, nt);
        gru_mfma<<<256, 512, 0, stream>>>(gic, awhh, bih, bhh, hstate, g, t0, nt);
    }
    head_kernel<<<BTOT / 16, 256, 0, stream>>>(g, wv, eps, muwp, lswp, mub, lsb, outp);
}

// Round 21
// 1510.083 us; speedup vs baseline: 1.4532x; 1.0874x over previous
//
#include <hip/hip_runtime.h>
#include <math.h>

// Problem constants
#define BTOT   4096
#define CIN    3
#define TIN    64
#define SIN    128

// ws layout (float offsets)
#define SEQ_OFF    0                            // [4096][60][124]
#define G_OFF      (SEQ_OFF + 4096*60*124)      // [4096][129]
#define HST_OFF    (G_OFF + 4096*129)           // [4096][132] h state between chunks
#define AWHH_OFF   (HST_OFF + 4096*132)         // [25][5][2][64][8] bf16 Whh frags
#define AWIH_OFF   (AWHH_OFF + 64000)           // [25][4][2][64][8] bf16 Wih frags
#define MUWP_OFF   (AWIH_OFF + 51200)           // [129][260]
#define LSWP_OFF   (MUWP_OFF + 129*260)         // [129][260]
#define BUF_OFF    (LSWP_OFF + 129*260)         // seqbf[CT][32][10240 ull] ++ gic[CT][387][4096]

// per-t float sizes for chunking
#define PER_T_GIC   (387 * 4096)
#define PER_T_SBF   655360                       // 32*40960 shorts = 655360 float slots
#define SBF_T_SH    1310720                      // shorts per t

typedef __attribute__((ext_vector_type(8))) short bf16x8;
typedef __attribute__((ext_vector_type(4))) float f32x4;

// Inline transcendentals (no libm calls in hot loops)
__device__ __forceinline__ float fast_tanh(float x) {
    float ax = fabsf(x);
    float t  = __expf(-2.f * ax);
    float r  = (1.f - t) / (1.f + t);
    return copysignf(r, x);
}
__device__ __forceinline__ float fast_sigmoid(float x) {
    return 1.f / (1.f + __expf(-x));
}
// bf16 round-to-nearest-even helpers (bit ops only)
__device__ __forceinline__ unsigned short f2bf(float x) {
    unsigned int u = __float_as_uint(x);
    unsigned int r = u + 0x7FFFu + ((u >> 16) & 1u);
    return (unsigned short)(r >> 16);
}
__device__ __forceinline__ float bf2f(unsigned short b) {
    return __uint_as_float(((unsigned int)b) << 16);
}

// ---------------------------------------------------------------------------
// Prep: bf16 hi/lo fragment tables for Whh (5 k-tiles) and Wih (4 k-tiles),
// plus fc weight padding. (Passing R18/R19.)
// ---------------------------------------------------------------------------
__global__ __launch_bounds__(256) void prep_pad(
    const float* __restrict__ Whh, const float* __restrict__ Wih,
    const float* __restrict__ muw, const float* __restrict__ lsw,
    float* __restrict__ ws)
{
    int idx = blockIdx.x * 256 + threadIdx.x;
    const int NHH = 25 * 5 * 2 * 512;   // 128000 shorts
    const int NIA = 25 * 4 * 2 * 512;   // 102400 shorts
    const int N2  = 129 * 260;
    if (idx < NHH) {
        int a      = idx;
        int frag   = a >> 9;
        int within = a & 511;
        int l      = within >> 3;
        int c      = within & 7;
        int half   = frag & 1;
        int q      = frag >> 1;
        int kt     = q % 5;
        int jt     = q / 5;
        int j      = jt * 16 + (l & 15);
        int k      = kt * 32 + (l >> 4) * 8 + c;
        float v    = (j < 387 && k < 129) ? Whh[(size_t)j * 129 + k] : 0.f;
        unsigned short hb = f2bf(v);
        ((short*)(ws + AWHH_OFF))[a] = (short)((half == 0) ? hb : f2bf(v - bf2f(hb)));
    } else if (idx < NHH + NIA) {
        int a      = idx - NHH;
        int frag   = a >> 9;
        int within = a & 511;
        int l      = within >> 3;
        int c      = within & 7;
        int half   = frag & 1;
        int q      = frag >> 1;
        int kt     = q & 3;
        int jt     = q >> 2;
        int j      = jt * 16 + (l & 15);
        int k      = kt * 32 + (l >> 4) * 8 + c;
        float v    = (j < 387 && k < 124) ? Wih[(size_t)j * 124 + k] : 0.f;
        unsigned short hb = f2bf(v);
        ((short*)(ws + AWIH_OFF))[a] = (short)((half == 0) ? hb : f2bf(v - bf2f(hb)));
    } else if (idx < NHH + NIA + N2) {
        int i = idx - NHH - NIA; int j = i / 260, k = i - j * 260;
        ws[MUWP_OFF + i] = (k < 258) ? muw[j * 258 + k] : 0.f;
    } else if (idx < NHH + NIA + 2 * N2) {
        int i = idx - NHH - NIA - N2; int j = i / 260, k = i - j * 260;
        ws[LSWP_OFF + i] = (k < 258) ? lsw[j * 258 + k] : 0.f;
    }
}

// ---------------------------------------------------------------------------
// conv_fused v3 — passing R20 (unchanged).
// ---------------------------------------------------------------------------
#define RACC(F4_, F2_, W0_, W1_, W2_) \
    acc0 += (F4_).x*(W0_) + (F4_).y*(W1_) + (F4_).z*(W2_); \
    acc1 += (F4_).y*(W0_) + (F4_).z*(W1_) + (F4_).w*(W2_); \
    acc2 += (F4_).z*(W0_) + (F4_).w*(W1_) + (F2_).x*(W2_); \
    acc3 += (F4_).w*(W0_) + (F2_).x*(W1_) + (F2_).y*(W2_);

#define LDSET(S, TR_) { \
    S##0_4 = *(const float4*)(xc0 + (TR_) * 128 + s0); \
    S##0_2 = *(const float2*)(xc0 + (TR_) * 128 + f2c); \
    S##1_4 = *(const float4*)(xc1 + (TR_) * 128 + s0); \
    S##1_2 = *(const float2*)(xc1 + (TR_) * 128 + f2c); \
    S##2_4 = *(const float4*)(xc2 + (TR_) * 128 + s0); \
    S##2_2 = *(const float2*)(xc2 + (TR_) * 128 + f2c); }

#define C1STEP(SA, SB, SC, TQ_) { \
    float acc0 = bo, acc1 = bo, acc2 = bo, acc3 = bo; \
    RACC(SA##0_4, SA##0_2, w000, w001, w002) \
    RACC(SA##1_4, SA##1_2, w100, w101, w102) \
    RACC(SA##2_4, SA##2_2, w200, w201, w202) \
    RACC(SB##0_4, SB##0_2, w010, w011, w012) \
    RACC(SB##1_4, SB##1_2, w110, w111, w112) \
    RACC(SB##2_4, SB##2_2, w210, w211, w212) \
    RACC(SC##0_4, SC##0_2, w020, w021, w022) \
    RACC(SC##1_4, SC##1_2, w120, w121, w122) \
    RACC(SC##2_4, SC##2_2, w220, w221, w222) \
    float4 r_; \
    r_.x = (acc0 >= 0.f) ? acc0 : 0.01f * acc0; \
    r_.y = (acc1 >= 0.f) ? acc1 : 0.01f * acc1; \
    r_.z = (acc2 >= 0.f) ? acc2 : 0.01f * acc2; \
    r_.w = (acc3 >= 0.f) ? acc3 : 0.01f * acc3; \
    *(float4*)(h1t + (o * 12 + (TQ_)) * 128 + s0) = r_; }

#define C2SEG(o_, kt_, W0_, W1_, W2_) { \
    const float* rp_ = h1t + ((o_) * 12 + tq + (kt_)) * 128 + s0; \
    float4 v4_ = *(const float4*)rp_; \
    float2 v2_ = *(const float2*)(rp_ + 4); \
    acc0 += v4_.x*(W0_) + v4_.y*(W1_) + v4_.z*(W2_); \
    acc1 += v4_.y*(W0_) + v4_.z*(W1_) + v4_.w*(W2_); \
    acc2 += v4_.z*(W0_) + v4_.w*(W1_) + v2_.x*(W2_); \
    acc3 += v4_.w*(W0_) + v2_.x*(W1_) + v2_.y*(W2_); }

__global__ __launch_bounds__(256) void conv_fused(
    const float* __restrict__ x,
    const float* __restrict__ w1, const float* __restrict__ b1,
    const float* __restrict__ w2, const float* __restrict__ b2,
    float* __restrict__ seq)
{
    __shared__ __attribute__((aligned(16))) float h1t[6 * 12 * 128];
    __shared__ float w1s[162];
    __shared__ float w2s[54];
    __shared__ float b1s[6];
    __shared__ float b2s;

    const int tid  = threadIdx.x;
    const int tile = blockIdx.x;   // 0..5
    const int bb   = blockIdx.y;   // batch
    const int T0   = tile * 10;

    if (tid < 162)                  w1s[tid] = w1[tid];
    if (tid >= 192 && tid < 246)    w2s[tid - 192] = w2[tid - 192];
    if (tid >= 248 && tid < 254)    b1s[tid - 248] = b1[tid - 248];
    if (tid == 255)                 b2s = b2[0];
    __syncthreads();

    if (tid < 192) {
        const int o   = tid >> 5;
        const int s0  = (tid & 31) * 4;
        const int f2c = (s0 < 124) ? (s0 + 4) : 122;   // clamp: junk cols only
        const float* wb = w1s + o * 27;
        float w000 = wb[0],  w001 = wb[1],  w002 = wb[2];
        float w010 = wb[3],  w011 = wb[4],  w012 = wb[5];
        float w020 = wb[6],  w021 = wb[7],  w022 = wb[8];
        float w100 = wb[9],  w101 = wb[10], w102 = wb[11];
        float w110 = wb[12], w111 = wb[13], w112 = wb[14];
        float w120 = wb[15], w121 = wb[16], w122 = wb[17];
        float w200 = wb[18], w201 = wb[19], w202 = wb[20];
        float w210 = wb[21], w211 = wb[22], w212 = wb[23];
        float w220 = wb[24], w221 = wb[25], w222 = wb[26];
        float bo = b1s[o];

        const float* xc0 = x + (size_t)bb * (3 * 64 * 128) + (size_t)T0 * 128;
        const float* xc1 = xc0 + 64 * 128;
        const float* xc2 = xc0 + 2 * 64 * 128;

        float4 A0_4, A1_4, A2_4, B0_4, B1_4, B2_4, C0_4, C1_4, C2_4;
        float2 A0_2, A1_2, A2_2, B0_2, B1_2, B2_2, C0_2, C1_2, C2_2;

        LDSET(A, 0)
        LDSET(B, 1)
        LDSET(C, 2)  C1STEP(A, B, C, 0)
        LDSET(A, 3)  C1STEP(B, C, A, 1)
        LDSET(B, 4)  C1STEP(C, A, B, 2)
        LDSET(C, 5)  C1STEP(A, B, C, 3)
        LDSET(A, 6)  C1STEP(B, C, A, 4)
        LDSET(B, 7)  C1STEP(C, A, B, 5)
        LDSET(C, 8)  C1STEP(A, B, C, 6)
        LDSET(A, 9)  C1STEP(B, C, A, 7)
        LDSET(B, 10) C1STEP(C, A, B, 8)
        LDSET(C, 11) C1STEP(A, B, C, 9)
        LDSET(A, 12) C1STEP(B, C, A, 10)
        LDSET(B, 13) C1STEP(C, A, B, 11)
    }
    __syncthreads();

    {
        float u000 = w2s[0],  u001 = w2s[1],  u002 = w2s[2];
        float u010 = w2s[3],  u011 = w2s[4],  u012 = w2s[5];
        float u020 = w2s[6],  u021 = w2s[7],  u022 = w2s[8];
        float u100 = w2s[9],  u101 = w2s[10], u102 = w2s[11];
        float u110 = w2s[12], u111 = w2s[13], u112 = w2s[14];
        float u120 = w2s[15], u121 = w2s[16], u122 = w2s[17];
        float u200 = w2s[18], u201 = w2s[19], u202 = w2s[20];
        float u210 = w2s[21], u211 = w2s[22], u212 = w2s[23];
        float u220 = w2s[24], u221 = w2s[25], u222 = w2s[26];
        float u300 = w2s[27], u301 = w2s[28], u302 = w2s[29];
        float u310 = w2s[30], u311 = w2s[31], u312 = w2s[32];
        float u320 = w2s[33], u321 = w2s[34], u322 = w2s[35];
        float u400 = w2s[36], u401 = w2s[37], u402 = w2s[38];
        float u410 = w2s[39], u411 = w2s[40], u412 = w2s[41];
        float u420 = w2s[42], u421 = w2s[43], u422 = w2s[44];
        float u500 = w2s[45], u501 = w2s[46], u502 = w2s[47];
        float u510 = w2s[48], u511 = w2s[49], u512 = w2s[50];
        float u520 = w2s[51], u521 = w2s[52], u522 = w2s[53];
        float bo2 = b2s;
        for (int idx = tid; idx < 310; idx += 256) {
            const int tq = idx / 31;
            const int s0 = (idx - tq * 31) * 4;
            float acc0 = bo2, acc1 = bo2, acc2 = bo2, acc3 = bo2;
            C2SEG(0, 0, u000, u001, u002)
            C2SEG(0, 1, u010, u011, u012)
            C2SEG(0, 2, u020, u021, u022)
            C2SEG(1, 0, u100, u101, u102)
            C2SEG(1, 1, u110, u111, u112)
            C2SEG(1, 2, u120, u121, u122)
            C2SEG(2, 0, u200, u201, u202)
            C2SEG(2, 1, u210, u211, u212)
            C2SEG(2, 2, u220, u221, u222)
            C2SEG(3, 0, u300, u301, u302)
            C2SEG(3, 1, u310, u311, u312)
            C2SEG(3, 2, u320, u321, u322)
            C2SEG(4, 0, u400, u401, u402)
            C2SEG(4, 1, u410, u411, u412)
            C2SEG(4, 2, u420, u421, u422)
            C2SEG(5, 0, u500, u501, u502)
            C2SEG(5, 1, u510, u511, u512)
            C2SEG(5, 2, u520, u521, u522)
            float4 r;
            r.x = (acc0 >= 0.f) ? acc0 : 0.01f * acc0;
            r.y = (acc1 >= 0.f) ? acc1 : 0.01f * acc1;
            r.z = (acc2 >= 0.f) ? acc2 : 0.01f * acc2;
            r.w = (acc3 >= 0.f) ? acc3 : 0.01f * acc3;
            *(float4*)(seq + ((size_t)bb * 60 + T0 + tq) * 124 + s0) = r;
        }
    }
}

// ---------------------------------------------------------------------------
// seq2bf (R21): convert seq fp32 -> hi/lo bf16 directly in the gi B-frag
// layout, ONCE per chunk (was: re-converted per step by every one of 25
// jt-blocks = 39% VALUBusy in gi_mfma). Layout per (tt,chunk), shorts:
//   S = (((kt*2+half)*128 + bi)*5 + ksub)*8 + c; pads (ksub==4, k>=124) = 0.
// One ull (4 shorts) per thread, coalesced stores.
// ---------------------------------------------------------------------------
__global__ __launch_bounds__(256) void seq2bf(
    const float* __restrict__ seq, unsigned long long* __restrict__ sbf,
    int t0, int nt)
{
    long a = (long)blockIdx.x * 256 + threadIdx.x;
    if (a >= (long)nt * 327680) return;
    int tt  = (int)(a / 327680);
    int u   = (int)(a - (long)tt * 327680);
    int chunk = u / 10240;
    int q   = u - chunk * 10240;
    int c0  = (q & 1) * 4;  q >>= 1;
    int ksub = q % 5;       q /= 5;
    int bi  = q & 127;
    int frag = q >> 7;       // 0..7
    int half = frag & 1;
    int kt   = frag >> 1;
    int k0   = kt * 32 + ksub * 8 + c0;

    unsigned long long outp = 0ull;
    if (ksub < 4 && k0 < 124) {
        float4 v = *(const float4*)(seq +
            ((size_t)(chunk * 128 + bi) * 60 + (t0 + tt)) * 124 + k0);
        unsigned short s0, s1, s2, s3;
        if (half == 0) {
            s0 = f2bf(v.x); s1 = f2bf(v.y); s2 = f2bf(v.z); s3 = f2bf(v.w);
        } else {
            s0 = f2bf(v.x - bf2f(f2bf(v.x)));
            s1 = f2bf(v.y - bf2f(f2bf(v.y)));
            s2 = f2bf(v.z - bf2f(f2bf(v.z)));
            s3 = f2bf(v.w - bf2f(f2bf(v.w)));
        }
        outp = (unsigned long long)s0 | ((unsigned long long)s1 << 16)
             | ((unsigned long long)s2 << 32) | ((unsigned long long)s3 << 48);
    }
    sbf[a] = outp;
}

// ---------------------------------------------------------------------------
// gi via MFMA v2 (R21): NO LDS, no barriers. B frags read directly from the
// precomputed seqbf (L2-resident 2.6MB t-slice shared by all 25 jt-blocks).
// Per wave-step: 8 x 16B global loads + 12 MFMA + 4 stores.
// ---------------------------------------------------------------------------
__global__ __launch_bounds__(512) void gi_mfma(
    const short* __restrict__ sbf, const short* __restrict__ awih,
    float* __restrict__ gic, int nt)
{
    const int tid = threadIdx.x;
    const int l   = tid & 63;
    const int w   = tid >> 6;          // n-tile 0..7
    const int jt  = blockIdx.y;        // 0..24
    const int bx  = blockIdx.x;
    const int b0  = bx * 128;

    const bf16x8* at = (const bf16x8*)awih;
    const int abase = jt * 8 * 64 + l;
    bf16x8 Ah0 = at[abase + 0 * 128];
    bf16x8 Al0 = at[abase + 0 * 128 + 64];
    bf16x8 Ah1 = at[abase + 1 * 128];
    bf16x8 Al1 = at[abase + 1 * 128 + 64];
    bf16x8 Ah2 = at[abase + 2 * 128];
    bf16x8 Al2 = at[abase + 2 * 128 + 64];
    bf16x8 Ah3 = at[abase + 3 * 128];
    bf16x8 Al3 = at[abase + 3 * 128 + 64];

    const int bn   = w * 16 + (l & 15);
    const int ksub = l >> 4;
    const int off0 = bx * 40960 + (bn * 5 + ksub) * 8;
    const int row0 = ksub * 4;

    for (int tt = 0; tt < nt; ++tt) {
        const short* sb = sbf + (size_t)tt * SBF_T_SH + off0;
        f32x4 acc = {0.f, 0.f, 0.f, 0.f};
        #define GI_KT(KT, AH, AL) { \
            bf16x8 bh = *(const bf16x8*)(sb + ((KT) * 2 + 0) * 5120); \
            bf16x8 bl = *(const bf16x8*)(sb + ((KT) * 2 + 1) * 5120); \
            acc = __builtin_amdgcn_mfma_f32_16x16x32_bf16(AL, bh, acc, 0, 0, 0); \
            acc = __builtin_amdgcn_mfma_f32_16x16x32_bf16(AH, bl, acc, 0, 0, 0); \
            acc = __builtin_amdgcn_mfma_f32_16x16x32_bf16(AH, bh, acc, 0, 0, 0); }
        GI_KT(0, Ah0, Al0)
        GI_KT(1, Ah1, Al1)
        GI_KT(2, Ah2, Al2)
        GI_KT(3, Ah3, Al3)
        #undef GI_KT

        float* gt = gic + (size_t)tt * 387 * 4096;
        #pragma unroll
        for (int i = 0; i < 4; ++i) {
            int j = jt * 16 + row0 + i;
            if (j < 387)
                gt[(size_t)j * 4096 + b0 + bn] = acc[i];
        }
    }
}

// ---------------------------------------------------------------------------
// GRU recurrence via MFMA (split bf16) — passing R19/R20 (unchanged).
// ---------------------------------------------------------------------------
__global__ __launch_bounds__(512) void gru_mfma(
    const float* __restrict__ gic, const short* __restrict__ awhh,
    const float* __restrict__ bih, const float* __restrict__ bhh,
    float* __restrict__ hstate, float* __restrict__ g_out,
    int t0, int nt)
{
    __shared__ __attribute__((aligned(16))) short hbf[2 * 16 * 168];
    __shared__ float hs2[16 * 132];
    __shared__ float GHb[16 * 390];
    __shared__ float bihS[387];
    __shared__ float bhhS[387];

    const int tid  = threadIdx.x;
    const int l    = tid & 63;
    const int w    = tid >> 6;        // wave 0..7
    const int b0   = blockIdx.x * 16;
    const int bcol = l & 15;
    const int krow = l >> 4;

    if (tid < 387) { bihS[tid] = bih[tid]; bhhS[tid] = bhh[tid]; }
    for (int e = tid; e < 2688; e += 512) ((unsigned int*)hbf)[e] = 0u;
    if (t0 == 0) {
        for (int e = tid; e < 16 * 132; e += 512) hs2[e] = 0.f;
        __syncthreads();
    } else {
        for (int e = tid; e < 16 * 132; e += 512) hs2[e] = hstate[(size_t)b0 * 132 + e];
        __syncthreads();
        for (int e = tid; e < 2064; e += 512) {
            int r = e & 15, j = e >> 4;
            float v = hs2[r * 132 + j];
            unsigned short hb = f2bf(v);
            hbf[r * 168 + j]        = (short)hb;
            hbf[2688 + r * 168 + j] = (short)f2bf(v - bf2f(hb));
        }
        __syncthreads();
    }

    const bf16x8* at = (const bf16x8*)awhh;

    #define GATE(E, PGA, PGB, PGC) { \
        int r_ = (E) & 15, j_ = (E) >> 4; \
        float pr_  = (PGA) + GHb[r_ * 390 + j_]       + bihS[j_]       + bhhS[j_]; \
        float pz_  = (PGB) + GHb[r_ * 390 + 129 + j_] + bihS[129 + j_] + bhhS[129 + j_]; \
        float gin_ = (PGC) + bihS[258 + j_]; \
        float ghn_ = GHb[r_ * 390 + 258 + j_] + bhhS[258 + j_]; \
        float rg_ = fast_sigmoid(pr_); \
        float zg_ = fast_sigmoid(pz_); \
        float nn_ = fast_tanh(gin_ + rg_ * ghn_); \
        float hn_ = (1.f - zg_) * nn_ + zg_ * hs2[r_ * 132 + j_]; \
        hs2[r_ * 132 + j_] = hn_; \
        unsigned short hb_ = f2bf(hn_); \
        hbf[r_ * 168 + j_]        = (short)hb_; \
        hbf[2688 + r_ * 168 + j_] = (short)f2bf(hn_ - bf2f(hb_)); }

    for (int tt = 0; tt < nt; ++tt) {
        const float* gib = gic + (size_t)tt * 387 * 4096 + b0;
        float pa0, pb0, pc0, pa1, pb1, pc1, pa2, pb2, pc2, pa3, pb3, pc3;
        {
            int r = tid & 15, j = tid >> 4;
            pa0 = gib[(size_t)j * 4096 + r];
            pb0 = gib[(size_t)(129 + j) * 4096 + r];
            pc0 = gib[(size_t)(258 + j) * 4096 + r];
            int e = tid + 512; r = e & 15; j = e >> 4;
            pa1 = gib[(size_t)j * 4096 + r];
            pb1 = gib[(size_t)(129 + j) * 4096 + r];
            pc1 = gib[(size_t)(258 + j) * 4096 + r];
            e = tid + 1024; r = e & 15; j = e >> 4;
            pa2 = gib[(size_t)j * 4096 + r];
            pb2 = gib[(size_t)(129 + j) * 4096 + r];
            pc2 = gib[(size_t)(258 + j) * 4096 + r];
            e = tid + 1536; r = e & 15; j = e >> 4;
            pa3 = gib[(size_t)j * 4096 + r];
            pb3 = gib[(size_t)(129 + j) * 4096 + r];
            pc3 = gib[(size_t)(258 + j) * 4096 + r];
        }

        f32x4 acc0 = {0.f,0.f,0.f,0.f}, acc1 = {0.f,0.f,0.f,0.f};
        f32x4 acc2 = {0.f,0.f,0.f,0.f}, acc3 = {0.f,0.f,0.f,0.f};
        #pragma unroll
        for (int kt = 0; kt < 5; ++kt) {
            bf16x8 bh = *(const bf16x8*)(hbf + bcol * 168 + kt * 32 + krow * 8);
            bf16x8 bl = *(const bf16x8*)(hbf + 2688 + bcol * 168 + kt * 32 + krow * 8);
            {
                int fb = ((w * 5 + kt) * 2) * 64 + l;
                bf16x8 Ah = at[fb], Al = at[fb + 64];
                acc0 = __builtin_amdgcn_mfma_f32_16x16x32_bf16(Al, bh, acc0, 0, 0, 0);
                acc0 = __builtin_amdgcn_mfma_f32_16x16x32_bf16(Ah, bl, acc0, 0, 0, 0);
                acc0 = __builtin_amdgcn_mfma_f32_16x16x32_bf16(Ah, bh, acc0, 0, 0, 0);
            }
            {
                int fb = (((8 + w) * 5 + kt) * 2) * 64 + l;
                bf16x8 Ah = at[fb], Al = at[fb + 64];
                acc1 = __builtin_amdgcn_mfma_f32_16x16x32_bf16(Al, bh, acc1, 0, 0, 0);
                acc1 = __builtin_amdgcn_mfma_f32_16x16x32_bf16(Ah, bl, acc1, 0, 0, 0);
                acc1 = __builtin_amdgcn_mfma_f32_16x16x32_bf16(Ah, bh, acc1, 0, 0, 0);
            }
            {
                int fb = (((16 + w) * 5 + kt) * 2) * 64 + l;
                bf16x8 Ah = at[fb], Al = at[fb + 64];
                acc2 = __builtin_amdgcn_mfma_f32_16x16x32_bf16(Al, bh, acc2, 0, 0, 0);
                acc2 = __builtin_amdgcn_mfma_f32_16x16x32_bf16(Ah, bl, acc2, 0, 0, 0);
                acc2 = __builtin_amdgcn_mfma_f32_16x16x32_bf16(Ah, bh, acc2, 0, 0, 0);
            }
            if (w == 0) {
                int fb = ((24 * 5 + kt) * 2) * 64 + l;
                bf16x8 Ah = at[fb], Al = at[fb + 64];
                acc3 = __builtin_amdgcn_mfma_f32_16x16x32_bf16(Al, bh, acc3, 0, 0, 0);
                acc3 = __builtin_amdgcn_mfma_f32_16x16x32_bf16(Ah, bl, acc3, 0, 0, 0);
                acc3 = __builtin_amdgcn_mfma_f32_16x16x32_bf16(Ah, bh, acc3, 0, 0, 0);
            }
        }
        {
            int rb = bcol * 390;
            int j0 = w * 16 + krow * 4;
            GHb[rb + j0 + 0] = acc0[0];
            GHb[rb + j0 + 1] = acc0[1];
            GHb[rb + j0 + 2] = acc0[2];
            GHb[rb + j0 + 3] = acc0[3];
            int j1 = (8 + w) * 16 + krow * 4;
            GHb[rb + j1 + 0] = acc1[0];
            GHb[rb + j1 + 1] = acc1[1];
            GHb[rb + j1 + 2] = acc1[2];
            GHb[rb + j1 + 3] = acc1[3];
            int j2 = (16 + w) * 16 + krow * 4;
            GHb[rb + j2 + 0] = acc2[0];
            GHb[rb + j2 + 1] = acc2[1];
            GHb[rb + j2 + 2] = acc2[2];
            GHb[rb + j2 + 3] = acc2[3];
            if (w == 0 && krow == 0) {
                GHb[rb + 384] = acc3[0];
                GHb[rb + 385] = acc3[1];
                GHb[rb + 386] = acc3[2];
            }
        }
        __syncthreads();

        GATE(tid,        pa0, pb0, pc0)
        GATE(tid + 512,  pa1, pb1, pc1)
        GATE(tid + 1024, pa2, pb2, pc2)
        GATE(tid + 1536, pa3, pb3, pc3)
        if (tid < 16) {
            float ta = gib[(size_t)128 * 4096 + tid];
            float tb = gib[(size_t)257 * 4096 + tid];
            float tc = gib[(size_t)386 * 4096 + tid];
            GATE(2048 + tid, ta, tb, tc)
        }
        __syncthreads();
    }

    for (int e = tid; e < 16 * 132; e += 512) hstate[(size_t)b0 * 132 + e] = hs2[e];
    if (t0 + nt >= 60) {
        for (int e = tid; e < 2064; e += 512) {
            int r = e & 15, j = e >> 4;
            float v = hs2[r * 132 + j];
            g_out[(size_t)(b0 + r) * 129 + j] = (v >= 0.f) ? v : 0.01f * v;
        }
        if (tid < 16) {
            float v = hs2[tid * 132 + 128];
            g_out[(size_t)(b0 + tid) * 129 + 128] = (v >= 0.f) ? v : 0.01f * v;
        }
    }
    #undef GATE
}

// ---------------------------------------------------------------------------
// Head: feat=[g,w] (258) -> mu, log_std -> sample, tanh, log_pi, normalize.
// ---------------------------------------------------------------------------
__global__ __launch_bounds__(256) void head_kernel(
    const float* __restrict__ gbuf, const float* __restrict__ wvec,
    const float* __restrict__ eps,
    const float* __restrict__ muwp, const float* __restrict__ lswp,
    const float* __restrict__ mub,  const float* __restrict__ lsb,
    float* __restrict__ out)
{
    __shared__ __attribute__((aligned(16))) float feat[16 * 260];
    __shared__ float PA[16 * 130];
    __shared__ float TERM[16 * 130];
    __shared__ float ROWSUM[16];
    __shared__ float ROWLOG[16];

    const int tid = threadIdx.x;
    const int b0  = blockIdx.x * 16;

    for (int i = tid; i < 16 * 260; i += 256) {
        int r = i / 260;
        int k = i - r * 260;
        float v = 0.f;
        if (k < 129)       v = gbuf[(size_t)(b0 + r) * 129 + k];
        else if (k < 258)  v = wvec[(size_t)(b0 + r) * 129 + (k - 129)];
        feat[i] = v;
    }
    __syncthreads();

    for (int idx = tid; idx < 16 * 129; idx += 256) {
        int r = idx & 15;
        int j = idx >> 4;
        const float4* fv = (const float4*)(feat + r * 260);
        const float4* mw = (const float4*)(muwp + (size_t)j * 260);
        const float4* lw = (const float4*)(lswp + (size_t)j * 260);
        float am = 0.f, al = 0.f;
        for (int k = 0; k < 65; ++k) {
            float4 f = fv[k];
            float4 m = mw[k];
            float4 l = lw[k];
            am += f.x * m.x + f.y * m.y + f.z * m.z + f.w * m.w;
            al += f.x * l.x + f.y * l.y + f.z * l.z + f.w * l.w;
        }
        float mu = am + mub[j];
        float ls = fminf(fmaxf(al + lsb[j], -20.f), 2.f);
        float sd = __expf(ls);
        float e  = eps[(size_t)(b0 + r) * 129 + j];
        float xv = mu + sd * e;
        float pa = fast_tanh(xv);
        float tt = (xv - mu) / sd;
        float term = -0.5f * tt * tt - ls - 0.91893853320467274f
                     - __logf(1.f - pa * pa + 1e-6f);
        PA[r * 130 + j]   = pa;
        TERM[r * 130 + j] = term;
    }
    __syncthreads();

    {
        int r = tid >> 4;
        int i = tid & 15;
        float sp = 0.f, st = 0.f;
        for (int j = i; j < 129; j += 16) {
            sp += PA[r * 130 + j];
            st += TERM[r * 130 + j];
        }
        for (int off = 8; off > 0; off >>= 1) {
            sp += __shfl_down(sp, off, 16);
            st += __shfl_down(st, off, 16);
        }
        if (i == 0) { ROWSUM[r] = sp + 129.f; ROWLOG[r] = st; }
    }
    __syncthreads();

    for (int idx = tid; idx < 16 * 129; idx += 256) {
        int r = idx & 15;
        int j = idx >> 4;
        out[(size_t)(b0 + r) * 129 + j] = (PA[r * 130 + j] + 1.f) / ROWSUM[r];
    }
    if (tid < 16)
        out[(size_t)4096 * 129 + b0 + tid] = ROWLOG[tid];
}

// ---------------------------------------------------------------------------
extern "C" void kernel_launch(void* const* d_in, const int* in_sizes, int n_in,
                              void* d_out, int out_size, void* d_ws, size_t ws_size,
                              hipStream_t stream)
{
    const float* x   = (const float*)d_in[0];
    const float* wv  = (const float*)d_in[1];
    const float* eps = (const float*)d_in[2];
    const float* c1w = (const float*)d_in[3];
    const float* c1b = (const float*)d_in[4];
    const float* c2w = (const float*)d_in[5];
    const float* c2b = (const float*)d_in[6];
    const float* Wih = (const float*)d_in[7];
    const float* Whh = (const float*)d_in[8];
    const float* bih = (const float*)d_in[9];
    const float* bhh = (const float*)d_in[10];
    const float* muw = (const float*)d_in[11];
    const float* mub = (const float*)d_in[12];
    const float* lsw = (const float*)d_in[13];
    const float* lsb = (const float*)d_in[14];

    float* ws     = (float*)d_ws;
    float* seq    = ws + SEQ_OFF;
    float* g      = ws + G_OFF;
    float* hstate = ws + HST_OFF;
    const short* awhh = (const short*)(ws + AWHH_OFF);
    const short* awih = (const short*)(ws + AWIH_OFF);
    float* muwp   = ws + MUWP_OFF;
    float* lswp   = ws + LSWP_OFF;
    float* outp   = (float*)d_out;

    // chunk size over t: seqbf (655360 fl/t) + gic (1585152 fl/t)
    const long per_t = (long)PER_T_GIC + PER_T_SBF;
    long avail = (long)(ws_size / 4) - (long)BUF_OFF;
    int CT = 60;
    if (avail < 60 * per_t) {
        CT = (int)(avail / per_t);
        if (CT < 1) CT = 1;
        if (CT > 60) CT = 60;
    }
    float* sbff = ws + BUF_OFF;                       // seqbf region (CT*655360 floats)
    float* gic  = ws + BUF_OFF + (size_t)CT * PER_T_SBF;

    const int prep_elems = 25 * 5 * 2 * 512 + 25 * 4 * 2 * 512 + 2 * (129 * 260);
    prep_pad<<<(prep_elems + 255) / 256, 256, 0, stream>>>(Whh, Wih, muw, lsw, ws);
    conv_fused<<<dim3(6, BTOT), 256, 0, stream>>>(x, c1w, c1b, c2w, c2b, seq);

    for (int t0 = 0; t0 < 60; t0 += CT) {
        int nt = 60 - t0; if (nt > CT) nt = CT;
        long nb = ((long)nt * 327680 + 255) / 256;
        seq2bf<<<(int)nb, 256, 0, stream>>>(seq, (unsigned long long*)sbff, t0, nt);
        gi_mfma<<<dim3(32, 25), 512, 0, stream>>>((const short*)sbff, awih, gic, nt);
        gru_mfma<<<256, 512, 0, stream>>>(gic, awhh, bih, bhh, hstate, g, t0, nt);
    }
    head_kernel<<<BTOT / 16, 256, 0, stream>>>(g, wv, eps, muwp, lswp, mub, lsb, outp);
}